// Round 2
// baseline (5321.352 us; speedup 1.0000x reference)
//
#include <hip/hip_runtime.h>
#include <cstdint>

// ---------------------------------------------------------------------------
// QRoPETRegressor: 4-layer transformer (B=32, S=520 w/ 8 cls, D=512, NH=8,
// HD=64, MLP=2048) + variational heads.  bf16 MFMA GEMMs (fp32 accum),
// bf16 qkv, fp32 softmax/LN.
// ---------------------------------------------------------------------------

#define BATCH   32
#define SEQ     520          // 8 cls + 512
#define DIM     512
#define NHEAD   8
#define HDIM    64
#define MLPD    2048
#define NLAYER  4
#define NROW    (BATCH * SEQ)   // 16640
#define NPAIR   256             // rope pairs over D

typedef __attribute__((ext_vector_type(4))) float  f32x4;
typedef __attribute__((ext_vector_type(8))) short  short8;
typedef __attribute__((ext_vector_type(4))) short  short4v;

__device__ __forceinline__ unsigned short f2bf(float f) {
    unsigned u = __float_as_uint(f);
    unsigned r = (u + 0x7fffu + ((u >> 16) & 1u)) >> 16;
    return (unsigned short)r;
}
__device__ __forceinline__ float bf2f(short s) {
    return __uint_as_float(((unsigned)(unsigned short)s) << 16);
}
__device__ __forceinline__ float wred_sum(float v) {
    #pragma unroll
    for (int off = 32; off; off >>= 1) v += __shfl_xor(v, off);
    return v;
}
__device__ __forceinline__ float wred_max(float v) {
    #pragma unroll
    for (int off = 32; off; off >>= 1) v = fmaxf(v, __shfl_xor(v, off));
    return v;
}

// async global->LDS, 16B per lane; LDS base must be wave-uniform.
// NOTE: proper addrspacecast (NOT integer truncation of the flat address).
__device__ __forceinline__ void gload16(const void* g, void* l) {
    __builtin_amdgcn_global_load_lds(
        (const __attribute__((address_space(1))) unsigned int*)g,
        (__attribute__((address_space(3))) unsigned int*)l,
        16, 0, 0);
}

// ---------------------------------------------------------------------------
// Weight transpose-convert: src fp32 (K,N) row-major  ->  dst bf16 (N,K)
// grid: (N/64, K/64, L)
// ---------------------------------------------------------------------------
__global__ __launch_bounds__(256) void k_wconv(const float* __restrict__ src,
                                               short* __restrict__ dst,
                                               int K, int N) {
    src += (size_t)blockIdx.z * K * N;
    dst += (size_t)blockIdx.z * K * N;
    int n0 = blockIdx.x * 64, k0 = blockIdx.y * 64;
    __shared__ float t[64][65];
    int tid = threadIdx.x;
    int r = tid >> 2, cq = (tid & 3) * 16;
    const float* sp = src + (size_t)(k0 + r) * N + n0 + cq;
    #pragma unroll
    for (int e = 0; e < 16; e += 4) {
        float4 v = *(const float4*)(sp + e);
        t[r][cq + e] = v.x; t[r][cq + e + 1] = v.y;
        t[r][cq + e + 2] = v.z; t[r][cq + e + 3] = v.w;
    }
    __syncthreads();
    int n = tid >> 2, kq = (tid & 3) * 16;
    short* dp = dst + (size_t)(n0 + n) * K + k0 + kq;
    short8 o0, o1;
    #pragma unroll
    for (int e = 0; e < 8; e++) o0[e] = (short)f2bf(t[kq + e][n]);
    #pragma unroll
    for (int e = 0; e < 8; e++) o1[e] = (short)f2bf(t[kq + 8 + e][n]);
    *(short8*)dp = o0;
    *(short8*)(dp + 8) = o1;
}

// ---------------------------------------------------------------------------
// RoPE table: tab[s][i] = (cos, sin) of s * 10000^(-2i/512).  grid: (520,256)
// ---------------------------------------------------------------------------
__global__ void k_rope_tab(float2* __restrict__ tab) {
    int s = blockIdx.x, i = threadIdx.x;
    float fr = powf(10000.f, -2.f * (float)i / 512.f);
    float th = (float)s * fr;
    float sn, cn;
    sincosf(th, &sn, &cn);
    tab[s * NPAIR + i] = make_float2(cn, sn);
}

// ---------------------------------------------------------------------------
// Input proj + cls concat: h[b,s,:] = (s<8) ? cls[s] : x[b,s-8]@W_in + b_in
// grid: NROW blocks, 256 threads
// ---------------------------------------------------------------------------
__global__ __launch_bounds__(256) void k_in_proj(const float* __restrict__ x,
                                                 const float* __restrict__ Wi,
                                                 const float* __restrict__ bi,
                                                 const float* __restrict__ cls,
                                                 float* __restrict__ hf,
                                                 short* __restrict__ hb) {
    int row = blockIdx.x;
    int b = row / SEQ, s = row % SEQ;
    bool is_cls = s < 8;
    float xr[16];
    if (!is_cls) {
        const float* xp = x + (size_t)(b * 512 + (s - 8)) * 16;
        #pragma unroll
        for (int f = 0; f < 16; f++) xr[f] = xp[f];
    }
    for (int c = threadIdx.x; c < DIM; c += 256) {
        float v;
        if (is_cls) {
            v = cls[s * DIM + c];
        } else {
            v = bi[c];
            #pragma unroll
            for (int f = 0; f < 16; f++) v = fmaf(xr[f], Wi[f * DIM + c], v);
        }
        hf[(size_t)row * DIM + c] = v;
        hb[(size_t)row * DIM + c] = (short)f2bf(v);
    }
}

// ---------------------------------------------------------------------------
// GEMM: C[M,N] = act(A[M,K] @ W[K,N] + bias), A bf16 [M][K], Bt bf16 [N][K].
// 128x128 tile, BK=32, 4 waves, global_load_lds w16, mfma 16x16x32 bf16.
// M,N % 128 == 0, K % 32 == 0 (all shapes here satisfy this exactly).
// ---------------------------------------------------------------------------
template <bool RELU, bool OUTBF16>
__global__ __launch_bounds__(256) void k_gemm(const short* __restrict__ A,
                                              const short* __restrict__ Bt,
                                              const float* __restrict__ bias,
                                              void* __restrict__ Cout,
                                              int M, int N, int K) {
    __shared__ __align__(16) short As[128 * 32];
    __shared__ __align__(16) short Bs[128 * 32];
    const int tid = threadIdx.x;
    const int w = tid >> 6, l = tid & 63;
    const int brow = blockIdx.x * 128, bcol = blockIdx.y * 128;
    const int lr = l >> 2;            // 0..15 (row within 16-row chunk)
    const int lk = (l & 3) * 8;       // k element offset within 32
    const int fr = l & 15, fk = (l >> 4) * 8;
    const int wr = (w >> 1) * 64, wc = (w & 1) * 64;

    f32x4 acc[4][4];
    #pragma unroll
    for (int m = 0; m < 4; m++)
        #pragma unroll
        for (int n = 0; n < 4; n++) acc[m][n] = (f32x4){0.f, 0.f, 0.f, 0.f};

    for (int kt = 0; kt < K; kt += 32) {
        // stage A rows [w*32, w*32+32) and Bt rows likewise
        const short* ga = A + (size_t)(brow + w * 32 + lr) * K + kt + lk;
        gload16(ga,                  &As[(w * 32) * 32]);
        gload16(ga + (size_t)16 * K, &As[(w * 32 + 16) * 32]);
        const short* gb = Bt + (size_t)(bcol + w * 32 + lr) * K + kt + lk;
        gload16(gb,                  &Bs[(w * 32) * 32]);
        gload16(gb + (size_t)16 * K, &Bs[(w * 32 + 16) * 32]);
        __syncthreads();

        short8 af[4], bfr[4];
        #pragma unroll
        for (int m = 0; m < 4; m++)
            af[m] = *(const short8*)&As[(wr + m * 16 + fr) * 32 + fk];
        #pragma unroll
        for (int n = 0; n < 4; n++)
            bfr[n] = *(const short8*)&Bs[(wc + n * 16 + fr) * 32 + fk];
        #pragma unroll
        for (int m = 0; m < 4; m++)
            #pragma unroll
            for (int n = 0; n < 4; n++)
                acc[m][n] = __builtin_amdgcn_mfma_f32_16x16x32_bf16(
                    af[m], bfr[n], acc[m][n], 0, 0, 0);
        __syncthreads();
    }

    const int r0 = (l >> 4) * 4, c0 = l & 15;
    #pragma unroll
    for (int m = 0; m < 4; m++) {
        #pragma unroll
        for (int n = 0; n < 4; n++) {
            int col = bcol + wc + n * 16 + c0;
            float bv = bias[col];
            #pragma unroll
            for (int q = 0; q < 4; q++) {
                int row = brow + wr + m * 16 + r0 + q;
                float v = acc[m][n][q] + bv;
                if (RELU) v = fmaxf(v, 0.f);
                if (OUTBF16)
                    ((short*)Cout)[(size_t)row * N + col] = (short)f2bf(v);
                else
                    ((float*)Cout)[(size_t)row * N + col] = v;
            }
        }
    }
}

// ---------------------------------------------------------------------------
// RoPE apply in-place on bf16 q (cols 0..511) and k (cols 512..1023) of qkv.
// grid: NROW blocks, 256 threads (one pair each)
// ---------------------------------------------------------------------------
__global__ __launch_bounds__(256) void k_rope_apply(short* __restrict__ qkv,
                                                    const float2* __restrict__ tab) {
    int row = blockIdx.x;
    int i = threadIdx.x;
    int pos = row % SEQ;
    float2 cs = tab[pos * NPAIR + i];
    short* p = qkv + (size_t)row * 1536 + 2 * i;
    unsigned q = *(unsigned*)p;
    float x1 = bf2f((short)(q & 0xffff)), x2 = bf2f((short)(q >> 16));
    unsigned oq = (unsigned)f2bf(x1 * cs.x - x2 * cs.y) |
                  ((unsigned)f2bf(x1 * cs.y + x2 * cs.x) << 16);
    *(unsigned*)p = oq;
    short* pk = p + 512;
    unsigned k = *(unsigned*)pk;
    x1 = bf2f((short)(k & 0xffff)); x2 = bf2f((short)(k >> 16));
    unsigned ok = (unsigned)f2bf(x1 * cs.x - x2 * cs.y) |
                  ((unsigned)f2bf(x1 * cs.y + x2 * cs.x) << 16);
    *(unsigned*)pk = ok;
}

// ---------------------------------------------------------------------------
// Attention (fp32 accum, bf16 qkv): wave = 8 query rows of one (b,h);
// scores in registers, softmax via shuffles, P (bf16) through LDS for PV.
// grid: B*NH*65/4 = 4160 blocks, 256 threads (4 waves)
// ---------------------------------------------------------------------------
__global__ __launch_bounds__(256) void k_attn(const short* __restrict__ qkv,
                                              short* __restrict__ aob) {
    __shared__ __align__(16) float sQ[4][8][64];
    __shared__ __align__(16) short sP[4][SEQ][8];
    const int tid = threadIdx.x;
    const int w = tid >> 6, l = tid & 63;
    int g = blockIdx.x * 4 + w;         // 0..16639
    int ig = g % 65, bh = g / 65;       // ig: row-group, bh: (b,h)
    int h = bh & 7, b = bh >> 3;
    int i0 = ig * 8;

    const short* qbase = qkv + ((size_t)(b * SEQ + i0)) * 1536 + h * 64;
    #pragma unroll
    for (int r = 0; r < 8; r++)
        sQ[w][r][l] = bf2f(qbase[(size_t)r * 1536 + l]) * 0.125f;  // 1/sqrt(64)
    __syncthreads();

    float dot[8][9];
    #pragma unroll
    for (int r = 0; r < 8; r++)
        #pragma unroll
        for (int jj = 0; jj < 9; jj++)
            dot[r][jj] = (jj * 64 + l < SEQ) ? 0.f : -1e30f;

    const short* kb = qkv + (size_t)(b * SEQ) * 1536 + 512 + h * 64;
    for (int dblk = 0; dblk < 8; dblk++) {     // d in chunks of 8
        float4 qa[8], qb[8];
        #pragma unroll
        for (int r = 0; r < 8; r++) {
            qa[r] = *(const float4*)&sQ[w][r][dblk * 8];
            qb[r] = *(const float4*)&sQ[w][r][dblk * 8 + 4];
        }
        #pragma unroll
        for (int jj = 0; jj < 9; jj++) {
            int j = jj * 64 + l;
            int jc = j < SEQ ? j : SEQ - 1;
            short8 kv = *(const short8*)(kb + (size_t)jc * 1536 + dblk * 8);
            float k0 = bf2f(kv[0]), k1 = bf2f(kv[1]), k2 = bf2f(kv[2]),
                  k3 = bf2f(kv[3]), k4 = bf2f(kv[4]), k5 = bf2f(kv[5]),
                  k6 = bf2f(kv[6]), k7 = bf2f(kv[7]);
            #pragma unroll
            for (int r = 0; r < 8; r++) {
                float s = dot[r][jj];
                s = fmaf(qa[r].x, k0, s);
                s = fmaf(qa[r].y, k1, s);
                s = fmaf(qa[r].z, k2, s);
                s = fmaf(qa[r].w, k3, s);
                s = fmaf(qb[r].x, k4, s);
                s = fmaf(qb[r].y, k5, s);
                s = fmaf(qb[r].z, k6, s);
                s = fmaf(qb[r].w, k7, s);
                dot[r][jj] = s;
            }
        }
    }

    // softmax per row
    float inv[8];
    #pragma unroll
    for (int r = 0; r < 8; r++) {
        float m = -1e30f;
        #pragma unroll
        for (int jj = 0; jj < 9; jj++) m = fmaxf(m, dot[r][jj]);
        m = wred_max(m);
        float sum = 0.f;
        #pragma unroll
        for (int jj = 0; jj < 9; jj++) {
            float e = __expf(dot[r][jj] - m);
            dot[r][jj] = e;
            sum += e;
        }
        sum = wred_sum(sum);
        inv[r] = 1.f / sum;
    }
    #pragma unroll
    for (int jj = 0; jj < 9; jj++) {
        int j = jj * 64 + l;
        if (j < SEQ) {
            short8 pk;
            #pragma unroll
            for (int r = 0; r < 8; r++) pk[r] = (short)f2bf(dot[r][jj] * inv[r]);
            *(short8*)&sP[w][j][0] = pk;
        }
    }
    __syncthreads();

    // PV: lane = output dim d
    const short* vb = qkv + (size_t)(b * SEQ) * 1536 + 1024 + h * 64 + l;
    float out[8] = {0.f, 0.f, 0.f, 0.f, 0.f, 0.f, 0.f, 0.f};
    #pragma unroll 4
    for (int j = 0; j < SEQ; j++) {
        short8 p8 = *(const short8*)&sP[w][j][0];
        float vv = bf2f(vb[(size_t)j * 1536]);
        #pragma unroll
        for (int r = 0; r < 8; r++) out[r] = fmaf(bf2f(p8[r]), vv, out[r]);
    }
    short* ao = aob + ((size_t)(b * SEQ + i0)) * DIM + h * 64 + l;
    #pragma unroll
    for (int r = 0; r < 8; r++) ao[(size_t)r * DIM] = (short)f2bf(out[r]);
}

// ---------------------------------------------------------------------------
// Residual + LayerNorm: hf = LN(hf + delta)*g + b; also emits bf16 copy.
// grid: NROW blocks, 64 threads
// ---------------------------------------------------------------------------
__global__ __launch_bounds__(64) void k_ln(float* __restrict__ hf,
                                           const float* __restrict__ delta,
                                           const float* __restrict__ g,
                                           const float* __restrict__ bta,
                                           short* __restrict__ hb) {
    int row = blockIdx.x, l = threadIdx.x;
    size_t base = (size_t)row * DIM;
    float4 a0 = *(const float4*)&hf[base + l * 4];
    float4 a1 = *(const float4*)&hf[base + 256 + l * 4];
    float4 d0 = *(const float4*)&delta[base + l * 4];
    float4 d1 = *(const float4*)&delta[base + 256 + l * 4];
    a0.x += d0.x; a0.y += d0.y; a0.z += d0.z; a0.w += d0.w;
    a1.x += d1.x; a1.y += d1.y; a1.z += d1.z; a1.w += d1.w;
    float s1 = a0.x + a0.y + a0.z + a0.w + a1.x + a1.y + a1.z + a1.w;
    float s2 = a0.x * a0.x + a0.y * a0.y + a0.z * a0.z + a0.w * a0.w +
               a1.x * a1.x + a1.y * a1.y + a1.z * a1.z + a1.w * a1.w;
    s1 = wred_sum(s1);
    s2 = wred_sum(s2);
    float mu = s1 * (1.f / 512.f);
    float var = s2 * (1.f / 512.f) - mu * mu;
    float rr = rsqrtf(var + 1e-6f);
    float4 g0 = *(const float4*)&g[l * 4];
    float4 g1 = *(const float4*)&g[256 + l * 4];
    float4 b0 = *(const float4*)&bta[l * 4];
    float4 b1 = *(const float4*)&bta[256 + l * 4];
    float4 y0, y1;
    y0.x = (a0.x - mu) * rr * g0.x + b0.x;
    y0.y = (a0.y - mu) * rr * g0.y + b0.y;
    y0.z = (a0.z - mu) * rr * g0.z + b0.z;
    y0.w = (a0.w - mu) * rr * g0.w + b0.w;
    y1.x = (a1.x - mu) * rr * g1.x + b1.x;
    y1.y = (a1.y - mu) * rr * g1.y + b1.y;
    y1.z = (a1.z - mu) * rr * g1.z + b1.z;
    y1.w = (a1.w - mu) * rr * g1.w + b1.w;
    *(float4*)&hf[base + l * 4] = y0;
    *(float4*)&hf[base + 256 + l * 4] = y1;
    short4v h0, h1;
    h0[0] = (short)f2bf(y0.x); h0[1] = (short)f2bf(y0.y);
    h0[2] = (short)f2bf(y0.z); h0[3] = (short)f2bf(y0.w);
    h1[0] = (short)f2bf(y1.x); h1[1] = (short)f2bf(y1.y);
    h1[2] = (short)f2bf(y1.z); h1[3] = (short)f2bf(y1.w);
    *(short4v*)&hb[base + l * 4] = h0;
    *(short4v*)&hb[base + 256 + l * 4] = h1;
}

// ---------------------------------------------------------------------------
// Head hidden: hid[b,o,j] = relu(x_cls[b,o,:] @ Wh[o] + bh[o,j])
// grid: (2, 8, 32) blocks of 256
// ---------------------------------------------------------------------------
__global__ __launch_bounds__(256) void k_hid(const float* __restrict__ hf,
                                             const float* __restrict__ Wh,
                                             const float* __restrict__ bh,
                                             float* __restrict__ hid) {
    int j = blockIdx.x * 256 + threadIdx.x;
    int o = blockIdx.y, b = blockIdx.z;
    const float* xr = hf + ((size_t)(b * SEQ + o)) * DIM;
    const float* wcol = Wh + (size_t)o * DIM * DIM + j;
    float acc = bh[o * DIM + j];
    #pragma unroll 8
    for (int d = 0; d < DIM; d++) acc = fmaf(xr[d], wcol[(size_t)d * DIM], acc);
    hid[((size_t)b * 8 + o) * DIM + j] = fmaxf(acc, 0.f);
}

// ---------------------------------------------------------------------------
// Variational heads -> out[0:256] = mu, out[256:512] = log(EPS+softplus(lv))
// grid: 256 blocks (b*8+o) of 64 threads
// ---------------------------------------------------------------------------
__device__ __forceinline__ float softplus_f(float x) { return log1pf(expf(x)); }

__global__ __launch_bounds__(64) void k_var(const float* __restrict__ hid,
                                            const float* __restrict__ mu_wmu,
                                            const float* __restrict__ mu_wrho,
                                            const float* __restrict__ mu_bmu,
                                            const float* __restrict__ mu_brho,
                                            const float* __restrict__ lv_wmu,
                                            const float* __restrict__ lv_wrho,
                                            const float* __restrict__ lv_bmu,
                                            const float* __restrict__ lv_brho,
                                            const float* __restrict__ eps_mu_w,
                                            const float* __restrict__ eps_mu_b,
                                            const float* __restrict__ eps_lv_w,
                                            const float* __restrict__ eps_lv_b,
                                            float* __restrict__ out) {
    const float EPS = 1e-8f;
    int bo = blockIdx.x;
    int o = bo & 7;
    int l = threadIdx.x;
    float am = 0.f, al = 0.f;
    #pragma unroll
    for (int k = 0; k < 8; k++) {
        int d = k * 64 + l;
        int od = o * DIM + d;
        float hv = hid[(size_t)bo * DIM + d];
        am = fmaf(hv, mu_wmu[od] + (softplus_f(mu_wrho[od]) + EPS) * eps_mu_w[od], am);
        al = fmaf(hv, lv_wmu[od] + (softplus_f(lv_wrho[od]) + EPS) * eps_lv_w[od], al);
    }
    am = wred_sum(am);
    al = wred_sum(al);
    if (l == 0) {
        float mu = am + mu_bmu[o] + (softplus_f(mu_brho[o]) + EPS) * eps_mu_b[o];
        out[bo] = mu;
        float lvv = al + lv_bmu[o] + (softplus_f(lv_brho[o]) + EPS) * eps_lv_b[o];
        out[256 + bo] = logf(EPS + softplus_f(lvv));
    }
}

// ---------------------------------------------------------------------------
extern "C" void kernel_launch(void* const* d_in, const int* in_sizes, int n_in,
                              void* d_out, int out_size, void* d_ws, size_t ws_size,
                              hipStream_t stream) {
    const float* x      = (const float*)d_in[0];
    const float* W_in   = (const float*)d_in[1];
    const float* b_in   = (const float*)d_in[2];
    const float* cls    = (const float*)d_in[3];
    const float* Wqkv   = (const float*)d_in[4];
    const float* bqkv   = (const float*)d_in[5];
    const float* Wo     = (const float*)d_in[6];
    const float* bo     = (const float*)d_in[7];
    const float* ln1_g  = (const float*)d_in[8];
    const float* ln1_b  = (const float*)d_in[9];
    const float* Wm1    = (const float*)d_in[10];
    const float* bm1    = (const float*)d_in[11];
    const float* Wm2    = (const float*)d_in[12];
    const float* bm2    = (const float*)d_in[13];
    const float* ln2_g  = (const float*)d_in[14];
    const float* ln2_b  = (const float*)d_in[15];
    const float* Wh     = (const float*)d_in[16];
    const float* bh     = (const float*)d_in[17];
    const float* mu_wmu = (const float*)d_in[18];
    const float* mu_wrho= (const float*)d_in[19];
    const float* mu_bmu = (const float*)d_in[20];
    const float* mu_brho= (const float*)d_in[21];
    const float* lv_wmu = (const float*)d_in[22];
    const float* lv_wrho= (const float*)d_in[23];
    const float* lv_bmu = (const float*)d_in[24];
    const float* lv_brho= (const float*)d_in[25];
    const float* e_mu_w = (const float*)d_in[26];
    const float* e_mu_b = (const float*)d_in[27];
    const float* e_lv_w = (const float*)d_in[28];
    const float* e_lv_b = (const float*)d_in[29];
    float* out = (float*)d_out;

    // ---- workspace layout (~188 MB total; qkv/mid share one union region) --
    char* p = (char*)d_ws;
    auto alloc = [&](size_t bytes) {
        char* r = p;
        p += (bytes + 255) & ~(size_t)255;
        return r;
    };
    const size_t qkv_bytes = (size_t)NROW * 1536 * 2;   // bf16
    const size_t mid_bytes = (size_t)NROW * MLPD * 2;   // bf16
    float*  hf    = (float*) alloc((size_t)NROW * DIM * 4);
    float*  delta = (float*) alloc((size_t)NROW * DIM * 4);
    char*   U1    =          alloc(qkv_bytes > mid_bytes ? qkv_bytes : mid_bytes);
    short*  qkv   = (short*)U1;   // live: qkv-GEMM .. attn
    short*  mid   = (short*)U1;   // live: MLP1 .. MLP2 (disjoint from qkv)
    short*  hb    = (short*) alloc((size_t)NROW * DIM * 2);
    short*  aob   = (short*) alloc((size_t)NROW * DIM * 2);
    short*  wqkvt = (short*) alloc((size_t)NLAYER * 1536 * 512 * 2);
    short*  wot   = (short*) alloc((size_t)NLAYER * 512 * 512 * 2);
    short*  wm1t  = (short*) alloc((size_t)NLAYER * 2048 * 512 * 2);
    short*  wm2t  = (short*) alloc((size_t)NLAYER * 512 * 2048 * 2);
    float2* ropet = (float2*)alloc((size_t)SEQ * NPAIR * 8);
    float*  hid   = (float*) alloc((size_t)256 * DIM * 4);

    // weight convert + rope table (once per call)
    k_wconv<<<dim3(24, 8, 4), 256, 0, stream>>>(Wqkv, wqkvt, 512, 1536);
    k_wconv<<<dim3(8, 8, 4),  256, 0, stream>>>(Wo,   wot,   512, 512);
    k_wconv<<<dim3(32, 8, 4), 256, 0, stream>>>(Wm1,  wm1t,  512, 2048);
    k_wconv<<<dim3(8, 32, 4), 256, 0, stream>>>(Wm2,  wm2t,  2048, 512);
    k_rope_tab<<<SEQ, NPAIR, 0, stream>>>(ropet);
    k_in_proj<<<NROW, 256, 0, stream>>>(x, W_in, b_in, cls, hf, hb);

    for (int l = 0; l < NLAYER; l++) {
        k_gemm<false, true><<<dim3(NROW / 128, 1536 / 128), 256, 0, stream>>>(
            hb, wqkvt + (size_t)l * 1536 * 512, bqkv + l * 1536, qkv, NROW, 1536, 512);
        k_rope_apply<<<NROW, NPAIR, 0, stream>>>(qkv, ropet);
        k_attn<<<BATCH * NHEAD * 65 / 4, 256, 0, stream>>>(qkv, aob);
        k_gemm<false, false><<<dim3(NROW / 128, 512 / 128), 256, 0, stream>>>(
            aob, wot + (size_t)l * 512 * 512, bo + l * 512, delta, NROW, 512, 512);
        k_ln<<<NROW, 64, 0, stream>>>(hf, delta, ln1_g + l * 512, ln1_b + l * 512, hb);
        k_gemm<true, true><<<dim3(NROW / 128, 2048 / 128), 256, 0, stream>>>(
            hb, wm1t + (size_t)l * 2048 * 512, bm1 + l * 2048, mid, NROW, 2048, 512);
        k_gemm<false, false><<<dim3(NROW / 128, 512 / 128), 256, 0, stream>>>(
            mid, wm2t + (size_t)l * 512 * 2048, bm2 + l * 512, delta, NROW, 512, 2048);
        k_ln<<<NROW, 64, 0, stream>>>(hf, delta, ln2_g + l * 512, ln2_b + l * 512, hb);
    }

    k_hid<<<dim3(2, 8, 32), 256, 0, stream>>>(hf, Wh, bh, hid);
    k_var<<<256, 64, 0, stream>>>(hid, mu_wmu, mu_wrho, mu_bmu, mu_brho,
                                  lv_wmu, lv_wrho, lv_bmu, lv_brho,
                                  e_mu_w, e_mu_b, e_lv_w, e_lv_b, out);
}

// Round 3
// 1452.040 us; speedup vs baseline: 3.6647x; 3.6647x over previous
//
#include <hip/hip_runtime.h>
#include <cstdint>

// ---------------------------------------------------------------------------
// QRoPETRegressor: 4-layer transformer (B=32, S=520 w/ 8 cls, D=512, NH=8,
// HD=64, MLP=2048) + variational heads.  bf16 MFMA GEMMs + MFMA flash attn.
// ---------------------------------------------------------------------------

#define BATCH   32
#define SEQ     520          // 8 cls + 512
#define SP      576          // padded seq (9 * 64) for attention tiles
#define DIM     512
#define NHEAD   8
#define HDIM    64
#define MLPD    2048
#define NLAYER  4
#define NROW    (BATCH * SEQ)   // 16640
#define NPAIR   256             // rope pairs over D

typedef __attribute__((ext_vector_type(4))) float  f32x4;
typedef __attribute__((ext_vector_type(8))) short  short8;
typedef __attribute__((ext_vector_type(4))) short  short4v;

__device__ __forceinline__ unsigned short f2bf(float f) {
    unsigned u = __float_as_uint(f);
    unsigned r = (u + 0x7fffu + ((u >> 16) & 1u)) >> 16;
    return (unsigned short)r;
}
__device__ __forceinline__ float bf2f(short s) {
    return __uint_as_float(((unsigned)(unsigned short)s) << 16);
}
__device__ __forceinline__ float wred_sum(float v) {
    #pragma unroll
    for (int off = 32; off; off >>= 1) v += __shfl_xor(v, off);
    return v;
}

// async global->LDS, 16B per lane; LDS base wave-uniform, global addr per-lane.
__device__ __forceinline__ void gload16(const void* g, void* l) {
    __builtin_amdgcn_global_load_lds(
        (const __attribute__((address_space(1))) unsigned int*)g,
        (__attribute__((address_space(3))) unsigned int*)l,
        16, 0, 0);
}

// ---------------------------------------------------------------------------
// Weight transpose-convert: src fp32 (K,N) row-major  ->  dst bf16 (N,K)
// ---------------------------------------------------------------------------
__global__ __launch_bounds__(256) void k_wconv(const float* __restrict__ src,
                                               short* __restrict__ dst,
                                               int K, int N) {
    src += (size_t)blockIdx.z * K * N;
    dst += (size_t)blockIdx.z * K * N;
    int n0 = blockIdx.x * 64, k0 = blockIdx.y * 64;
    __shared__ float t[64][65];
    int tid = threadIdx.x;
    int r = tid >> 2, cq = (tid & 3) * 16;
    const float* sp = src + (size_t)(k0 + r) * N + n0 + cq;
    #pragma unroll
    for (int e = 0; e < 16; e += 4) {
        float4 v = *(const float4*)(sp + e);
        t[r][cq + e] = v.x; t[r][cq + e + 1] = v.y;
        t[r][cq + e + 2] = v.z; t[r][cq + e + 3] = v.w;
    }
    __syncthreads();
    int n = tid >> 2, kq = (tid & 3) * 16;
    short* dp = dst + (size_t)(n0 + n) * K + k0 + kq;
    short8 o0, o1;
    #pragma unroll
    for (int e = 0; e < 8; e++) o0[e] = (short)f2bf(t[kq + e][n]);
    #pragma unroll
    for (int e = 0; e < 8; e++) o1[e] = (short)f2bf(t[kq + 8 + e][n]);
    *(short8*)dp = o0;
    *(short8*)(dp + 8) = o1;
}

// ---------------------------------------------------------------------------
// RoPE table
// ---------------------------------------------------------------------------
__global__ void k_rope_tab(float2* __restrict__ tab) {
    int s = blockIdx.x, i = threadIdx.x;
    float fr = powf(10000.f, -2.f * (float)i / 512.f);
    float th = (float)s * fr;
    float sn, cn;
    sincosf(th, &sn, &cn);
    tab[s * NPAIR + i] = make_float2(cn, sn);
}

// ---------------------------------------------------------------------------
// Input proj + cls concat
// ---------------------------------------------------------------------------
__global__ __launch_bounds__(256) void k_in_proj(const float* __restrict__ x,
                                                 const float* __restrict__ Wi,
                                                 const float* __restrict__ bi,
                                                 const float* __restrict__ cls,
                                                 float* __restrict__ hf,
                                                 short* __restrict__ hb) {
    int row = blockIdx.x;
    int b = row / SEQ, s = row % SEQ;
    bool is_cls = s < 8;
    float xr[16];
    if (!is_cls) {
        const float* xp = x + (size_t)(b * 512 + (s - 8)) * 16;
        #pragma unroll
        for (int f = 0; f < 16; f++) xr[f] = xp[f];
    }
    for (int c = threadIdx.x; c < DIM; c += 256) {
        float v;
        if (is_cls) {
            v = cls[s * DIM + c];
        } else {
            v = bi[c];
            #pragma unroll
            for (int f = 0; f < 16; f++) v = fmaf(xr[f], Wi[f * DIM + c], v);
        }
        hf[(size_t)row * DIM + c] = v;
        hb[(size_t)row * DIM + c] = (short)f2bf(v);
    }
}

// ---------------------------------------------------------------------------
// GEMM: C[M,N] = act(A[M,K] @ W[K,N] + bias), A bf16 [M][K], Bt bf16 [N][K].
// ---------------------------------------------------------------------------
template <bool RELU, bool OUTBF16>
__global__ __launch_bounds__(256) void k_gemm(const short* __restrict__ A,
                                              const short* __restrict__ Bt,
                                              const float* __restrict__ bias,
                                              void* __restrict__ Cout,
                                              int M, int N, int K) {
    __shared__ __align__(16) short As[128 * 32];
    __shared__ __align__(16) short Bs[128 * 32];
    const int tid = threadIdx.x;
    const int w = tid >> 6, l = tid & 63;
    const int brow = blockIdx.x * 128, bcol = blockIdx.y * 128;
    const int lr = l >> 2;
    const int lk = (l & 3) * 8;
    const int fr = l & 15, fk = (l >> 4) * 8;
    const int wr = (w >> 1) * 64, wc = (w & 1) * 64;

    f32x4 acc[4][4];
    #pragma unroll
    for (int m = 0; m < 4; m++)
        #pragma unroll
        for (int n = 0; n < 4; n++) acc[m][n] = (f32x4){0.f, 0.f, 0.f, 0.f};

    for (int kt = 0; kt < K; kt += 32) {
        const short* ga = A + (size_t)(brow + w * 32 + lr) * K + kt + lk;
        gload16(ga,                  &As[(w * 32) * 32]);
        gload16(ga + (size_t)16 * K, &As[(w * 32 + 16) * 32]);
        const short* gb = Bt + (size_t)(bcol + w * 32 + lr) * K + kt + lk;
        gload16(gb,                  &Bs[(w * 32) * 32]);
        gload16(gb + (size_t)16 * K, &Bs[(w * 32 + 16) * 32]);
        __syncthreads();

        short8 af[4], bfr[4];
        #pragma unroll
        for (int m = 0; m < 4; m++)
            af[m] = *(const short8*)&As[(wr + m * 16 + fr) * 32 + fk];
        #pragma unroll
        for (int n = 0; n < 4; n++)
            bfr[n] = *(const short8*)&Bs[(wc + n * 16 + fr) * 32 + fk];
        #pragma unroll
        for (int m = 0; m < 4; m++)
            #pragma unroll
            for (int n = 0; n < 4; n++)
                acc[m][n] = __builtin_amdgcn_mfma_f32_16x16x32_bf16(
                    af[m], bfr[n], acc[m][n], 0, 0, 0);
        __syncthreads();
    }

    const int r0 = (l >> 4) * 4, c0 = l & 15;
    #pragma unroll
    for (int m = 0; m < 4; m++) {
        #pragma unroll
        for (int n = 0; n < 4; n++) {
            int col = bcol + wc + n * 16 + c0;
            float bv = bias[col];
            #pragma unroll
            for (int q = 0; q < 4; q++) {
                int row = brow + wr + m * 16 + r0 + q;
                float v = acc[m][n][q] + bv;
                if (RELU) v = fmaxf(v, 0.f);
                if (OUTBF16)
                    ((short*)Cout)[(size_t)row * N + col] = (short)f2bf(v);
                else
                    ((float*)Cout)[(size_t)row * N + col] = v;
            }
        }
    }
}

// ---------------------------------------------------------------------------
// RoPE on Q only (in place), folding the 1/sqrt(HD)=0.125 score scale into Q.
// grid: NROW x 256
// ---------------------------------------------------------------------------
__global__ __launch_bounds__(256) void k_rope_q(short* __restrict__ qkv,
                                                const float2* __restrict__ tab) {
    int row = blockIdx.x;
    int i = threadIdx.x;
    int pos = row % SEQ;
    float2 cs = tab[pos * NPAIR + i];
    short* p = qkv + (size_t)row * 1536 + 2 * i;
    unsigned q = *(unsigned*)p;
    float x1 = bf2f((short)(q & 0xffff)), x2 = bf2f((short)(q >> 16));
    unsigned oq = (unsigned)f2bf((x1 * cs.x - x2 * cs.y) * 0.125f) |
                  ((unsigned)f2bf((x1 * cs.y + x2 * cs.x) * 0.125f) << 16);
    *(unsigned*)p = oq;
}

// ---------------------------------------------------------------------------
// K/V prep: rope K -> kbuf[bh][SP][64] (zero-padded rows >= SEQ);
//           transpose V -> vtbuf[bh][64][SP] (zero-padded cols >= SEQ).
// grid: B*NH*9 blocks x 256
// ---------------------------------------------------------------------------
__global__ __launch_bounds__(256) void k_kvprep(const short* __restrict__ qkv,
                                                const float2* __restrict__ tab,
                                                short* __restrict__ kbuf,
                                                short* __restrict__ vtbuf) {
    int bx = blockIdx.x;
    int jt = bx % 9, bh = bx / 9, b = bh >> 3, h = bh & 7;
    int tid = threadIdx.x;
    int row = tid >> 2, ch = tid & 3;        // 64 rows x 4 chunks of 16 elems
    int s = jt * 64 + row;
    bool valid = s < SEQ;
    size_t g = (size_t)(b * SEQ + (valid ? s : 0)) * 1536;

    // ---- K: rope + zero-pad ----
    short8 ok0 = (short8)0, ok1 = (short8)0;
    if (valid) {
        short8 k0 = *(const short8*)(qkv + g + 512 + h * 64 + ch * 16);
        short8 k1 = *(const short8*)(qkv + g + 512 + h * 64 + ch * 16 + 8);
        #pragma unroll
        for (int pp = 0; pp < 4; pp++) {
            float2 cs = tab[s * NPAIR + h * 32 + ch * 8 + pp];
            float x1 = bf2f(k0[2 * pp]), x2 = bf2f(k0[2 * pp + 1]);
            ok0[2 * pp]     = (short)f2bf(x1 * cs.x - x2 * cs.y);
            ok0[2 * pp + 1] = (short)f2bf(x1 * cs.y + x2 * cs.x);
            cs = tab[s * NPAIR + h * 32 + ch * 8 + 4 + pp];
            x1 = bf2f(k1[2 * pp]); x2 = bf2f(k1[2 * pp + 1]);
            ok1[2 * pp]     = (short)f2bf(x1 * cs.x - x2 * cs.y);
            ok1[2 * pp + 1] = (short)f2bf(x1 * cs.y + x2 * cs.x);
        }
    }
    short* kd = kbuf + ((size_t)bh * SP + jt * 64 + row) * 64 + ch * 16;
    *(short8*)kd = ok0;
    *(short8*)(kd + 8) = ok1;

    // ---- V: transpose via LDS ----
    __shared__ short vt[64][72];
    short8 v0 = (short8)0, v1 = (short8)0;
    if (valid) {
        v0 = *(const short8*)(qkv + g + 1024 + h * 64 + ch * 16);
        v1 = *(const short8*)(qkv + g + 1024 + h * 64 + ch * 16 + 8);
    }
    *(short8*)&vt[row][ch * 16] = v0;
    *(short8*)&vt[row][ch * 16 + 8] = v1;
    __syncthreads();
    int d = row;                              // output d-row
    short8 w0, w1;
    #pragma unroll
    for (int e = 0; e < 8; e++) w0[e] = vt[ch * 16 + e][d];
    #pragma unroll
    for (int e = 0; e < 8; e++) w1[e] = vt[ch * 16 + 8 + e][d];
    short* vd = vtbuf + ((size_t)bh * 64 + d) * SP + jt * 64 + ch * 16;
    *(short8*)vd = w0;
    *(short8*)(vd + 8) = w1;
}

// ---------------------------------------------------------------------------
// MFMA flash attention.  Block = (b,h,qt): 64 q-rows, 4 waves x 16 rows.
// K tile [64][64] and Vt tile [64][64] in LDS (XOR-swizzled 16B blocks via
// pre-swizzled global source).  Online softmax; P via per-wave LDS tile.
// grid: B*NH*9 = 2304 blocks x 256
// ---------------------------------------------------------------------------
__global__ __launch_bounds__(256) void k_attn_mfma(const short* __restrict__ qkv,
                                                   const short* __restrict__ kbuf,
                                                   const short* __restrict__ vtbuf,
                                                   short* __restrict__ aob) {
    __shared__ __align__(16) short Kl[64 * 64];
    __shared__ __align__(16) short Vl[64 * 64];
    __shared__ __align__(16) short sP[4][16][72];
    const int tid = threadIdx.x;
    const int w = tid >> 6, l = tid & 63;
    const int c = l & 15, t4 = l >> 4;
    int bx = blockIdx.x;
    int qt = bx % 9, bh = bx / 9, b = bh >> 3, h = bh & 7;

    // Q fragments (A-frag: lane row = c, k = t4*8..+8), pre-scaled by 0.125
    int q0 = qt * 64 + w * 16;
    int qrow = q0 + c;
    size_t gq = (size_t)(b * SEQ + (qrow < SEQ ? qrow : SEQ - 1)) * 1536 + h * 64;
    short8 qf0 = *(const short8*)(qkv + gq + t4 * 8);
    short8 qf1 = *(const short8*)(qkv + gq + 32 + t4 * 8);

    f32x4 o0 = {0,0,0,0}, o1 = {0,0,0,0}, o2 = {0,0,0,0}, o3 = {0,0,0,0};
    float mrow[4] = {-1e30f, -1e30f, -1e30f, -1e30f};
    float lrow[4] = {0.f, 0.f, 0.f, 0.f};

    const short* kb = kbuf + (size_t)bh * SP * 64;
    const short* vb = vtbuf + (size_t)bh * 64 * SP;
    const int r1 = w * 16 + (l >> 3);         // staged row (K) / d-row (V)
    const int r2 = r1 + 8;
    const int blk = l & 7;                    // 16B block within 128B row

    for (int jt = 0; jt < 9; jt++) {
        // ---- stage K[64][64] and Vt[64][64]; source pre-swizzled so LDS
        //      slot (row, blk) holds data (row, blk^(row&7))
        gload16(kb + ((size_t)(jt * 64 + r1)) * 64 + ((blk ^ (r1 & 7)) * 8),
                &Kl[(w * 16) * 64]);
        gload16(kb + ((size_t)(jt * 64 + r2)) * 64 + ((blk ^ (r2 & 7)) * 8),
                &Kl[(w * 16 + 8) * 64]);
        gload16(vb + (size_t)r1 * SP + jt * 64 + ((blk ^ (r1 & 7)) * 8),
                &Vl[(w * 16) * 64]);
        gload16(vb + (size_t)r2 * SP + jt * 64 + ((blk ^ (r2 & 7)) * 8),
                &Vl[(w * 16 + 8) * 64]);
        __syncthreads();

        // ---- QK^T: S[16 q][64 kv] per wave
        f32x4 s0 = {0,0,0,0}, s1 = {0,0,0,0}, s2 = {0,0,0,0}, s3 = {0,0,0,0};
        {
            int kr0 = 0 * 16 + c, kr1 = 16 + c, kr2 = 32 + c, kr3 = 48 + c;
            short8 kf;
            kf = *(const short8*)&Kl[kr0 * 64 + ((t4 ^ (kr0 & 7)) * 8)];
            s0 = __builtin_amdgcn_mfma_f32_16x16x32_bf16(qf0, kf, s0, 0, 0, 0);
            kf = *(const short8*)&Kl[kr0 * 64 + (((4 + t4) ^ (kr0 & 7)) * 8)];
            s0 = __builtin_amdgcn_mfma_f32_16x16x32_bf16(qf1, kf, s0, 0, 0, 0);
            kf = *(const short8*)&Kl[kr1 * 64 + ((t4 ^ (kr1 & 7)) * 8)];
            s1 = __builtin_amdgcn_mfma_f32_16x16x32_bf16(qf0, kf, s1, 0, 0, 0);
            kf = *(const short8*)&Kl[kr1 * 64 + (((4 + t4) ^ (kr1 & 7)) * 8)];
            s1 = __builtin_amdgcn_mfma_f32_16x16x32_bf16(qf1, kf, s1, 0, 0, 0);
            kf = *(const short8*)&Kl[kr2 * 64 + ((t4 ^ (kr2 & 7)) * 8)];
            s2 = __builtin_amdgcn_mfma_f32_16x16x32_bf16(qf0, kf, s2, 0, 0, 0);
            kf = *(const short8*)&Kl[kr2 * 64 + (((4 + t4) ^ (kr2 & 7)) * 8)];
            s2 = __builtin_amdgcn_mfma_f32_16x16x32_bf16(qf1, kf, s2, 0, 0, 0);
            kf = *(const short8*)&Kl[kr3 * 64 + ((t4 ^ (kr3 & 7)) * 8)];
            s3 = __builtin_amdgcn_mfma_f32_16x16x32_bf16(qf0, kf, s3, 0, 0, 0);
            kf = *(const short8*)&Kl[kr3 * 64 + (((4 + t4) ^ (kr3 & 7)) * 8)];
            s3 = __builtin_amdgcn_mfma_f32_16x16x32_bf16(qf1, kf, s3, 0, 0, 0);
        }

        // ---- mask kv tail (jt==8: only j_local < 8 valid)
        if (jt == 8) {
            #pragma unroll
            for (int r = 0; r < 4; r++) {
                if (c >= 8) s0[r] = -1e30f;
                s1[r] = -1e30f; s2[r] = -1e30f; s3[r] = -1e30f;
            }
        }

        // ---- online softmax (rows q = t4*4 + r; 16-lane row groups)
        #pragma unroll
        for (int r = 0; r < 4; r++) {
            float mx = fmaxf(fmaxf(s0[r], s1[r]), fmaxf(s2[r], s3[r]));
            mx = fmaxf(mx, __shfl_xor(mx, 1));
            mx = fmaxf(mx, __shfl_xor(mx, 2));
            mx = fmaxf(mx, __shfl_xor(mx, 4));
            mx = fmaxf(mx, __shfl_xor(mx, 8));
            float mn = fmaxf(mrow[r], mx);
            float sc = __expf(mrow[r] - mn);
            mrow[r] = mn;
            float p0 = __expf(s0[r] - mn), p1 = __expf(s1[r] - mn);
            float p2 = __expf(s2[r] - mn), p3 = __expf(s3[r] - mn);
            float rs = p0 + p1 + p2 + p3;
            rs += __shfl_xor(rs, 1);
            rs += __shfl_xor(rs, 2);
            rs += __shfl_xor(rs, 4);
            rs += __shfl_xor(rs, 8);
            lrow[r] = lrow[r] * sc + rs;
            o0[r] *= sc; o1[r] *= sc; o2[r] *= sc; o3[r] *= sc;
            int q = t4 * 4 + r;
            sP[w][q][c]      = (short)f2bf(p0);
            sP[w][q][16 + c] = (short)f2bf(p1);
            sP[w][q][32 + c] = (short)f2bf(p2);
            sP[w][q][48 + c] = (short)f2bf(p3);
        }

        // ---- PV: O += P[16 q][64 j] * V[64 j][64 d]
        {
            short8 pf0 = *(const short8*)&sP[w][c][t4 * 8];
            short8 pf1 = *(const short8*)&sP[w][c][32 + t4 * 8];
            int vr0 = 0 * 16 + c, vr1 = 16 + c, vr2 = 32 + c, vr3 = 48 + c;
            short8 vf;
            vf = *(const short8*)&Vl[vr0 * 64 + ((t4 ^ (vr0 & 7)) * 8)];
            o0 = __builtin_amdgcn_mfma_f32_16x16x32_bf16(pf0, vf, o0, 0, 0, 0);
            vf = *(const short8*)&Vl[vr0 * 64 + (((4 + t4) ^ (vr0 & 7)) * 8)];
            o0 = __builtin_amdgcn_mfma_f32_16x16x32_bf16(pf1, vf, o0, 0, 0, 0);
            vf = *(const short8*)&Vl[vr1 * 64 + ((t4 ^ (vr1 & 7)) * 8)];
            o1 = __builtin_amdgcn_mfma_f32_16x16x32_bf16(pf0, vf, o1, 0, 0, 0);
            vf = *(const short8*)&Vl[vr1 * 64 + (((4 + t4) ^ (vr1 & 7)) * 8)];
            o1 = __builtin_amdgcn_mfma_f32_16x16x32_bf16(pf1, vf, o1, 0, 0, 0);
            vf = *(const short8*)&Vl[vr2 * 64 + ((t4 ^ (vr2 & 7)) * 8)];
            o2 = __builtin_amdgcn_mfma_f32_16x16x32_bf16(pf0, vf, o2, 0, 0, 0);
            vf = *(const short8*)&Vl[vr2 * 64 + (((4 + t4) ^ (vr2 & 7)) * 8)];
            o2 = __builtin_amdgcn_mfma_f32_16x16x32_bf16(pf1, vf, o2, 0, 0, 0);
            vf = *(const short8*)&Vl[vr3 * 64 + ((t4 ^ (vr3 & 7)) * 8)];
            o3 = __builtin_amdgcn_mfma_f32_16x16x32_bf16(pf0, vf, o3, 0, 0, 0);
            vf = *(const short8*)&Vl[vr3 * 64 + (((4 + t4) ^ (vr3 & 7)) * 8)];
            o3 = __builtin_amdgcn_mfma_f32_16x16x32_bf16(pf1, vf, o3, 0, 0, 0);
        }
        __syncthreads();
    }

    // ---- epilogue: normalize and store
    #pragma unroll
    for (int r = 0; r < 4; r++) {
        int q = q0 + t4 * 4 + r;
        if (q < SEQ) {
            float inv = 1.f / lrow[r];
            short* ao = aob + ((size_t)(b * SEQ + q)) * DIM + h * 64 + c;
            ao[0]  = (short)f2bf(o0[r] * inv);
            ao[16] = (short)f2bf(o1[r] * inv);
            ao[32] = (short)f2bf(o2[r] * inv);
            ao[48] = (short)f2bf(o3[r] * inv);
        }
    }
}

// ---------------------------------------------------------------------------
// Residual + LayerNorm
// ---------------------------------------------------------------------------
__global__ __launch_bounds__(64) void k_ln(float* __restrict__ hf,
                                           const float* __restrict__ delta,
                                           const float* __restrict__ g,
                                           const float* __restrict__ bta,
                                           short* __restrict__ hb) {
    int row = blockIdx.x, l = threadIdx.x;
    size_t base = (size_t)row * DIM;
    float4 a0 = *(const float4*)&hf[base + l * 4];
    float4 a1 = *(const float4*)&hf[base + 256 + l * 4];
    float4 d0 = *(const float4*)&delta[base + l * 4];
    float4 d1 = *(const float4*)&delta[base + 256 + l * 4];
    a0.x += d0.x; a0.y += d0.y; a0.z += d0.z; a0.w += d0.w;
    a1.x += d1.x; a1.y += d1.y; a1.z += d1.z; a1.w += d1.w;
    float s1 = a0.x + a0.y + a0.z + a0.w + a1.x + a1.y + a1.z + a1.w;
    float s2 = a0.x * a0.x + a0.y * a0.y + a0.z * a0.z + a0.w * a0.w +
               a1.x * a1.x + a1.y * a1.y + a1.z * a1.z + a1.w * a1.w;
    s1 = wred_sum(s1);
    s2 = wred_sum(s2);
    float mu = s1 * (1.f / 512.f);
    float var = s2 * (1.f / 512.f) - mu * mu;
    float rr = rsqrtf(var + 1e-6f);
    float4 g0 = *(const float4*)&g[l * 4];
    float4 g1 = *(const float4*)&g[256 + l * 4];
    float4 b0 = *(const float4*)&bta[l * 4];
    float4 b1 = *(const float4*)&bta[256 + l * 4];
    float4 y0, y1;
    y0.x = (a0.x - mu) * rr * g0.x + b0.x;
    y0.y = (a0.y - mu) * rr * g0.y + b0.y;
    y0.z = (a0.z - mu) * rr * g0.z + b0.z;
    y0.w = (a0.w - mu) * rr * g0.w + b0.w;
    y1.x = (a1.x - mu) * rr * g1.x + b1.x;
    y1.y = (a1.y - mu) * rr * g1.y + b1.y;
    y1.z = (a1.z - mu) * rr * g1.z + b1.z;
    y1.w = (a1.w - mu) * rr * g1.w + b1.w;
    *(float4*)&hf[base + l * 4] = y0;
    *(float4*)&hf[base + 256 + l * 4] = y1;
    short4v h0, h1;
    h0[0] = (short)f2bf(y0.x); h0[1] = (short)f2bf(y0.y);
    h0[2] = (short)f2bf(y0.z); h0[3] = (short)f2bf(y0.w);
    h1[0] = (short)f2bf(y1.x); h1[1] = (short)f2bf(y1.y);
    h1[2] = (short)f2bf(y1.z); h1[3] = (short)f2bf(y1.w);
    *(short4v*)&hb[base + l * 4] = h0;
    *(short4v*)&hb[base + 256 + l * 4] = h1;
}

// ---------------------------------------------------------------------------
// Head hidden
// ---------------------------------------------------------------------------
__global__ __launch_bounds__(256) void k_hid(const float* __restrict__ hf,
                                             const float* __restrict__ Wh,
                                             const float* __restrict__ bh,
                                             float* __restrict__ hid) {
    int j = blockIdx.x * 256 + threadIdx.x;
    int o = blockIdx.y, b = blockIdx.z;
    const float* xr = hf + ((size_t)(b * SEQ + o)) * DIM;
    const float* wcol = Wh + (size_t)o * DIM * DIM + j;
    float acc = bh[o * DIM + j];
    #pragma unroll 8
    for (int d = 0; d < DIM; d++) acc = fmaf(xr[d], wcol[(size_t)d * DIM], acc);
    hid[((size_t)b * 8 + o) * DIM + j] = fmaxf(acc, 0.f);
}

// ---------------------------------------------------------------------------
// Variational heads
// ---------------------------------------------------------------------------
__device__ __forceinline__ float softplus_f(float x) { return log1pf(expf(x)); }

__global__ __launch_bounds__(64) void k_var(const float* __restrict__ hid,
                                            const float* __restrict__ mu_wmu,
                                            const float* __restrict__ mu_wrho,
                                            const float* __restrict__ mu_bmu,
                                            const float* __restrict__ mu_brho,
                                            const float* __restrict__ lv_wmu,
                                            const float* __restrict__ lv_wrho,
                                            const float* __restrict__ lv_bmu,
                                            const float* __restrict__ lv_brho,
                                            const float* __restrict__ eps_mu_w,
                                            const float* __restrict__ eps_mu_b,
                                            const float* __restrict__ eps_lv_w,
                                            const float* __restrict__ eps_lv_b,
                                            float* __restrict__ out) {
    const float EPS = 1e-8f;
    int bo = blockIdx.x;
    int o = bo & 7;
    int l = threadIdx.x;
    float am = 0.f, al = 0.f;
    #pragma unroll
    for (int k = 0; k < 8; k++) {
        int d = k * 64 + l;
        int od = o * DIM + d;
        float hv = hid[(size_t)bo * DIM + d];
        am = fmaf(hv, mu_wmu[od] + (softplus_f(mu_wrho[od]) + EPS) * eps_mu_w[od], am);
        al = fmaf(hv, lv_wmu[od] + (softplus_f(lv_wrho[od]) + EPS) * eps_lv_w[od], al);
    }
    am = wred_sum(am);
    al = wred_sum(al);
    if (l == 0) {
        float mu = am + mu_bmu[o] + (softplus_f(mu_brho[o]) + EPS) * eps_mu_b[o];
        out[bo] = mu;
        float lvv = al + lv_bmu[o] + (softplus_f(lv_brho[o]) + EPS) * eps_lv_b[o];
        out[256 + bo] = logf(EPS + softplus_f(lvv));
    }
}

// ---------------------------------------------------------------------------
extern "C" void kernel_launch(void* const* d_in, const int* in_sizes, int n_in,
                              void* d_out, int out_size, void* d_ws, size_t ws_size,
                              hipStream_t stream) {
    const float* x      = (const float*)d_in[0];
    const float* W_in   = (const float*)d_in[1];
    const float* b_in   = (const float*)d_in[2];
    const float* cls    = (const float*)d_in[3];
    const float* Wqkv   = (const float*)d_in[4];
    const float* bqkv   = (const float*)d_in[5];
    const float* Wo     = (const float*)d_in[6];
    const float* bo     = (const float*)d_in[7];
    const float* ln1_g  = (const float*)d_in[8];
    const float* ln1_b  = (const float*)d_in[9];
    const float* Wm1    = (const float*)d_in[10];
    const float* bm1    = (const float*)d_in[11];
    const float* Wm2    = (const float*)d_in[12];
    const float* bm2    = (const float*)d_in[13];
    const float* ln2_g  = (const float*)d_in[14];
    const float* ln2_b  = (const float*)d_in[15];
    const float* Wh     = (const float*)d_in[16];
    const float* bh     = (const float*)d_in[17];
    const float* mu_wmu = (const float*)d_in[18];
    const float* mu_wrho= (const float*)d_in[19];
    const float* mu_bmu = (const float*)d_in[20];
    const float* mu_brho= (const float*)d_in[21];
    const float* lv_wmu = (const float*)d_in[22];
    const float* lv_wrho= (const float*)d_in[23];
    const float* lv_bmu = (const float*)d_in[24];
    const float* lv_brho= (const float*)d_in[25];
    const float* e_mu_w = (const float*)d_in[26];
    const float* e_mu_b = (const float*)d_in[27];
    const float* e_lv_w = (const float*)d_in[28];
    const float* e_lv_b = (const float*)d_in[29];
    float* out = (float*)d_out;

    // ---- workspace layout; qkv+kbuf+vtbuf union'd with MLP mid buffer ----
    char* p = (char*)d_ws;
    auto alloc = [&](size_t bytes) {
        char* r = p;
        p += (bytes + 255) & ~(size_t)255;
        return r;
    };
    const size_t qkv_bytes = (size_t)NROW * 1536 * 2;              // 51.1 MB
    const size_t kbuf_bytes = (size_t)BATCH * NHEAD * SP * 64 * 2; // 18.9 MB
    const size_t attn_bytes = qkv_bytes + 2 * kbuf_bytes + 512;
    const size_t mid_bytes = (size_t)NROW * MLPD * 2;              // 68.2 MB
    float*  hf    = (float*) alloc((size_t)NROW * DIM * 4);
    float*  delta = (float*) alloc((size_t)NROW * DIM * 4);
    char*   U1    =          alloc(attn_bytes > mid_bytes ? attn_bytes : mid_bytes);
    short*  qkv   = (short*)U1;
    short*  kbuf  = (short*)(U1 + ((qkv_bytes + 255) & ~(size_t)255));
    short*  vtbuf = kbuf + kbuf_bytes / 2;
    short*  mid   = (short*)U1;              // aliases qkv region (disjoint lifetime)
    short*  hb    = (short*) alloc((size_t)NROW * DIM * 2);
    short*  aob   = (short*) alloc((size_t)NROW * DIM * 2);
    short*  wqkvt = (short*) alloc((size_t)NLAYER * 1536 * 512 * 2);
    short*  wot   = (short*) alloc((size_t)NLAYER * 512 * 512 * 2);
    short*  wm1t  = (short*) alloc((size_t)NLAYER * 2048 * 512 * 2);
    short*  wm2t  = (short*) alloc((size_t)NLAYER * 512 * 2048 * 2);
    float2* ropet = (float2*)alloc((size_t)SEQ * NPAIR * 8);
    float*  hid   = (float*) alloc((size_t)256 * DIM * 4);

    k_wconv<<<dim3(24, 8, 4), 256, 0, stream>>>(Wqkv, wqkvt, 512, 1536);
    k_wconv<<<dim3(8, 8, 4),  256, 0, stream>>>(Wo,   wot,   512, 512);
    k_wconv<<<dim3(32, 8, 4), 256, 0, stream>>>(Wm1,  wm1t,  512, 2048);
    k_wconv<<<dim3(8, 32, 4), 256, 0, stream>>>(Wm2,  wm2t,  2048, 512);
    k_rope_tab<<<SEQ, NPAIR, 0, stream>>>(ropet);
    k_in_proj<<<NROW, 256, 0, stream>>>(x, W_in, b_in, cls, hf, hb);

    for (int l = 0; l < NLAYER; l++) {
        k_gemm<false, true><<<dim3(NROW / 128, 1536 / 128), 256, 0, stream>>>(
            hb, wqkvt + (size_t)l * 1536 * 512, bqkv + l * 1536, qkv, NROW, 1536, 512);
        k_rope_q<<<NROW, NPAIR, 0, stream>>>(qkv, ropet);
        k_kvprep<<<BATCH * NHEAD * 9, 256, 0, stream>>>(qkv, ropet, kbuf, vtbuf);
        k_attn_mfma<<<BATCH * NHEAD * 9, 256, 0, stream>>>(qkv, kbuf, vtbuf, aob);
        k_gemm<false, false><<<dim3(NROW / 128, 512 / 128), 256, 0, stream>>>(
            aob, wot + (size_t)l * 512 * 512, bo + l * 512, delta, NROW, 512, 512);
        k_ln<<<NROW, 64, 0, stream>>>(hf, delta, ln1_g + l * 512, ln1_b + l * 512, hb);
        k_gemm<true, true><<<dim3(NROW / 128, 2048 / 128), 256, 0, stream>>>(
            hb, wm1t + (size_t)l * 2048 * 512, bm1 + l * 2048, mid, NROW, 2048, 512);
        k_gemm<false, false><<<dim3(NROW / 128, 512 / 128), 256, 0, stream>>>(
            mid, wm2t + (size_t)l * 512 * 2048, bm2 + l * 512, delta, NROW, 512, 2048);
        k_ln<<<NROW, 64, 0, stream>>>(hf, delta, ln2_g + l * 512, ln2_b + l * 512, hb);
    }

    k_hid<<<dim3(2, 8, 32), 256, 0, stream>>>(hf, Wh, bh, hid);
    k_var<<<256, 64, 0, stream>>>(hid, mu_wmu, mu_wrho, mu_bmu, mu_brho,
                                  lv_wmu, lv_wrho, lv_bmu, lv_brho,
                                  e_mu_w, e_mu_b, e_lv_w, e_lv_b, out);
}

// Round 4
// 1410.995 us; speedup vs baseline: 3.7713x; 1.0291x over previous
//
#include <hip/hip_runtime.h>
#include <cstdint>

// ---------------------------------------------------------------------------
// QRoPETRegressor: 4-layer transformer (B=32, S=520 w/ 8 cls, D=512, NH=8,
// HD=64, MLP=2048) + variational heads.  bf16 MFMA GEMMs + MFMA flash attn.
// R4: GEMM BK=64 + XOR-swizzled LDS (T2), XCD-chunked tile swizzle (T1),
//     attention grid re-ordered for per-XCD K/V locality.
// ---------------------------------------------------------------------------

#define BATCH   32
#define SEQ     520          // 8 cls + 512
#define SP      576          // padded seq (9 * 64) for attention tiles
#define DIM     512
#define NHEAD   8
#define HDIM    64
#define MLPD    2048
#define NLAYER  4
#define NROW    (BATCH * SEQ)   // 16640
#define NPAIR   256             // rope pairs over D

typedef __attribute__((ext_vector_type(4))) float  f32x4;
typedef __attribute__((ext_vector_type(8))) short  short8;
typedef __attribute__((ext_vector_type(4))) short  short4v;

__device__ __forceinline__ unsigned short f2bf(float f) {
    unsigned u = __float_as_uint(f);
    unsigned r = (u + 0x7fffu + ((u >> 16) & 1u)) >> 16;
    return (unsigned short)r;
}
__device__ __forceinline__ float bf2f(short s) {
    return __uint_as_float(((unsigned)(unsigned short)s) << 16);
}
__device__ __forceinline__ float wred_sum(float v) {
    #pragma unroll
    for (int off = 32; off; off >>= 1) v += __shfl_xor(v, off);
    return v;
}

// async global->LDS, 16B per lane; LDS base wave-uniform, global addr per-lane.
__device__ __forceinline__ void gload16(const void* g, void* l) {
    __builtin_amdgcn_global_load_lds(
        (const __attribute__((address_space(1))) unsigned int*)g,
        (__attribute__((address_space(3))) unsigned int*)l,
        16, 0, 0);
}

// ---------------------------------------------------------------------------
// Weight transpose-convert: src fp32 (K,N) row-major  ->  dst bf16 (N,K)
// ---------------------------------------------------------------------------
__global__ __launch_bounds__(256) void k_wconv(const float* __restrict__ src,
                                               short* __restrict__ dst,
                                               int K, int N) {
    src += (size_t)blockIdx.z * K * N;
    dst += (size_t)blockIdx.z * K * N;
    int n0 = blockIdx.x * 64, k0 = blockIdx.y * 64;
    __shared__ float t[64][65];
    int tid = threadIdx.x;
    int r = tid >> 2, cq = (tid & 3) * 16;
    const float* sp = src + (size_t)(k0 + r) * N + n0 + cq;
    #pragma unroll
    for (int e = 0; e < 16; e += 4) {
        float4 v = *(const float4*)(sp + e);
        t[r][cq + e] = v.x; t[r][cq + e + 1] = v.y;
        t[r][cq + e + 2] = v.z; t[r][cq + e + 3] = v.w;
    }
    __syncthreads();
    int n = tid >> 2, kq = (tid & 3) * 16;
    short* dp = dst + (size_t)(n0 + n) * K + k0 + kq;
    short8 o0, o1;
    #pragma unroll
    for (int e = 0; e < 8; e++) o0[e] = (short)f2bf(t[kq + e][n]);
    #pragma unroll
    for (int e = 0; e < 8; e++) o1[e] = (short)f2bf(t[kq + 8 + e][n]);
    *(short8*)dp = o0;
    *(short8*)(dp + 8) = o1;
}

// ---------------------------------------------------------------------------
// RoPE table
// ---------------------------------------------------------------------------
__global__ void k_rope_tab(float2* __restrict__ tab) {
    int s = blockIdx.x, i = threadIdx.x;
    float fr = powf(10000.f, -2.f * (float)i / 512.f);
    float th = (float)s * fr;
    float sn, cn;
    sincosf(th, &sn, &cn);
    tab[s * NPAIR + i] = make_float2(cn, sn);
}

// ---------------------------------------------------------------------------
// Input proj + cls concat
// ---------------------------------------------------------------------------
__global__ __launch_bounds__(256) void k_in_proj(const float* __restrict__ x,
                                                 const float* __restrict__ Wi,
                                                 const float* __restrict__ bi,
                                                 const float* __restrict__ cls,
                                                 float* __restrict__ hf,
                                                 short* __restrict__ hb) {
    int row = blockIdx.x;
    int b = row / SEQ, s = row % SEQ;
    bool is_cls = s < 8;
    float xr[16];
    if (!is_cls) {
        const float* xp = x + (size_t)(b * 512 + (s - 8)) * 16;
        #pragma unroll
        for (int f = 0; f < 16; f++) xr[f] = xp[f];
    }
    for (int c = threadIdx.x; c < DIM; c += 256) {
        float v;
        if (is_cls) {
            v = cls[s * DIM + c];
        } else {
            v = bi[c];
            #pragma unroll
            for (int f = 0; f < 16; f++) v = fmaf(xr[f], Wi[f * DIM + c], v);
        }
        hf[(size_t)row * DIM + c] = v;
        hb[(size_t)row * DIM + c] = (short)f2bf(v);
    }
}

// ---------------------------------------------------------------------------
// GEMM: C[M,N] = act(A[M,K] @ W[K,N] + bias), A bf16 [M][K], Bt bf16 [N][K].
// 128x128 tile, BK=64, XOR-swizzled LDS (16B block ^ (row&7), both sides),
// 1-D grid with XCD-chunked tile swizzle (grid must be divisible by 8).
// ---------------------------------------------------------------------------
template <bool RELU, bool OUTBF16>
__global__ __launch_bounds__(256) void k_gemm(const short* __restrict__ A,
                                              const short* __restrict__ Bt,
                                              const float* __restrict__ bias,
                                              void* __restrict__ Cout,
                                              int N, int K) {
    __shared__ __align__(16) short As[128 * 64];
    __shared__ __align__(16) short Bs[128 * 64];
    const int tid = threadIdx.x;
    const int w = tid >> 6, l = tid & 63;

    // XCD-chunked swizzle: consecutive tiles (same A row-tile) on one XCD.
    const int chunk = gridDim.x >> 3;
    const int t = (blockIdx.x & 7) * chunk + (blockIdx.x >> 3);
    const int C = N >> 7;
    const int brow = (t / C) * 128, bcol = (t % C) * 128;

    const int srow = l >> 3;          // 0..7   staged row within 8-row group
    const int sblk = l & 7;           // 16B block within 128B row
    const int fr = l & 15, t4 = l >> 4;
    const int wr = (w >> 1) * 64, wc = (w & 1) * 64;

    f32x4 acc[4][4];
    #pragma unroll
    for (int m = 0; m < 4; m++)
        #pragma unroll
        for (int n = 0; n < 4; n++) acc[m][n] = (f32x4){0.f, 0.f, 0.f, 0.f};

    for (int kt = 0; kt < K; kt += 64) {
        // ---- stage A/B tiles, 4 gload16 each per wave (8 rows per call);
        //      global source pre-swizzled: block sblk^srow of row r
        #pragma unroll
        for (int i = 0; i < 4; i++) {
            int rb = w * 32 + i * 8;
            gload16(A + (size_t)(brow + rb + srow) * K + kt + ((sblk ^ srow) * 8),
                    &As[rb * 64]);
        }
        #pragma unroll
        for (int i = 0; i < 4; i++) {
            int rb = w * 32 + i * 8;
            gload16(Bt + (size_t)(bcol + rb + srow) * K + kt + ((sblk ^ srow) * 8),
                    &Bs[rb * 64]);
        }
        __syncthreads();

        // ---- fragments: row r, k-lower = block t4, k-upper = block 4+t4,
        //      stored at slot ^ (r&7)
        short8 af[4][2], bfr[4][2];
        #pragma unroll
        for (int m = 0; m < 4; m++) {
            int r = wr + m * 16 + fr;
            af[m][0] = *(const short8*)&As[r * 64 + ((t4 ^ (r & 7)) * 8)];
            af[m][1] = *(const short8*)&As[r * 64 + (((4 + t4) ^ (r & 7)) * 8)];
        }
        #pragma unroll
        for (int n = 0; n < 4; n++) {
            int r = wc + n * 16 + fr;
            bfr[n][0] = *(const short8*)&Bs[r * 64 + ((t4 ^ (r & 7)) * 8)];
            bfr[n][1] = *(const short8*)&Bs[r * 64 + (((4 + t4) ^ (r & 7)) * 8)];
        }
        #pragma unroll
        for (int kk = 0; kk < 2; kk++)
            #pragma unroll
            for (int m = 0; m < 4; m++)
                #pragma unroll
                for (int n = 0; n < 4; n++)
                    acc[m][n] = __builtin_amdgcn_mfma_f32_16x16x32_bf16(
                        af[m][kk], bfr[n][kk], acc[m][n], 0, 0, 0);
        __syncthreads();
    }

    const int r0 = (l >> 4) * 4, c0 = l & 15;
    #pragma unroll
    for (int m = 0; m < 4; m++) {
        #pragma unroll
        for (int n = 0; n < 4; n++) {
            int col = bcol + wc + n * 16 + c0;
            float bv = bias[col];
            #pragma unroll
            for (int q = 0; q < 4; q++) {
                int row = brow + wr + m * 16 + r0 + q;
                float v = acc[m][n][q] + bv;
                if (RELU) v = fmaxf(v, 0.f);
                if (OUTBF16)
                    ((short*)Cout)[(size_t)row * N + col] = (short)f2bf(v);
                else
                    ((float*)Cout)[(size_t)row * N + col] = v;
            }
        }
    }
}

// ---------------------------------------------------------------------------
// RoPE on Q only (in place), folding the 1/sqrt(HD)=0.125 score scale into Q.
// ---------------------------------------------------------------------------
__global__ __launch_bounds__(256) void k_rope_q(short* __restrict__ qkv,
                                                const float2* __restrict__ tab) {
    int row = blockIdx.x;
    int i = threadIdx.x;
    int pos = row % SEQ;
    float2 cs = tab[pos * NPAIR + i];
    short* p = qkv + (size_t)row * 1536 + 2 * i;
    unsigned q = *(unsigned*)p;
    float x1 = bf2f((short)(q & 0xffff)), x2 = bf2f((short)(q >> 16));
    unsigned oq = (unsigned)f2bf((x1 * cs.x - x2 * cs.y) * 0.125f) |
                  ((unsigned)f2bf((x1 * cs.y + x2 * cs.x) * 0.125f) << 16);
    *(unsigned*)p = oq;
}

// ---------------------------------------------------------------------------
// K/V prep: rope K -> kbuf[bh][SP][64] (zero-padded rows >= SEQ);
//           transpose V -> vtbuf[bh][64][SP] (zero-padded cols >= SEQ).
// ---------------------------------------------------------------------------
__global__ __launch_bounds__(256) void k_kvprep(const short* __restrict__ qkv,
                                                const float2* __restrict__ tab,
                                                short* __restrict__ kbuf,
                                                short* __restrict__ vtbuf) {
    int bx = blockIdx.x;
    int jt = bx % 9, bh = bx / 9, b = bh >> 3, h = bh & 7;
    int tid = threadIdx.x;
    int row = tid >> 2, ch = tid & 3;        // 64 rows x 4 chunks of 16 elems
    int s = jt * 64 + row;
    bool valid = s < SEQ;
    size_t g = (size_t)(b * SEQ + (valid ? s : 0)) * 1536;

    // ---- K: rope + zero-pad ----
    short8 ok0 = (short8)0, ok1 = (short8)0;
    if (valid) {
        short8 k0 = *(const short8*)(qkv + g + 512 + h * 64 + ch * 16);
        short8 k1 = *(const short8*)(qkv + g + 512 + h * 64 + ch * 16 + 8);
        #pragma unroll
        for (int pp = 0; pp < 4; pp++) {
            float2 cs = tab[s * NPAIR + h * 32 + ch * 8 + pp];
            float x1 = bf2f(k0[2 * pp]), x2 = bf2f(k0[2 * pp + 1]);
            ok0[2 * pp]     = (short)f2bf(x1 * cs.x - x2 * cs.y);
            ok0[2 * pp + 1] = (short)f2bf(x1 * cs.y + x2 * cs.x);
            cs = tab[s * NPAIR + h * 32 + ch * 8 + 4 + pp];
            x1 = bf2f(k1[2 * pp]); x2 = bf2f(k1[2 * pp + 1]);
            ok1[2 * pp]     = (short)f2bf(x1 * cs.x - x2 * cs.y);
            ok1[2 * pp + 1] = (short)f2bf(x1 * cs.y + x2 * cs.x);
        }
    }
    short* kd = kbuf + ((size_t)bh * SP + jt * 64 + row) * 64 + ch * 16;
    *(short8*)kd = ok0;
    *(short8*)(kd + 8) = ok1;

    // ---- V: transpose via LDS ----
    __shared__ short vt[64][72];
    short8 v0 = (short8)0, v1 = (short8)0;
    if (valid) {
        v0 = *(const short8*)(qkv + g + 1024 + h * 64 + ch * 16);
        v1 = *(const short8*)(qkv + g + 1024 + h * 64 + ch * 16 + 8);
    }
    *(short8*)&vt[row][ch * 16] = v0;
    *(short8*)&vt[row][ch * 16 + 8] = v1;
    __syncthreads();
    int d = row;                              // output d-row
    short8 w0, w1;
    #pragma unroll
    for (int e = 0; e < 8; e++) w0[e] = vt[ch * 16 + e][d];
    #pragma unroll
    for (int e = 0; e < 8; e++) w1[e] = vt[ch * 16 + 8 + e][d];
    short* vd = vtbuf + ((size_t)bh * 64 + d) * SP + jt * 64 + ch * 16;
    *(short8*)vd = w0;
    *(short8*)(vd + 8) = w1;
}

// ---------------------------------------------------------------------------
// MFMA flash attention.  Block = (qt,bh): 64 q-rows, 4 waves x 16 rows.
// grid: bx = qt*256 + bh  (same-bh blocks land on the same XCD under
// round-robin dispatch -> K/V L2 locality).
// ---------------------------------------------------------------------------
__global__ __launch_bounds__(256) void k_attn_mfma(const short* __restrict__ qkv,
                                                   const short* __restrict__ kbuf,
                                                   const short* __restrict__ vtbuf,
                                                   short* __restrict__ aob) {
    __shared__ __align__(16) short Kl[64 * 64];
    __shared__ __align__(16) short Vl[64 * 64];
    __shared__ __align__(16) short sP[4][16][72];
    const int tid = threadIdx.x;
    const int w = tid >> 6, l = tid & 63;
    const int c = l & 15, t4 = l >> 4;
    int bx = blockIdx.x;
    int qt = bx >> 8, bh = bx & 255, b = bh >> 3, h = bh & 7;

    // Q fragments (A-frag: lane row = c, k = t4*8..+8), pre-scaled by 0.125
    int q0 = qt * 64 + w * 16;
    int qrow = q0 + c;
    size_t gq = (size_t)(b * SEQ + (qrow < SEQ ? qrow : SEQ - 1)) * 1536 + h * 64;
    short8 qf0 = *(const short8*)(qkv + gq + t4 * 8);
    short8 qf1 = *(const short8*)(qkv + gq + 32 + t4 * 8);

    f32x4 o0 = {0,0,0,0}, o1 = {0,0,0,0}, o2 = {0,0,0,0}, o3 = {0,0,0,0};
    float mrow[4] = {-1e30f, -1e30f, -1e30f, -1e30f};
    float lrow[4] = {0.f, 0.f, 0.f, 0.f};

    const short* kb = kbuf + (size_t)bh * SP * 64;
    const short* vb = vtbuf + (size_t)bh * 64 * SP;
    const int r1 = w * 16 + (l >> 3);         // staged row (K) / d-row (V)
    const int r2 = r1 + 8;
    const int blk = l & 7;                    // 16B block within 128B row

    for (int jt = 0; jt < 9; jt++) {
        gload16(kb + ((size_t)(jt * 64 + r1)) * 64 + ((blk ^ (r1 & 7)) * 8),
                &Kl[(w * 16) * 64]);
        gload16(kb + ((size_t)(jt * 64 + r2)) * 64 + ((blk ^ (r2 & 7)) * 8),
                &Kl[(w * 16 + 8) * 64]);
        gload16(vb + (size_t)r1 * SP + jt * 64 + ((blk ^ (r1 & 7)) * 8),
                &Vl[(w * 16) * 64]);
        gload16(vb + (size_t)r2 * SP + jt * 64 + ((blk ^ (r2 & 7)) * 8),
                &Vl[(w * 16 + 8) * 64]);
        __syncthreads();

        // ---- QK^T: S[16 q][64 kv] per wave
        f32x4 s0 = {0,0,0,0}, s1 = {0,0,0,0}, s2 = {0,0,0,0}, s3 = {0,0,0,0};
        {
            int kr0 = 0 * 16 + c, kr1 = 16 + c, kr2 = 32 + c, kr3 = 48 + c;
            short8 kf;
            kf = *(const short8*)&Kl[kr0 * 64 + ((t4 ^ (kr0 & 7)) * 8)];
            s0 = __builtin_amdgcn_mfma_f32_16x16x32_bf16(qf0, kf, s0, 0, 0, 0);
            kf = *(const short8*)&Kl[kr0 * 64 + (((4 + t4) ^ (kr0 & 7)) * 8)];
            s0 = __builtin_amdgcn_mfma_f32_16x16x32_bf16(qf1, kf, s0, 0, 0, 0);
            kf = *(const short8*)&Kl[kr1 * 64 + ((t4 ^ (kr1 & 7)) * 8)];
            s1 = __builtin_amdgcn_mfma_f32_16x16x32_bf16(qf0, kf, s1, 0, 0, 0);
            kf = *(const short8*)&Kl[kr1 * 64 + (((4 + t4) ^ (kr1 & 7)) * 8)];
            s1 = __builtin_amdgcn_mfma_f32_16x16x32_bf16(qf1, kf, s1, 0, 0, 0);
            kf = *(const short8*)&Kl[kr2 * 64 + ((t4 ^ (kr2 & 7)) * 8)];
            s2 = __builtin_amdgcn_mfma_f32_16x16x32_bf16(qf0, kf, s2, 0, 0, 0);
            kf = *(const short8*)&Kl[kr2 * 64 + (((4 + t4) ^ (kr2 & 7)) * 8)];
            s2 = __builtin_amdgcn_mfma_f32_16x16x32_bf16(qf1, kf, s2, 0, 0, 0);
            kf = *(const short8*)&Kl[kr3 * 64 + ((t4 ^ (kr3 & 7)) * 8)];
            s3 = __builtin_amdgcn_mfma_f32_16x16x32_bf16(qf0, kf, s3, 0, 0, 0);
            kf = *(const short8*)&Kl[kr3 * 64 + (((4 + t4) ^ (kr3 & 7)) * 8)];
            s3 = __builtin_amdgcn_mfma_f32_16x16x32_bf16(qf1, kf, s3, 0, 0, 0);
        }

        if (jt == 8) {
            #pragma unroll
            for (int r = 0; r < 4; r++) {
                if (c >= 8) s0[r] = -1e30f;
                s1[r] = -1e30f; s2[r] = -1e30f; s3[r] = -1e30f;
            }
        }

        // ---- online softmax (rows q = t4*4 + r; 16-lane row groups)
        #pragma unroll
        for (int r = 0; r < 4; r++) {
            float mx = fmaxf(fmaxf(s0[r], s1[r]), fmaxf(s2[r], s3[r]));
            mx = fmaxf(mx, __shfl_xor(mx, 1));
            mx = fmaxf(mx, __shfl_xor(mx, 2));
            mx = fmaxf(mx, __shfl_xor(mx, 4));
            mx = fmaxf(mx, __shfl_xor(mx, 8));
            float mn = fmaxf(mrow[r], mx);
            float sc = __expf(mrow[r] - mn);
            mrow[r] = mn;
            float p0 = __expf(s0[r] - mn), p1 = __expf(s1[r] - mn);
            float p2 = __expf(s2[r] - mn), p3 = __expf(s3[r] - mn);
            float rs = p0 + p1 + p2 + p3;
            rs += __shfl_xor(rs, 1);
            rs += __shfl_xor(rs, 2);
            rs += __shfl_xor(rs, 4);
            rs += __shfl_xor(rs, 8);
            lrow[r] = lrow[r] * sc + rs;
            o0[r] *= sc; o1[r] *= sc; o2[r] *= sc; o3[r] *= sc;
            int q = t4 * 4 + r;
            sP[w][q][c]      = (short)f2bf(p0);
            sP[w][q][16 + c] = (short)f2bf(p1);
            sP[w][q][32 + c] = (short)f2bf(p2);
            sP[w][q][48 + c] = (short)f2bf(p3);
        }

        // ---- PV: O += P[16 q][64 j] * V[64 j][64 d]
        {
            short8 pf0 = *(const short8*)&sP[w][c][t4 * 8];
            short8 pf1 = *(const short8*)&sP[w][c][32 + t4 * 8];
            int vr0 = 0 * 16 + c, vr1 = 16 + c, vr2 = 32 + c, vr3 = 48 + c;
            short8 vf;
            vf = *(const short8*)&Vl[vr0 * 64 + ((t4 ^ (vr0 & 7)) * 8)];
            o0 = __builtin_amdgcn_mfma_f32_16x16x32_bf16(pf0, vf, o0, 0, 0, 0);
            vf = *(const short8*)&Vl[vr0 * 64 + (((4 + t4) ^ (vr0 & 7)) * 8)];
            o0 = __builtin_amdgcn_mfma_f32_16x16x32_bf16(pf1, vf, o0, 0, 0, 0);
            vf = *(const short8*)&Vl[vr1 * 64 + ((t4 ^ (vr1 & 7)) * 8)];
            o1 = __builtin_amdgcn_mfma_f32_16x16x32_bf16(pf0, vf, o1, 0, 0, 0);
            vf = *(const short8*)&Vl[vr1 * 64 + (((4 + t4) ^ (vr1 & 7)) * 8)];
            o1 = __builtin_amdgcn_mfma_f32_16x16x32_bf16(pf1, vf, o1, 0, 0, 0);
            vf = *(const short8*)&Vl[vr2 * 64 + ((t4 ^ (vr2 & 7)) * 8)];
            o2 = __builtin_amdgcn_mfma_f32_16x16x32_bf16(pf0, vf, o2, 0, 0, 0);
            vf = *(const short8*)&Vl[vr2 * 64 + (((4 + t4) ^ (vr2 & 7)) * 8)];
            o2 = __builtin_amdgcn_mfma_f32_16x16x32_bf16(pf1, vf, o2, 0, 0, 0);
            vf = *(const short8*)&Vl[vr3 * 64 + ((t4 ^ (vr3 & 7)) * 8)];
            o3 = __builtin_amdgcn_mfma_f32_16x16x32_bf16(pf0, vf, o3, 0, 0, 0);
            vf = *(const short8*)&Vl[vr3 * 64 + (((4 + t4) ^ (vr3 & 7)) * 8)];
            o3 = __builtin_amdgcn_mfma_f32_16x16x32_bf16(pf1, vf, o3, 0, 0, 0);
        }
        __syncthreads();
    }

    #pragma unroll
    for (int r = 0; r < 4; r++) {
        int q = q0 + t4 * 4 + r;
        if (q < SEQ) {
            float inv = 1.f / lrow[r];
            short* ao = aob + ((size_t)(b * SEQ + q)) * DIM + h * 64 + c;
            ao[0]  = (short)f2bf(o0[r] * inv);
            ao[16] = (short)f2bf(o1[r] * inv);
            ao[32] = (short)f2bf(o2[r] * inv);
            ao[48] = (short)f2bf(o3[r] * inv);
        }
    }
}

// ---------------------------------------------------------------------------
// Residual + LayerNorm
// ---------------------------------------------------------------------------
__global__ __launch_bounds__(64) void k_ln(float* __restrict__ hf,
                                           const float* __restrict__ delta,
                                           const float* __restrict__ g,
                                           const float* __restrict__ bta,
                                           short* __restrict__ hb) {
    int row = blockIdx.x, l = threadIdx.x;
    size_t base = (size_t)row * DIM;
    float4 a0 = *(const float4*)&hf[base + l * 4];
    float4 a1 = *(const float4*)&hf[base + 256 + l * 4];
    float4 d0 = *(const float4*)&delta[base + l * 4];
    float4 d1 = *(const float4*)&delta[base + 256 + l * 4];
    a0.x += d0.x; a0.y += d0.y; a0.z += d0.z; a0.w += d0.w;
    a1.x += d1.x; a1.y += d1.y; a1.z += d1.z; a1.w += d1.w;
    float s1 = a0.x + a0.y + a0.z + a0.w + a1.x + a1.y + a1.z + a1.w;
    float s2 = a0.x * a0.x + a0.y * a0.y + a0.z * a0.z + a0.w * a0.w +
               a1.x * a1.x + a1.y * a1.y + a1.z * a1.z + a1.w * a1.w;
    s1 = wred_sum(s1);
    s2 = wred_sum(s2);
    float mu = s1 * (1.f / 512.f);
    float var = s2 * (1.f / 512.f) - mu * mu;
    float rr = rsqrtf(var + 1e-6f);
    float4 g0 = *(const float4*)&g[l * 4];
    float4 g1 = *(const float4*)&g[256 + l * 4];
    float4 b0 = *(const float4*)&bta[l * 4];
    float4 b1 = *(const float4*)&bta[256 + l * 4];
    float4 y0, y1;
    y0.x = (a0.x - mu) * rr * g0.x + b0.x;
    y0.y = (a0.y - mu) * rr * g0.y + b0.y;
    y0.z = (a0.z - mu) * rr * g0.z + b0.z;
    y0.w = (a0.w - mu) * rr * g0.w + b0.w;
    y1.x = (a1.x - mu) * rr * g1.x + b1.x;
    y1.y = (a1.y - mu) * rr * g1.y + b1.y;
    y1.z = (a1.z - mu) * rr * g1.z + b1.z;
    y1.w = (a1.w - mu) * rr * g1.w + b1.w;
    *(float4*)&hf[base + l * 4] = y0;
    *(float4*)&hf[base + 256 + l * 4] = y1;
    short4v h0, h1;
    h0[0] = (short)f2bf(y0.x); h0[1] = (short)f2bf(y0.y);
    h0[2] = (short)f2bf(y0.z); h0[3] = (short)f2bf(y0.w);
    h1[0] = (short)f2bf(y1.x); h1[1] = (short)f2bf(y1.y);
    h1[2] = (short)f2bf(y1.z); h1[3] = (short)f2bf(y1.w);
    *(short4v*)&hb[base + l * 4] = h0;
    *(short4v*)&hb[base + 256 + l * 4] = h1;
}

// ---------------------------------------------------------------------------
// Head hidden
// ---------------------------------------------------------------------------
__global__ __launch_bounds__(256) void k_hid(const float* __restrict__ hf,
                                             const float* __restrict__ Wh,
                                             const float* __restrict__ bh,
                                             float* __restrict__ hid) {
    int j = blockIdx.x * 256 + threadIdx.x;
    int o = blockIdx.y, b = blockIdx.z;
    const float* xr = hf + ((size_t)(b * SEQ + o)) * DIM;
    const float* wcol = Wh + (size_t)o * DIM * DIM + j;
    float acc = bh[o * DIM + j];
    #pragma unroll 8
    for (int d = 0; d < DIM; d++) acc = fmaf(xr[d], wcol[(size_t)d * DIM], acc);
    hid[((size_t)b * 8 + o) * DIM + j] = fmaxf(acc, 0.f);
}

// ---------------------------------------------------------------------------
// Variational heads
// ---------------------------------------------------------------------------
__device__ __forceinline__ float softplus_f(float x) { return log1pf(expf(x)); }

__global__ __launch_bounds__(64) void k_var(const float* __restrict__ hid,
                                            const float* __restrict__ mu_wmu,
                                            const float* __restrict__ mu_wrho,
                                            const float* __restrict__ mu_bmu,
                                            const float* __restrict__ mu_brho,
                                            const float* __restrict__ lv_wmu,
                                            const float* __restrict__ lv_wrho,
                                            const float* __restrict__ lv_bmu,
                                            const float* __restrict__ lv_brho,
                                            const float* __restrict__ eps_mu_w,
                                            const float* __restrict__ eps_mu_b,
                                            const float* __restrict__ eps_lv_w,
                                            const float* __restrict__ eps_lv_b,
                                            float* __restrict__ out) {
    const float EPS = 1e-8f;
    int bo = blockIdx.x;
    int o = bo & 7;
    int l = threadIdx.x;
    float am = 0.f, al = 0.f;
    #pragma unroll
    for (int k = 0; k < 8; k++) {
        int d = k * 64 + l;
        int od = o * DIM + d;
        float hv = hid[(size_t)bo * DIM + d];
        am = fmaf(hv, mu_wmu[od] + (softplus_f(mu_wrho[od]) + EPS) * eps_mu_w[od], am);
        al = fmaf(hv, lv_wmu[od] + (softplus_f(lv_wrho[od]) + EPS) * eps_lv_w[od], al);
    }
    am = wred_sum(am);
    al = wred_sum(al);
    if (l == 0) {
        float mu = am + mu_bmu[o] + (softplus_f(mu_brho[o]) + EPS) * eps_mu_b[o];
        out[bo] = mu;
        float lvv = al + lv_bmu[o] + (softplus_f(lv_brho[o]) + EPS) * eps_lv_b[o];
        out[256 + bo] = logf(EPS + softplus_f(lvv));
    }
}

// ---------------------------------------------------------------------------
extern "C" void kernel_launch(void* const* d_in, const int* in_sizes, int n_in,
                              void* d_out, int out_size, void* d_ws, size_t ws_size,
                              hipStream_t stream) {
    const float* x      = (const float*)d_in[0];
    const float* W_in   = (const float*)d_in[1];
    const float* b_in   = (const float*)d_in[2];
    const float* cls    = (const float*)d_in[3];
    const float* Wqkv   = (const float*)d_in[4];
    const float* bqkv   = (const float*)d_in[5];
    const float* Wo     = (const float*)d_in[6];
    const float* bo     = (const float*)d_in[7];
    const float* ln1_g  = (const float*)d_in[8];
    const float* ln1_b  = (const float*)d_in[9];
    const float* Wm1    = (const float*)d_in[10];
    const float* bm1    = (const float*)d_in[11];
    const float* Wm2    = (const float*)d_in[12];
    const float* bm2    = (const float*)d_in[13];
    const float* ln2_g  = (const float*)d_in[14];
    const float* ln2_b  = (const float*)d_in[15];
    const float* Wh     = (const float*)d_in[16];
    const float* bh     = (const float*)d_in[17];
    const float* mu_wmu = (const float*)d_in[18];
    const float* mu_wrho= (const float*)d_in[19];
    const float* mu_bmu = (const float*)d_in[20];
    const float* mu_brho= (const float*)d_in[21];
    const float* lv_wmu = (const float*)d_in[22];
    const float* lv_wrho= (const float*)d_in[23];
    const float* lv_bmu = (const float*)d_in[24];
    const float* lv_brho= (const float*)d_in[25];
    const float* e_mu_w = (const float*)d_in[26];
    const float* e_mu_b = (const float*)d_in[27];
    const float* e_lv_w = (const float*)d_in[28];
    const float* e_lv_b = (const float*)d_in[29];
    float* out = (float*)d_out;

    // ---- workspace layout; qkv+kbuf+vtbuf union'd with MLP mid buffer ----
    char* p = (char*)d_ws;
    auto alloc = [&](size_t bytes) {
        char* r = p;
        p += (bytes + 255) & ~(size_t)255;
        return r;
    };
    const size_t qkv_bytes = (size_t)NROW * 1536 * 2;              // 51.1 MB
    const size_t kbuf_bytes = (size_t)BATCH * NHEAD * SP * 64 * 2; // 18.9 MB
    const size_t attn_bytes = qkv_bytes + 2 * kbuf_bytes + 512;
    const size_t mid_bytes = (size_t)NROW * MLPD * 2;              // 68.2 MB
    float*  hf    = (float*) alloc((size_t)NROW * DIM * 4);
    float*  delta = (float*) alloc((size_t)NROW * DIM * 4);
    char*   U1    =          alloc(attn_bytes > mid_bytes ? attn_bytes : mid_bytes);
    short*  qkv   = (short*)U1;
    short*  kbuf  = (short*)(U1 + ((qkv_bytes + 255) & ~(size_t)255));
    short*  vtbuf = kbuf + kbuf_bytes / 2;
    short*  mid   = (short*)U1;              // aliases qkv region (disjoint lifetime)
    short*  hb    = (short*) alloc((size_t)NROW * DIM * 2);
    short*  aob   = (short*) alloc((size_t)NROW * DIM * 2);
    short*  wqkvt = (short*) alloc((size_t)NLAYER * 1536 * 512 * 2);
    short*  wot   = (short*) alloc((size_t)NLAYER * 512 * 512 * 2);
    short*  wm1t  = (short*) alloc((size_t)NLAYER * 2048 * 512 * 2);
    short*  wm2t  = (short*) alloc((size_t)NLAYER * 512 * 2048 * 2);
    float2* ropet = (float2*)alloc((size_t)SEQ * NPAIR * 8);
    float*  hid   = (float*) alloc((size_t)256 * DIM * 4);

    k_wconv<<<dim3(24, 8, 4), 256, 0, stream>>>(Wqkv, wqkvt, 512, 1536);
    k_wconv<<<dim3(8, 8, 4),  256, 0, stream>>>(Wo,   wot,   512, 512);
    k_wconv<<<dim3(32, 8, 4), 256, 0, stream>>>(Wm1,  wm1t,  512, 2048);
    k_wconv<<<dim3(8, 32, 4), 256, 0, stream>>>(Wm2,  wm2t,  2048, 512);
    k_rope_tab<<<SEQ, NPAIR, 0, stream>>>(ropet);
    k_in_proj<<<NROW, 256, 0, stream>>>(x, W_in, b_in, cls, hf, hb);

    const int RT = NROW / 128;   // 130 row tiles
    for (int l = 0; l < NLAYER; l++) {
        k_gemm<false, true><<<RT * 12, 256, 0, stream>>>(
            hb, wqkvt + (size_t)l * 1536 * 512, bqkv + l * 1536, qkv, 1536, 512);
        k_rope_q<<<NROW, NPAIR, 0, stream>>>(qkv, ropet);
        k_kvprep<<<BATCH * NHEAD * 9, 256, 0, stream>>>(qkv, ropet, kbuf, vtbuf);
        k_attn_mfma<<<9 * 256, 256, 0, stream>>>(qkv, kbuf, vtbuf, aob);
        k_gemm<false, false><<<RT * 4, 256, 0, stream>>>(
            aob, wot + (size_t)l * 512 * 512, bo + l * 512, delta, 512, 512);
        k_ln<<<NROW, 64, 0, stream>>>(hf, delta, ln1_g + l * 512, ln1_b + l * 512, hb);
        k_gemm<true, true><<<RT * 16, 256, 0, stream>>>(
            hb, wm1t + (size_t)l * 2048 * 512, bm1 + l * 2048, mid, 2048, 512);
        k_gemm<false, false><<<RT * 4, 256, 0, stream>>>(
            mid, wm2t + (size_t)l * 512 * 2048, bm2 + l * 512, delta, 512, 2048);
        k_ln<<<NROW, 64, 0, stream>>>(hf, delta, ln2_g + l * 512, ln2_b + l * 512, hb);
    }

    k_hid<<<dim3(2, 8, 32), 256, 0, stream>>>(hf, Wh, bh, hid);
    k_var<<<256, 64, 0, stream>>>(hid, mu_wmu, mu_wrho, mu_bmu, mu_brho,
                                  lv_wmu, lv_wrho, lv_bmu, lv_brho,
                                  e_mu_w, e_mu_b, e_lv_w, e_lv_b, out);
}

// Round 5
// 1231.581 us; speedup vs baseline: 4.3207x; 1.1457x over previous
//
#include <hip/hip_runtime.h>
#include <cstdint>

// ---------------------------------------------------------------------------
// QRoPETRegressor: 4-layer transformer (B=32, S=520 w/ 8 cls, D=512, NH=8,
// HD=64, MLP=2048) + variational heads.
// R5: 2-phase prefetch GEMM (dbuf LDS, 1 barrier/K-step), pipelined attn,
//     rope fused into attn Q-load, bf16 residual stream.
// ---------------------------------------------------------------------------

#define BATCH   32
#define SEQ     520
#define SP      576
#define DIM     512
#define NHEAD   8
#define HDIM    64
#define MLPD    2048
#define NLAYER  4
#define NROW    (BATCH * SEQ)   // 16640
#define NPAIR   256

typedef __attribute__((ext_vector_type(4))) float  f32x4;
typedef __attribute__((ext_vector_type(8))) short  short8;

__device__ __forceinline__ unsigned short f2bf(float f) {
    unsigned u = __float_as_uint(f);
    unsigned r = (u + 0x7fffu + ((u >> 16) & 1u)) >> 16;
    return (unsigned short)r;
}
__device__ __forceinline__ float bf2f(short s) {
    return __uint_as_float(((unsigned)(unsigned short)s) << 16);
}
__device__ __forceinline__ float wred_sum(float v) {
    #pragma unroll
    for (int off = 32; off; off >>= 1) v += __shfl_xor(v, off);
    return v;
}

__device__ __forceinline__ void gload16(const void* g, void* l) {
    __builtin_amdgcn_global_load_lds(
        (const __attribute__((address_space(1))) unsigned int*)g,
        (__attribute__((address_space(3))) unsigned int*)l,
        16, 0, 0);
}

// ---------------------------------------------------------------------------
// Weight transpose-convert: src fp32 (K,N) -> dst bf16 (N,K)
// ---------------------------------------------------------------------------
__global__ __launch_bounds__(256) void k_wconv(const float* __restrict__ src,
                                               short* __restrict__ dst,
                                               int K, int N) {
    src += (size_t)blockIdx.z * K * N;
    dst += (size_t)blockIdx.z * K * N;
    int n0 = blockIdx.x * 64, k0 = blockIdx.y * 64;
    __shared__ float t[64][65];
    int tid = threadIdx.x;
    int r = tid >> 2, cq = (tid & 3) * 16;
    const float* sp = src + (size_t)(k0 + r) * N + n0 + cq;
    #pragma unroll
    for (int e = 0; e < 16; e += 4) {
        float4 v = *(const float4*)(sp + e);
        t[r][cq + e] = v.x; t[r][cq + e + 1] = v.y;
        t[r][cq + e + 2] = v.z; t[r][cq + e + 3] = v.w;
    }
    __syncthreads();
    int n = tid >> 2, kq = (tid & 3) * 16;
    short* dp = dst + (size_t)(n0 + n) * K + k0 + kq;
    short8 o0, o1;
    #pragma unroll
    for (int e = 0; e < 8; e++) o0[e] = (short)f2bf(t[kq + e][n]);
    #pragma unroll
    for (int e = 0; e < 8; e++) o1[e] = (short)f2bf(t[kq + 8 + e][n]);
    *(short8*)dp = o0;
    *(short8*)(dp + 8) = o1;
}

// ---------------------------------------------------------------------------
__global__ void k_rope_tab(float2* __restrict__ tab) {
    int s = blockIdx.x, i = threadIdx.x;
    float fr = powf(10000.f, -2.f * (float)i / 512.f);
    float th = (float)s * fr;
    float sn, cn;
    sincosf(th, &sn, &cn);
    tab[s * NPAIR + i] = make_float2(cn, sn);
}

// ---------------------------------------------------------------------------
// Input proj + cls concat -> bf16 h
// ---------------------------------------------------------------------------
__global__ __launch_bounds__(256) void k_in_proj(const float* __restrict__ x,
                                                 const float* __restrict__ Wi,
                                                 const float* __restrict__ bi,
                                                 const float* __restrict__ cls,
                                                 short* __restrict__ hb) {
    int row = blockIdx.x;
    int b = row / SEQ, s = row % SEQ;
    bool is_cls = s < 8;
    float xr[16];
    if (!is_cls) {
        const float* xp = x + (size_t)(b * 512 + (s - 8)) * 16;
        #pragma unroll
        for (int f = 0; f < 16; f++) xr[f] = xp[f];
    }
    for (int c = threadIdx.x; c < DIM; c += 256) {
        float v;
        if (is_cls) {
            v = cls[s * DIM + c];
        } else {
            v = bi[c];
            #pragma unroll
            for (int f = 0; f < 16; f++) v = fmaf(xr[f], Wi[f * DIM + c], v);
        }
        hb[(size_t)row * DIM + c] = (short)f2bf(v);
    }
}

// ---------------------------------------------------------------------------
// GEMM: C[M,N](bf16) = act(A[M,K] @ W[K,N] + bias), A bf16 [M][K], Bt [N][K].
// 128x128 tile, templated BK (32/64), double-buffered LDS with 2-phase
// prefetch: STAGE(t+1) -> compute(t) -> __syncthreads (drains prefetch AFTER
// compute).  XOR-swizzled LDS, XCD-chunked tile order.
// ---------------------------------------------------------------------------
template <int BK, bool RELU>
__global__ __launch_bounds__(256) void k_gemm(const short* __restrict__ A,
                                              const short* __restrict__ Bt,
                                              const float* __restrict__ bias,
                                              short* __restrict__ Cout,
                                              int N, int K) {
    constexpr int NB  = BK / 8;                 // 16B blocks per row
    constexpr int MSK = NB - 1;
    constexpr int RPG = 1024 / (BK * 2);        // rows covered per gload16
    constexpr int GPW = 32 / RPG;               // gloads per wave per matrix
    __shared__ __align__(16) short As[2][128 * BK];
    __shared__ __align__(16) short Bs[2][128 * BK];
    const int tid = threadIdx.x;
    const int w = tid >> 6, l = tid & 63;

    const int chunk = gridDim.x >> 3;
    const int t = (blockIdx.x & 7) * chunk + (blockIdx.x >> 3);
    const int C = N >> 7;
    const int brow = (t / C) * 128, bcol = (t % C) * 128;

    const int srow = l / NB;                    // staged row within group
    const int sblk = l & MSK;
    const int soff = ((sblk ^ (srow & MSK)) * 8);
    const int fr = l & 15, t4 = l >> 4;
    const int wr = (w >> 1) * 64, wc = (w & 1) * 64;

    const short* Ab = A  + (size_t)(brow + w * 32 + srow) * K + soff;
    const short* Bb = Bt + (size_t)(bcol + w * 32 + srow) * K + soff;

    f32x4 acc[4][4];
    #pragma unroll
    for (int m = 0; m < 4; m++)
        #pragma unroll
        for (int n = 0; n < 4; n++) acc[m][n] = (f32x4){0.f, 0.f, 0.f, 0.f};

    auto stage = [&](int ko, int pb) {
        #pragma unroll
        for (int i = 0; i < GPW; i++)
            gload16(Ab + (size_t)(i * RPG) * K + ko,
                    &As[pb][(w * 32 + i * RPG) * BK]);
        #pragma unroll
        for (int i = 0; i < GPW; i++)
            gload16(Bb + (size_t)(i * RPG) * K + ko,
                    &Bs[pb][(w * 32 + i * RPG) * BK]);
    };

    const int nk = K / BK;
    stage(0, 0);
    __syncthreads();

    for (int kt = 0; kt < nk; ++kt) {
        const int cur = kt & 1;
        if (kt + 1 < nk) stage((kt + 1) * BK, cur ^ 1);
        __builtin_amdgcn_sched_barrier(0);   // keep prefetch issue first

        short8 af[4][BK / 32], bf[4][BK / 32];
        #pragma unroll
        for (int m = 0; m < 4; m++) {
            int r = wr + m * 16 + fr;
            #pragma unroll
            for (int kk = 0; kk < BK / 32; kk++)
                af[m][kk] = *(const short8*)
                    &As[cur][r * BK + (((kk * 4 + t4) ^ (r & MSK)) * 8)];
        }
        #pragma unroll
        for (int n = 0; n < 4; n++) {
            int r = wc + n * 16 + fr;
            #pragma unroll
            for (int kk = 0; kk < BK / 32; kk++)
                bf[n][kk] = *(const short8*)
                    &Bs[cur][r * BK + (((kk * 4 + t4) ^ (r & MSK)) * 8)];
        }
        #pragma unroll
        for (int kk = 0; kk < BK / 32; kk++)
            #pragma unroll
            for (int m = 0; m < 4; m++)
                #pragma unroll
                for (int n = 0; n < 4; n++)
                    acc[m][n] = __builtin_amdgcn_mfma_f32_16x16x32_bf16(
                        af[m][kk], bf[n][kk], acc[m][n], 0, 0, 0);
        __syncthreads();                     // drains prefetch (vmcnt 0) late
    }

    const int r0 = (l >> 4) * 4, c0 = l & 15;
    #pragma unroll
    for (int m = 0; m < 4; m++) {
        #pragma unroll
        for (int n = 0; n < 4; n++) {
            int col = bcol + wc + n * 16 + c0;
            float bv = bias[col];
            #pragma unroll
            for (int q = 0; q < 4; q++) {
                int row = brow + wr + m * 16 + r0 + q;
                float v = acc[m][n][q] + bv;
                if (RELU) v = fmaxf(v, 0.f);
                Cout[(size_t)row * N + col] = (short)f2bf(v);
            }
        }
    }
}

// ---------------------------------------------------------------------------
// K/V prep: rope K -> kbuf[bh][SP][64]; transpose V -> vtbuf[bh][64][SP].
// ---------------------------------------------------------------------------
__global__ __launch_bounds__(256) void k_kvprep(const short* __restrict__ qkv,
                                                const float2* __restrict__ tab,
                                                short* __restrict__ kbuf,
                                                short* __restrict__ vtbuf) {
    int bx = blockIdx.x;
    int jt = bx % 9, bh = bx / 9, b = bh >> 3, h = bh & 7;
    int tid = threadIdx.x;
    int row = tid >> 2, ch = tid & 3;
    int s = jt * 64 + row;
    bool valid = s < SEQ;
    size_t g = (size_t)(b * SEQ + (valid ? s : 0)) * 1536;

    short8 ok0 = (short8)0, ok1 = (short8)0;
    if (valid) {
        short8 k0 = *(const short8*)(qkv + g + 512 + h * 64 + ch * 16);
        short8 k1 = *(const short8*)(qkv + g + 512 + h * 64 + ch * 16 + 8);
        #pragma unroll
        for (int pp = 0; pp < 4; pp++) {
            float2 cs = tab[s * NPAIR + h * 32 + ch * 8 + pp];
            float x1 = bf2f(k0[2 * pp]), x2 = bf2f(k0[2 * pp + 1]);
            ok0[2 * pp]     = (short)f2bf(x1 * cs.x - x2 * cs.y);
            ok0[2 * pp + 1] = (short)f2bf(x1 * cs.y + x2 * cs.x);
            cs = tab[s * NPAIR + h * 32 + ch * 8 + 4 + pp];
            x1 = bf2f(k1[2 * pp]); x2 = bf2f(k1[2 * pp + 1]);
            ok1[2 * pp]     = (short)f2bf(x1 * cs.x - x2 * cs.y);
            ok1[2 * pp + 1] = (short)f2bf(x1 * cs.y + x2 * cs.x);
        }
    }
    short* kd = kbuf + ((size_t)bh * SP + jt * 64 + row) * 64 + ch * 16;
    *(short8*)kd = ok0;
    *(short8*)(kd + 8) = ok1;

    __shared__ short vt[64][72];
    short8 v0 = (short8)0, v1 = (short8)0;
    if (valid) {
        v0 = *(const short8*)(qkv + g + 1024 + h * 64 + ch * 16);
        v1 = *(const short8*)(qkv + g + 1024 + h * 64 + ch * 16 + 8);
    }
    *(short8*)&vt[row][ch * 16] = v0;
    *(short8*)&vt[row][ch * 16 + 8] = v1;
    __syncthreads();
    int d = row;
    short8 w0, w1;
    #pragma unroll
    for (int e = 0; e < 8; e++) w0[e] = vt[ch * 16 + e][d];
    #pragma unroll
    for (int e = 0; e < 8; e++) w1[e] = vt[ch * 16 + 8 + e][d];
    short* vd = vtbuf + ((size_t)bh * 64 + d) * SP + jt * 64 + ch * 16;
    *(short8*)vd = w0;
    *(short8*)(vd + 8) = w1;
}

// ---------------------------------------------------------------------------
// MFMA flash attention, 2-phase pipelined K/V staging, rope fused on Q.
// grid: bx = qt*256 + bh
// ---------------------------------------------------------------------------
__global__ __launch_bounds__(256) void k_attn_mfma(const short* __restrict__ qkv,
                                                   const short* __restrict__ kbuf,
                                                   const short* __restrict__ vtbuf,
                                                   const float2* __restrict__ tab,
                                                   short* __restrict__ aob) {
    __shared__ __align__(16) short Kl[2][64 * 64];
    __shared__ __align__(16) short Vl[2][64 * 64];
    __shared__ __align__(16) short sP[4][16][72];
    const int tid = threadIdx.x;
    const int w = tid >> 6, l = tid & 63;
    const int c = l & 15, t4 = l >> 4;
    int bx = blockIdx.x;
    int qt = bx >> 8, bh = bx & 255, b = bh >> 3, h = bh & 7;

    // ---- Q fragments with fused rope (+0.125 scale) ----
    int q0 = qt * 64 + w * 16;
    int qrow = q0 + c;
    int qr = qrow < SEQ ? qrow : SEQ - 1;
    size_t gq = (size_t)(b * SEQ + qr) * 1536 + h * 64;
    short8 qf0 = *(const short8*)(qkv + gq + t4 * 8);
    short8 qf1 = *(const short8*)(qkv + gq + 32 + t4 * 8);
    {
        const float2* tq = tab + (size_t)qr * NPAIR + h * 32;
        #pragma unroll
        for (int pp = 0; pp < 4; pp++) {
            float2 cs = tq[t4 * 4 + pp];
            float x1 = bf2f(qf0[2 * pp]), x2 = bf2f(qf0[2 * pp + 1]);
            qf0[2 * pp]     = (short)f2bf((x1 * cs.x - x2 * cs.y) * 0.125f);
            qf0[2 * pp + 1] = (short)f2bf((x1 * cs.y + x2 * cs.x) * 0.125f);
            cs = tq[16 + t4 * 4 + pp];
            x1 = bf2f(qf1[2 * pp]); x2 = bf2f(qf1[2 * pp + 1]);
            qf1[2 * pp]     = (short)f2bf((x1 * cs.x - x2 * cs.y) * 0.125f);
            qf1[2 * pp + 1] = (short)f2bf((x1 * cs.y + x2 * cs.x) * 0.125f);
        }
    }

    f32x4 o0 = {0,0,0,0}, o1 = {0,0,0,0}, o2 = {0,0,0,0}, o3 = {0,0,0,0};
    float mrow[4] = {-1e30f, -1e30f, -1e30f, -1e30f};
    float lrow[4] = {0.f, 0.f, 0.f, 0.f};

    const short* kb = kbuf + (size_t)bh * SP * 64;
    const short* vb = vtbuf + (size_t)bh * 64 * SP;
    const int r1 = w * 16 + (l >> 3);
    const int r2 = r1 + 8;
    const int blk = l & 7;

    auto stage = [&](int jt, int pb) {
        gload16(kb + ((size_t)(jt * 64 + r1)) * 64 + ((blk ^ (r1 & 7)) * 8),
                &Kl[pb][(w * 16) * 64]);
        gload16(kb + ((size_t)(jt * 64 + r2)) * 64 + ((blk ^ (r2 & 7)) * 8),
                &Kl[pb][(w * 16 + 8) * 64]);
        gload16(vb + (size_t)r1 * SP + jt * 64 + ((blk ^ (r1 & 7)) * 8),
                &Vl[pb][(w * 16) * 64]);
        gload16(vb + (size_t)r2 * SP + jt * 64 + ((blk ^ (r2 & 7)) * 8),
                &Vl[pb][(w * 16 + 8) * 64]);
    };

    stage(0, 0);
    __syncthreads();

    for (int jt = 0; jt < 9; jt++) {
        const int cur = jt & 1;
        if (jt + 1 < 9) stage(jt + 1, cur ^ 1);
        __builtin_amdgcn_sched_barrier(0);

        // ---- QK^T
        f32x4 s0 = {0,0,0,0}, s1 = {0,0,0,0}, s2 = {0,0,0,0}, s3 = {0,0,0,0};
        {
            int kr0 = c, kr1 = 16 + c, kr2 = 32 + c, kr3 = 48 + c;
            short8 kf;
            kf = *(const short8*)&Kl[cur][kr0 * 64 + ((t4 ^ (kr0 & 7)) * 8)];
            s0 = __builtin_amdgcn_mfma_f32_16x16x32_bf16(qf0, kf, s0, 0, 0, 0);
            kf = *(const short8*)&Kl[cur][kr0 * 64 + (((4 + t4) ^ (kr0 & 7)) * 8)];
            s0 = __builtin_amdgcn_mfma_f32_16x16x32_bf16(qf1, kf, s0, 0, 0, 0);
            kf = *(const short8*)&Kl[cur][kr1 * 64 + ((t4 ^ (kr1 & 7)) * 8)];
            s1 = __builtin_amdgcn_mfma_f32_16x16x32_bf16(qf0, kf, s1, 0, 0, 0);
            kf = *(const short8*)&Kl[cur][kr1 * 64 + (((4 + t4) ^ (kr1 & 7)) * 8)];
            s1 = __builtin_amdgcn_mfma_f32_16x16x32_bf16(qf1, kf, s1, 0, 0, 0);
            kf = *(const short8*)&Kl[cur][kr2 * 64 + ((t4 ^ (kr2 & 7)) * 8)];
            s2 = __builtin_amdgcn_mfma_f32_16x16x32_bf16(qf0, kf, s2, 0, 0, 0);
            kf = *(const short8*)&Kl[cur][kr2 * 64 + (((4 + t4) ^ (kr2 & 7)) * 8)];
            s2 = __builtin_amdgcn_mfma_f32_16x16x32_bf16(qf1, kf, s2, 0, 0, 0);
            kf = *(const short8*)&Kl[cur][kr3 * 64 + ((t4 ^ (kr3 & 7)) * 8)];
            s3 = __builtin_amdgcn_mfma_f32_16x16x32_bf16(qf0, kf, s3, 0, 0, 0);
            kf = *(const short8*)&Kl[cur][kr3 * 64 + (((4 + t4) ^ (kr3 & 7)) * 8)];
            s3 = __builtin_amdgcn_mfma_f32_16x16x32_bf16(qf1, kf, s3, 0, 0, 0);
        }

        if (jt == 8) {
            #pragma unroll
            for (int r = 0; r < 4; r++) {
                if (c >= 8) s0[r] = -1e30f;
                s1[r] = -1e30f; s2[r] = -1e30f; s3[r] = -1e30f;
            }
        }

        // ---- online softmax; rescale only when the running max grows
        #pragma unroll
        for (int r = 0; r < 4; r++) {
            float mx = fmaxf(fmaxf(s0[r], s1[r]), fmaxf(s2[r], s3[r]));
            mx = fmaxf(mx, __shfl_xor(mx, 1));
            mx = fmaxf(mx, __shfl_xor(mx, 2));
            mx = fmaxf(mx, __shfl_xor(mx, 4));
            mx = fmaxf(mx, __shfl_xor(mx, 8));
            if (mx > mrow[r]) {
                float sc = __expf(mrow[r] - mx);
                mrow[r] = mx;
                lrow[r] *= sc;
                o0[r] *= sc; o1[r] *= sc; o2[r] *= sc; o3[r] *= sc;
            }
            float p0 = __expf(s0[r] - mrow[r]), p1 = __expf(s1[r] - mrow[r]);
            float p2 = __expf(s2[r] - mrow[r]), p3 = __expf(s3[r] - mrow[r]);
            float rs = p0 + p1 + p2 + p3;
            rs += __shfl_xor(rs, 1);
            rs += __shfl_xor(rs, 2);
            rs += __shfl_xor(rs, 4);
            rs += __shfl_xor(rs, 8);
            lrow[r] += rs;
            int q = t4 * 4 + r;
            sP[w][q][c]      = (short)f2bf(p0);
            sP[w][q][16 + c] = (short)f2bf(p1);
            sP[w][q][32 + c] = (short)f2bf(p2);
            sP[w][q][48 + c] = (short)f2bf(p3);
        }

        // ---- PV
        {
            short8 pf0 = *(const short8*)&sP[w][c][t4 * 8];
            short8 pf1 = *(const short8*)&sP[w][c][32 + t4 * 8];
            int vr0 = c, vr1 = 16 + c, vr2 = 32 + c, vr3 = 48 + c;
            short8 vf;
            vf = *(const short8*)&Vl[cur][vr0 * 64 + ((t4 ^ (vr0 & 7)) * 8)];
            o0 = __builtin_amdgcn_mfma_f32_16x16x32_bf16(pf0, vf, o0, 0, 0, 0);
            vf = *(const short8*)&Vl[cur][vr0 * 64 + (((4 + t4) ^ (vr0 & 7)) * 8)];
            o0 = __builtin_amdgcn_mfma_f32_16x16x32_bf16(pf1, vf, o0, 0, 0, 0);
            vf = *(const short8*)&Vl[cur][vr1 * 64 + ((t4 ^ (vr1 & 7)) * 8)];
            o1 = __builtin_amdgcn_mfma_f32_16x16x32_bf16(pf0, vf, o1, 0, 0, 0);
            vf = *(const short8*)&Vl[cur][vr1 * 64 + (((4 + t4) ^ (vr1 & 7)) * 8)];
            o1 = __builtin_amdgcn_mfma_f32_16x16x32_bf16(pf1, vf, o1, 0, 0, 0);
            vf = *(const short8*)&Vl[cur][vr2 * 64 + ((t4 ^ (vr2 & 7)) * 8)];
            o2 = __builtin_amdgcn_mfma_f32_16x16x32_bf16(pf0, vf, o2, 0, 0, 0);
            vf = *(const short8*)&Vl[cur][vr2 * 64 + (((4 + t4) ^ (vr2 & 7)) * 8)];
            o2 = __builtin_amdgcn_mfma_f32_16x16x32_bf16(pf1, vf, o2, 0, 0, 0);
            vf = *(const short8*)&Vl[cur][vr3 * 64 + ((t4 ^ (vr3 & 7)) * 8)];
            o3 = __builtin_amdgcn_mfma_f32_16x16x32_bf16(pf0, vf, o3, 0, 0, 0);
            vf = *(const short8*)&Vl[cur][vr3 * 64 + (((4 + t4) ^ (vr3 & 7)) * 8)];
            o3 = __builtin_amdgcn_mfma_f32_16x16x32_bf16(pf1, vf, o3, 0, 0, 0);
        }
        __syncthreads();    // drains prefetched K/V after compute
    }

    #pragma unroll
    for (int r = 0; r < 4; r++) {
        int q = q0 + t4 * 4 + r;
        if (q < SEQ) {
            float inv = 1.f / lrow[r];
            short* ao = aob + ((size_t)(b * SEQ + q)) * DIM + h * 64 + c;
            ao[0]  = (short)f2bf(o0[r] * inv);
            ao[16] = (short)f2bf(o1[r] * inv);
            ao[32] = (short)f2bf(o2[r] * inv);
            ao[48] = (short)f2bf(o3[r] * inv);
        }
    }
}

// ---------------------------------------------------------------------------
// Residual + LayerNorm, bf16 in/out.  4 rows per block (one per wave).
// ---------------------------------------------------------------------------
__global__ __launch_bounds__(256) void k_ln(short* __restrict__ hb,
                                            const short* __restrict__ delta,
                                            const float* __restrict__ g,
                                            const float* __restrict__ bta) {
    int row = blockIdx.x * 4 + (threadIdx.x >> 6);
    int l = threadIdx.x & 63;
    size_t base = (size_t)row * DIM + l * 8;
    short8 hv = *(const short8*)&hb[base];
    short8 dv = *(const short8*)&delta[base];
    float a[8];
    float s1 = 0.f, s2 = 0.f;
    #pragma unroll
    for (int e = 0; e < 8; e++) {
        a[e] = bf2f(hv[e]) + bf2f(dv[e]);
        s1 += a[e];
        s2 += a[e] * a[e];
    }
    s1 = wred_sum(s1);
    s2 = wred_sum(s2);
    float mu = s1 * (1.f / 512.f);
    float rr = rsqrtf(s2 * (1.f / 512.f) - mu * mu + 1e-6f);
    float4 g0 = *(const float4*)&g[l * 8];
    float4 g1 = *(const float4*)&g[l * 8 + 4];
    float4 b0 = *(const float4*)&bta[l * 8];
    float4 b1 = *(const float4*)&bta[l * 8 + 4];
    short8 o;
    o[0] = (short)f2bf((a[0] - mu) * rr * g0.x + b0.x);
    o[1] = (short)f2bf((a[1] - mu) * rr * g0.y + b0.y);
    o[2] = (short)f2bf((a[2] - mu) * rr * g0.z + b0.z);
    o[3] = (short)f2bf((a[3] - mu) * rr * g0.w + b0.w);
    o[4] = (short)f2bf((a[4] - mu) * rr * g1.x + b1.x);
    o[5] = (short)f2bf((a[5] - mu) * rr * g1.y + b1.y);
    o[6] = (short)f2bf((a[6] - mu) * rr * g1.z + b1.z);
    o[7] = (short)f2bf((a[7] - mu) * rr * g1.w + b1.w);
    *(short8*)&hb[base] = o;
}

// ---------------------------------------------------------------------------
// Head hidden: hid[b,o,j] = relu(x_cls[b,o,:] @ Wh[o] + bh[o,j]),  x bf16
// ---------------------------------------------------------------------------
__global__ __launch_bounds__(256) void k_hid(const short* __restrict__ hb,
                                             const float* __restrict__ Wh,
                                             const float* __restrict__ bh,
                                             float* __restrict__ hid) {
    int j = blockIdx.x * 256 + threadIdx.x;
    int o = blockIdx.y, b = blockIdx.z;
    const short* xr = hb + ((size_t)(b * SEQ + o)) * DIM;
    const float* wcol = Wh + (size_t)o * DIM * DIM + j;
    float acc = bh[o * DIM + j];
    #pragma unroll 8
    for (int d = 0; d < DIM; d++)
        acc = fmaf(bf2f(xr[d]), wcol[(size_t)d * DIM], acc);
    hid[((size_t)b * 8 + o) * DIM + j] = fmaxf(acc, 0.f);
}

// ---------------------------------------------------------------------------
__device__ __forceinline__ float softplus_f(float x) { return log1pf(expf(x)); }

__global__ __launch_bounds__(64) void k_var(const float* __restrict__ hid,
                                            const float* __restrict__ mu_wmu,
                                            const float* __restrict__ mu_wrho,
                                            const float* __restrict__ mu_bmu,
                                            const float* __restrict__ mu_brho,
                                            const float* __restrict__ lv_wmu,
                                            const float* __restrict__ lv_wrho,
                                            const float* __restrict__ lv_bmu,
                                            const float* __restrict__ lv_brho,
                                            const float* __restrict__ eps_mu_w,
                                            const float* __restrict__ eps_mu_b,
                                            const float* __restrict__ eps_lv_w,
                                            const float* __restrict__ eps_lv_b,
                                            float* __restrict__ out) {
    const float EPS = 1e-8f;
    int bo = blockIdx.x;
    int o = bo & 7;
    int l = threadIdx.x;
    float am = 0.f, al = 0.f;
    #pragma unroll
    for (int k = 0; k < 8; k++) {
        int d = k * 64 + l;
        int od = o * DIM + d;
        float hv = hid[(size_t)bo * DIM + d];
        am = fmaf(hv, mu_wmu[od] + (softplus_f(mu_wrho[od]) + EPS) * eps_mu_w[od], am);
        al = fmaf(hv, lv_wmu[od] + (softplus_f(lv_wrho[od]) + EPS) * eps_lv_w[od], al);
    }
    am = wred_sum(am);
    al = wred_sum(al);
    if (l == 0) {
        float mu = am + mu_bmu[o] + (softplus_f(mu_brho[o]) + EPS) * eps_mu_b[o];
        out[bo] = mu;
        float lvv = al + lv_bmu[o] + (softplus_f(lv_brho[o]) + EPS) * eps_lv_b[o];
        out[256 + bo] = logf(EPS + softplus_f(lvv));
    }
}

// ---------------------------------------------------------------------------
extern "C" void kernel_launch(void* const* d_in, const int* in_sizes, int n_in,
                              void* d_out, int out_size, void* d_ws, size_t ws_size,
                              hipStream_t stream) {
    const float* x      = (const float*)d_in[0];
    const float* W_in   = (const float*)d_in[1];
    const float* b_in   = (const float*)d_in[2];
    const float* cls    = (const float*)d_in[3];
    const float* Wqkv   = (const float*)d_in[4];
    const float* bqkv   = (const float*)d_in[5];
    const float* Wo     = (const float*)d_in[6];
    const float* bo     = (const float*)d_in[7];
    const float* ln1_g  = (const float*)d_in[8];
    const float* ln1_b  = (const float*)d_in[9];
    const float* Wm1    = (const float*)d_in[10];
    const float* bm1    = (const float*)d_in[11];
    const float* Wm2    = (const float*)d_in[12];
    const float* bm2    = (const float*)d_in[13];
    const float* ln2_g  = (const float*)d_in[14];
    const float* ln2_b  = (const float*)d_in[15];
    const float* Wh     = (const float*)d_in[16];
    const float* bh     = (const float*)d_in[17];
    const float* mu_wmu = (const float*)d_in[18];
    const float* mu_wrho= (const float*)d_in[19];
    const float* mu_bmu = (const float*)d_in[20];
    const float* mu_brho= (const float*)d_in[21];
    const float* lv_wmu = (const float*)d_in[22];
    const float* lv_wrho= (const float*)d_in[23];
    const float* lv_bmu = (const float*)d_in[24];
    const float* lv_brho= (const float*)d_in[25];
    const float* e_mu_w = (const float*)d_in[26];
    const float* e_mu_b = (const float*)d_in[27];
    const float* e_lv_w = (const float*)d_in[28];
    const float* e_lv_b = (const float*)d_in[29];
    float* out = (float*)d_out;

    char* p = (char*)d_ws;
    auto alloc = [&](size_t bytes) {
        char* r = p;
        p += (bytes + 255) & ~(size_t)255;
        return r;
    };
    const size_t qkv_bytes = (size_t)NROW * 1536 * 2;
    const size_t kbuf_bytes = (size_t)BATCH * NHEAD * SP * 64 * 2;
    const size_t attn_bytes = qkv_bytes + 2 * kbuf_bytes + 512;
    const size_t mid_bytes = (size_t)NROW * MLPD * 2;
    char*   U1    =          alloc(attn_bytes > mid_bytes ? attn_bytes : mid_bytes);
    short*  qkv   = (short*)U1;
    short*  kbuf  = (short*)(U1 + ((qkv_bytes + 255) & ~(size_t)255));
    short*  vtbuf = kbuf + kbuf_bytes / 2;
    short*  mid   = (short*)U1;
    short*  hb    = (short*) alloc((size_t)NROW * DIM * 2);
    short*  deltab= (short*) alloc((size_t)NROW * DIM * 2);
    short*  aob   = (short*) alloc((size_t)NROW * DIM * 2);
    short*  wqkvt = (short*) alloc((size_t)NLAYER * 1536 * 512 * 2);
    short*  wot   = (short*) alloc((size_t)NLAYER * 512 * 512 * 2);
    short*  wm1t  = (short*) alloc((size_t)NLAYER * 2048 * 512 * 2);
    short*  wm2t  = (short*) alloc((size_t)NLAYER * 512 * 2048 * 2);
    float2* ropet = (float2*)alloc((size_t)SEQ * NPAIR * 8);
    float*  hid   = (float*) alloc((size_t)256 * DIM * 4);

    k_wconv<<<dim3(24, 8, 4), 256, 0, stream>>>(Wqkv, wqkvt, 512, 1536);
    k_wconv<<<dim3(8, 8, 4),  256, 0, stream>>>(Wo,   wot,   512, 512);
    k_wconv<<<dim3(32, 8, 4), 256, 0, stream>>>(Wm1,  wm1t,  512, 2048);
    k_wconv<<<dim3(8, 32, 4), 256, 0, stream>>>(Wm2,  wm2t,  2048, 512);
    k_rope_tab<<<SEQ, NPAIR, 0, stream>>>(ropet);
    k_in_proj<<<NROW, 256, 0, stream>>>(x, W_in, b_in, cls, hb);

    const int RT = NROW / 128;   // 130
    for (int l = 0; l < NLAYER; l++) {
        k_gemm<32, false><<<RT * 12, 256, 0, stream>>>(
            hb, wqkvt + (size_t)l * 1536 * 512, bqkv + l * 1536, qkv, 1536, 512);
        k_kvprep<<<BATCH * NHEAD * 9, 256, 0, stream>>>(qkv, ropet, kbuf, vtbuf);
        k_attn_mfma<<<9 * 256, 256, 0, stream>>>(qkv, kbuf, vtbuf, ropet, aob);
        k_gemm<64, false><<<RT * 4, 256, 0, stream>>>(
            aob, wot + (size_t)l * 512 * 512, bo + l * 512, deltab, 512, 512);
        k_ln<<<NROW / 4, 256, 0, stream>>>(hb, deltab, ln1_g + l * 512, ln1_b + l * 512);
        k_gemm<32, true><<<RT * 16, 256, 0, stream>>>(
            hb, wm1t + (size_t)l * 2048 * 512, bm1 + l * 2048, mid, 2048, 512);
        k_gemm<64, false><<<RT * 4, 256, 0, stream>>>(
            mid, wm2t + (size_t)l * 512 * 2048, bm2 + l * 512, deltab, 512, 2048);
        k_ln<<<NROW / 4, 256, 0, stream>>>(hb, deltab, ln2_g + l * 512, ln2_b + l * 512);
    }

    k_hid<<<dim3(2, 8, 32), 256, 0, stream>>>(hb, Wh, bh, hid);
    k_var<<<256, 64, 0, stream>>>(hid, mu_wmu, mu_wrho, mu_bmu, mu_brho,
                                  lv_wmu, lv_wrho, lv_bmu, lv_brho,
                                  e_mu_w, e_mu_b, e_lv_w, e_lv_b, out);
}

// Round 6
// 1157.135 us; speedup vs baseline: 4.5987x; 1.0643x over previous
//
#include <hip/hip_runtime.h>
#include <cstdint>

// ---------------------------------------------------------------------------
// QRoPETRegressor: 4-layer transformer (B=32, S=520 w/ 8 cls, D=512, NH=8,
// HD=64, MLP=2048) + variational heads.
// R6: attn softmax defer-max/defer-sum (T13), exp2 domain, cvt_pk_bf16 (T12),
//     setprio (T5), residual fused into GEMM epilogue.
// ---------------------------------------------------------------------------

#define BATCH   32
#define SEQ     520
#define SP      576
#define DIM     512
#define NHEAD   8
#define HDIM    64
#define MLPD    2048
#define NLAYER  4
#define NROW    (BATCH * SEQ)   // 16640
#define NPAIR   256

typedef __attribute__((ext_vector_type(4))) float  f32x4;
typedef __attribute__((ext_vector_type(8))) short  short8;

__device__ __forceinline__ unsigned short f2bf(float f) {
    unsigned u = __float_as_uint(f);
    unsigned r = (u + 0x7fffu + ((u >> 16) & 1u)) >> 16;
    return (unsigned short)r;
}
__device__ __forceinline__ float bf2f(short s) {
    return __uint_as_float(((unsigned)(unsigned short)s) << 16);
}
// packed fp32x2 -> bf16x2 (RNE), single instruction
__device__ __forceinline__ unsigned cvt_pk_bf16(float lo, float hi) {
    unsigned r;
    asm("v_cvt_pk_bf16_f32 %0, %1, %2" : "=v"(r) : "v"(lo), "v"(hi));
    return r;
}
// hardware 2^x
__device__ __forceinline__ float exp2_hw(float x) {
    float r;
    asm("v_exp_f32 %0, %1" : "=v"(r) : "v"(x));
    return r;
}
__device__ __forceinline__ float wred_sum(float v) {
    #pragma unroll
    for (int off = 32; off; off >>= 1) v += __shfl_xor(v, off);
    return v;
}

__device__ __forceinline__ void gload16(const void* g, void* l) {
    __builtin_amdgcn_global_load_lds(
        (const __attribute__((address_space(1))) unsigned int*)g,
        (__attribute__((address_space(3))) unsigned int*)l,
        16, 0, 0);
}

// ---------------------------------------------------------------------------
// Weight transpose-convert: src fp32 (K,N) -> dst bf16 (N,K)
// ---------------------------------------------------------------------------
__global__ __launch_bounds__(256) void k_wconv(const float* __restrict__ src,
                                               short* __restrict__ dst,
                                               int K, int N) {
    src += (size_t)blockIdx.z * K * N;
    dst += (size_t)blockIdx.z * K * N;
    int n0 = blockIdx.x * 64, k0 = blockIdx.y * 64;
    __shared__ float t[64][65];
    int tid = threadIdx.x;
    int r = tid >> 2, cq = (tid & 3) * 16;
    const float* sp = src + (size_t)(k0 + r) * N + n0 + cq;
    #pragma unroll
    for (int e = 0; e < 16; e += 4) {
        float4 v = *(const float4*)(sp + e);
        t[r][cq + e] = v.x; t[r][cq + e + 1] = v.y;
        t[r][cq + e + 2] = v.z; t[r][cq + e + 3] = v.w;
    }
    __syncthreads();
    int n = tid >> 2, kq = (tid & 3) * 16;
    short* dp = dst + (size_t)(n0 + n) * K + k0 + kq;
    unsigned o0[4], o1[4];
    #pragma unroll
    for (int e = 0; e < 4; e++)
        o0[e] = cvt_pk_bf16(t[kq + 2 * e][n], t[kq + 2 * e + 1][n]);
    #pragma unroll
    for (int e = 0; e < 4; e++)
        o1[e] = cvt_pk_bf16(t[kq + 8 + 2 * e][n], t[kq + 9 + 2 * e][n]);
    *(uint4*)dp = make_uint4(o0[0], o0[1], o0[2], o0[3]);
    *(uint4*)(dp + 8) = make_uint4(o1[0], o1[1], o1[2], o1[3]);
}

// ---------------------------------------------------------------------------
__global__ void k_rope_tab(float2* __restrict__ tab) {
    int s = blockIdx.x, i = threadIdx.x;
    float fr = powf(10000.f, -2.f * (float)i / 512.f);
    float th = (float)s * fr;
    float sn, cn;
    sincosf(th, &sn, &cn);
    tab[s * NPAIR + i] = make_float2(cn, sn);
}

// ---------------------------------------------------------------------------
// Input proj + cls concat -> bf16 h
// ---------------------------------------------------------------------------
__global__ __launch_bounds__(256) void k_in_proj(const float* __restrict__ x,
                                                 const float* __restrict__ Wi,
                                                 const float* __restrict__ bi,
                                                 const float* __restrict__ cls,
                                                 short* __restrict__ hb) {
    int row = blockIdx.x;
    int b = row / SEQ, s = row % SEQ;
    bool is_cls = s < 8;
    float xr[16];
    if (!is_cls) {
        const float* xp = x + (size_t)(b * 512 + (s - 8)) * 16;
        #pragma unroll
        for (int f = 0; f < 16; f++) xr[f] = xp[f];
    }
    for (int c = threadIdx.x; c < DIM; c += 256) {
        float v;
        if (is_cls) {
            v = cls[s * DIM + c];
        } else {
            v = bi[c];
            #pragma unroll
            for (int f = 0; f < 16; f++) v = fmaf(xr[f], Wi[f * DIM + c], v);
        }
        hb[(size_t)row * DIM + c] = (short)f2bf(v);
    }
}

// ---------------------------------------------------------------------------
// GEMM: C[M,N](bf16) = act(A @ W + bias [+ Res]), A bf16 [M][K], Bt [N][K].
// 128x128 tile, templated BK, dbuf LDS 2-phase prefetch, XOR-swizzle, XCD
// chunked tile order.  ADDRES fuses the residual add (bf16 Res read).
// ---------------------------------------------------------------------------
template <int BK, bool RELU, bool ADDRES>
__global__ __launch_bounds__(256) void k_gemm(const short* __restrict__ A,
                                              const short* __restrict__ Bt,
                                              const float* __restrict__ bias,
                                              const short* __restrict__ Res,
                                              short* __restrict__ Cout,
                                              int N, int K) {
    constexpr int NB  = BK / 8;
    constexpr int MSK = NB - 1;
    constexpr int RPG = 1024 / (BK * 2);
    constexpr int GPW = 32 / RPG;
    __shared__ __align__(16) short As[2][128 * BK];
    __shared__ __align__(16) short Bs[2][128 * BK];
    const int tid = threadIdx.x;
    const int w = tid >> 6, l = tid & 63;

    const int chunk = gridDim.x >> 3;
    const int t = (blockIdx.x & 7) * chunk + (blockIdx.x >> 3);
    const int C = N >> 7;
    const int brow = (t / C) * 128, bcol = (t % C) * 128;

    const int srow = l / NB;
    const int sblk = l & MSK;
    const int soff = ((sblk ^ (srow & MSK)) * 8);
    const int fr = l & 15, t4 = l >> 4;
    const int wr = (w >> 1) * 64, wc = (w & 1) * 64;

    const short* Ab = A  + (size_t)(brow + w * 32 + srow) * K + soff;
    const short* Bb = Bt + (size_t)(bcol + w * 32 + srow) * K + soff;

    f32x4 acc[4][4];
    #pragma unroll
    for (int m = 0; m < 4; m++)
        #pragma unroll
        for (int n = 0; n < 4; n++) acc[m][n] = (f32x4){0.f, 0.f, 0.f, 0.f};

    auto stage = [&](int ko, int pb) {
        #pragma unroll
        for (int i = 0; i < GPW; i++)
            gload16(Ab + (size_t)(i * RPG) * K + ko,
                    &As[pb][(w * 32 + i * RPG) * BK]);
        #pragma unroll
        for (int i = 0; i < GPW; i++)
            gload16(Bb + (size_t)(i * RPG) * K + ko,
                    &Bs[pb][(w * 32 + i * RPG) * BK]);
    };

    const int nk = K / BK;
    stage(0, 0);
    __syncthreads();

    for (int kt = 0; kt < nk; ++kt) {
        const int cur = kt & 1;
        if (kt + 1 < nk) stage((kt + 1) * BK, cur ^ 1);
        __builtin_amdgcn_sched_barrier(0);

        short8 af[4][BK / 32], bf[4][BK / 32];
        #pragma unroll
        for (int m = 0; m < 4; m++) {
            int r = wr + m * 16 + fr;
            #pragma unroll
            for (int kk = 0; kk < BK / 32; kk++)
                af[m][kk] = *(const short8*)
                    &As[cur][r * BK + (((kk * 4 + t4) ^ (r & MSK)) * 8)];
        }
        #pragma unroll
        for (int n = 0; n < 4; n++) {
            int r = wc + n * 16 + fr;
            #pragma unroll
            for (int kk = 0; kk < BK / 32; kk++)
                bf[n][kk] = *(const short8*)
                    &Bs[cur][r * BK + (((kk * 4 + t4) ^ (r & MSK)) * 8)];
        }
        #pragma unroll
        for (int kk = 0; kk < BK / 32; kk++)
            #pragma unroll
            for (int m = 0; m < 4; m++)
                #pragma unroll
                for (int n = 0; n < 4; n++)
                    acc[m][n] = __builtin_amdgcn_mfma_f32_16x16x32_bf16(
                        af[m][kk], bf[n][kk], acc[m][n], 0, 0, 0);
        __syncthreads();
    }

    const int r0 = (l >> 4) * 4, c0 = l & 15;
    #pragma unroll
    for (int m = 0; m < 4; m++) {
        #pragma unroll
        for (int n = 0; n < 4; n++) {
            int col = bcol + wc + n * 16 + c0;
            float bv = bias[col];
            #pragma unroll
            for (int q = 0; q < 4; q++) {
                int row = brow + wr + m * 16 + r0 + q;
                float v = acc[m][n][q] + bv;
                if (ADDRES) v += bf2f(Res[(size_t)row * N + col]);
                if (RELU) v = fmaxf(v, 0.f);
                Cout[(size_t)row * N + col] = (short)f2bf(v);
            }
        }
    }
}

// ---------------------------------------------------------------------------
// K/V prep: rope K -> kbuf[bh][SP][64]; transpose V -> vtbuf[bh][64][SP].
// ---------------------------------------------------------------------------
__global__ __launch_bounds__(256) void k_kvprep(const short* __restrict__ qkv,
                                                const float2* __restrict__ tab,
                                                short* __restrict__ kbuf,
                                                short* __restrict__ vtbuf) {
    int bx = blockIdx.x;
    int jt = bx % 9, bh = bx / 9, b = bh >> 3, h = bh & 7;
    int tid = threadIdx.x;
    int row = tid >> 2, ch = tid & 3;
    int s = jt * 64 + row;
    bool valid = s < SEQ;
    size_t g = (size_t)(b * SEQ + (valid ? s : 0)) * 1536;

    short8 ok0 = (short8)0, ok1 = (short8)0;
    if (valid) {
        short8 k0 = *(const short8*)(qkv + g + 512 + h * 64 + ch * 16);
        short8 k1 = *(const short8*)(qkv + g + 512 + h * 64 + ch * 16 + 8);
        unsigned* u0 = (unsigned*)&ok0;
        unsigned* u1 = (unsigned*)&ok1;
        #pragma unroll
        for (int pp = 0; pp < 4; pp++) {
            float2 cs = tab[s * NPAIR + h * 32 + ch * 8 + pp];
            float x1 = bf2f(k0[2 * pp]), x2 = bf2f(k0[2 * pp + 1]);
            u0[pp] = cvt_pk_bf16(x1 * cs.x - x2 * cs.y, x1 * cs.y + x2 * cs.x);
            cs = tab[s * NPAIR + h * 32 + ch * 8 + 4 + pp];
            x1 = bf2f(k1[2 * pp]); x2 = bf2f(k1[2 * pp + 1]);
            u1[pp] = cvt_pk_bf16(x1 * cs.x - x2 * cs.y, x1 * cs.y + x2 * cs.x);
        }
    }
    short* kd = kbuf + ((size_t)bh * SP + jt * 64 + row) * 64 + ch * 16;
    *(short8*)kd = ok0;
    *(short8*)(kd + 8) = ok1;

    __shared__ short vt[64][72];
    short8 v0 = (short8)0, v1 = (short8)0;
    if (valid) {
        v0 = *(const short8*)(qkv + g + 1024 + h * 64 + ch * 16);
        v1 = *(const short8*)(qkv + g + 1024 + h * 64 + ch * 16 + 8);
    }
    *(short8*)&vt[row][ch * 16] = v0;
    *(short8*)&vt[row][ch * 16 + 8] = v1;
    __syncthreads();
    int d = row;
    short8 w0, w1;
    #pragma unroll
    for (int e = 0; e < 8; e++) w0[e] = vt[ch * 16 + e][d];
    #pragma unroll
    for (int e = 0; e < 8; e++) w1[e] = vt[ch * 16 + 8 + e][d];
    short* vd = vtbuf + ((size_t)bh * 64 + d) * SP + jt * 64 + ch * 16;
    *(short8*)vd = w0;
    *(short8*)(vd + 8) = w1;
}

// ---------------------------------------------------------------------------
// MFMA flash attention, 2-phase pipelined K/V staging, rope fused on Q.
// Softmax in log2 domain: defer-max (THR=8), per-lane deferred sum.
// grid: bx = qt*256 + bh
// ---------------------------------------------------------------------------
__global__ __launch_bounds__(256) void k_attn_mfma(const short* __restrict__ qkv,
                                                   const short* __restrict__ kbuf,
                                                   const short* __restrict__ vtbuf,
                                                   const float2* __restrict__ tab,
                                                   short* __restrict__ aob) {
    __shared__ __align__(16) short Kl[2][64 * 64];
    __shared__ __align__(16) short Vl[2][64 * 64];
    __shared__ __align__(16) short sP[4][16][72];
    const int tid = threadIdx.x;
    const int w = tid >> 6, l = tid & 63;
    const int c = l & 15, t4 = l >> 4;
    int bx = blockIdx.x;
    int qt = bx >> 8, bh = bx & 255, b = bh >> 3, h = bh & 7;

    // ---- Q fragments, rope fused, scaled by 0.125*log2(e) (exp2 domain) ----
    const float QSC = 0.125f * 1.44269504f;
    int q0 = qt * 64 + w * 16;
    int qrow = q0 + c;
    int qr = qrow < SEQ ? qrow : SEQ - 1;
    size_t gq = (size_t)(b * SEQ + qr) * 1536 + h * 64;
    short8 qf0 = *(const short8*)(qkv + gq + t4 * 8);
    short8 qf1 = *(const short8*)(qkv + gq + 32 + t4 * 8);
    {
        const float2* tq = tab + (size_t)qr * NPAIR + h * 32;
        unsigned* u0 = (unsigned*)&qf0;
        unsigned* u1 = (unsigned*)&qf1;
        #pragma unroll
        for (int pp = 0; pp < 4; pp++) {
            float2 cs = tq[t4 * 4 + pp];
            float x1 = bf2f(qf0[2 * pp]), x2 = bf2f(qf0[2 * pp + 1]);
            u0[pp] = cvt_pk_bf16((x1 * cs.x - x2 * cs.y) * QSC,
                                 (x1 * cs.y + x2 * cs.x) * QSC);
            cs = tq[16 + t4 * 4 + pp];
            x1 = bf2f(qf1[2 * pp]); x2 = bf2f(qf1[2 * pp + 1]);
            u1[pp] = cvt_pk_bf16((x1 * cs.x - x2 * cs.y) * QSC,
                                 (x1 * cs.y + x2 * cs.x) * QSC);
        }
    }

    f32x4 o0 = {0,0,0,0}, o1 = {0,0,0,0}, o2 = {0,0,0,0}, o3 = {0,0,0,0};
    float mrow[4] = {-1e30f, -1e30f, -1e30f, -1e30f};
    float lrow[4] = {0.f, 0.f, 0.f, 0.f};   // per-lane partial sums

    const short* kb = kbuf + (size_t)bh * SP * 64;
    const short* vb = vtbuf + (size_t)bh * 64 * SP;
    const int r1 = w * 16 + (l >> 3);
    const int r2 = r1 + 8;
    const int blk = l & 7;

    auto stage = [&](int jt, int pb) {
        gload16(kb + ((size_t)(jt * 64 + r1)) * 64 + ((blk ^ (r1 & 7)) * 8),
                &Kl[pb][(w * 16) * 64]);
        gload16(kb + ((size_t)(jt * 64 + r2)) * 64 + ((blk ^ (r2 & 7)) * 8),
                &Kl[pb][(w * 16 + 8) * 64]);
        gload16(vb + (size_t)r1 * SP + jt * 64 + ((blk ^ (r1 & 7)) * 8),
                &Vl[pb][(w * 16) * 64]);
        gload16(vb + (size_t)r2 * SP + jt * 64 + ((blk ^ (r2 & 7)) * 8),
                &Vl[pb][(w * 16 + 8) * 64]);
    };

    stage(0, 0);
    __syncthreads();

    for (int jt = 0; jt < 9; jt++) {
        const int cur = jt & 1;
        if (jt + 1 < 9) stage(jt + 1, cur ^ 1);
        __builtin_amdgcn_sched_barrier(0);

        // ---- QK^T (scores in log2 domain)
        f32x4 s0 = {0,0,0,0}, s1 = {0,0,0,0}, s2 = {0,0,0,0}, s3 = {0,0,0,0};
        __builtin_amdgcn_s_setprio(1);
        {
            int kr0 = c, kr1 = 16 + c, kr2 = 32 + c, kr3 = 48 + c;
            short8 kf;
            kf = *(const short8*)&Kl[cur][kr0 * 64 + ((t4 ^ (kr0 & 7)) * 8)];
            s0 = __builtin_amdgcn_mfma_f32_16x16x32_bf16(qf0, kf, s0, 0, 0, 0);
            kf = *(const short8*)&Kl[cur][kr0 * 64 + (((4 + t4) ^ (kr0 & 7)) * 8)];
            s0 = __builtin_amdgcn_mfma_f32_16x16x32_bf16(qf1, kf, s0, 0, 0, 0);
            kf = *(const short8*)&Kl[cur][kr1 * 64 + ((t4 ^ (kr1 & 7)) * 8)];
            s1 = __builtin_amdgcn_mfma_f32_16x16x32_bf16(qf0, kf, s1, 0, 0, 0);
            kf = *(const short8*)&Kl[cur][kr1 * 64 + (((4 + t4) ^ (kr1 & 7)) * 8)];
            s1 = __builtin_amdgcn_mfma_f32_16x16x32_bf16(qf1, kf, s1, 0, 0, 0);
            kf = *(const short8*)&Kl[cur][kr2 * 64 + ((t4 ^ (kr2 & 7)) * 8)];
            s2 = __builtin_amdgcn_mfma_f32_16x16x32_bf16(qf0, kf, s2, 0, 0, 0);
            kf = *(const short8*)&Kl[cur][kr2 * 64 + (((4 + t4) ^ (kr2 & 7)) * 8)];
            s2 = __builtin_amdgcn_mfma_f32_16x16x32_bf16(qf1, kf, s2, 0, 0, 0);
            kf = *(const short8*)&Kl[cur][kr3 * 64 + ((t4 ^ (kr3 & 7)) * 8)];
            s3 = __builtin_amdgcn_mfma_f32_16x16x32_bf16(qf0, kf, s3, 0, 0, 0);
            kf = *(const short8*)&Kl[cur][kr3 * 64 + (((4 + t4) ^ (kr3 & 7)) * 8)];
            s3 = __builtin_amdgcn_mfma_f32_16x16x32_bf16(qf1, kf, s3, 0, 0, 0);
        }
        __builtin_amdgcn_s_setprio(0);

        if (jt == 8) {
            #pragma unroll
            for (int r = 0; r < 4; r++) {
                if (c >= 8) s0[r] = -1e30f;
                s1[r] = -1e30f; s2[r] = -1e30f; s3[r] = -1e30f;
            }
        }

        // ---- online softmax: defer-max (THR=8 in log2 domain), lazy sum
        #pragma unroll
        for (int r = 0; r < 4; r++) {
            float pmax = fmaxf(fmaxf(s0[r], s1[r]), fmaxf(s2[r], s3[r]));
            if (!__all(pmax <= mrow[r] + 8.f)) {
                float mx = pmax;
                mx = fmaxf(mx, __shfl_xor(mx, 1));
                mx = fmaxf(mx, __shfl_xor(mx, 2));
                mx = fmaxf(mx, __shfl_xor(mx, 4));
                mx = fmaxf(mx, __shfl_xor(mx, 8));
                if (mx > mrow[r]) {
                    float sc = exp2_hw(mrow[r] - mx);
                    mrow[r] = mx;
                    lrow[r] *= sc;
                    o0[r] *= sc; o1[r] *= sc; o2[r] *= sc; o3[r] *= sc;
                }
            }
            float p0 = exp2_hw(s0[r] - mrow[r]);
            float p1 = exp2_hw(s1[r] - mrow[r]);
            float p2 = exp2_hw(s2[r] - mrow[r]);
            float p3 = exp2_hw(s3[r] - mrow[r]);
            lrow[r] += (p0 + p1) + (p2 + p3);
            unsigned pk01 = cvt_pk_bf16(p0, p1);
            unsigned pk23 = cvt_pk_bf16(p2, p3);
            int q = t4 * 4 + r;
            sP[w][q][c]      = (short)(pk01 & 0xffff);
            sP[w][q][16 + c] = (short)(pk01 >> 16);
            sP[w][q][32 + c] = (short)(pk23 & 0xffff);
            sP[w][q][48 + c] = (short)(pk23 >> 16);
        }

        // ---- PV
        __builtin_amdgcn_s_setprio(1);
        {
            short8 pf0 = *(const short8*)&sP[w][c][t4 * 8];
            short8 pf1 = *(const short8*)&sP[w][c][32 + t4 * 8];
            int vr0 = c, vr1 = 16 + c, vr2 = 32 + c, vr3 = 48 + c;
            short8 vf;
            vf = *(const short8*)&Vl[cur][vr0 * 64 + ((t4 ^ (vr0 & 7)) * 8)];
            o0 = __builtin_amdgcn_mfma_f32_16x16x32_bf16(pf0, vf, o0, 0, 0, 0);
            vf = *(const short8*)&Vl[cur][vr0 * 64 + (((4 + t4) ^ (vr0 & 7)) * 8)];
            o0 = __builtin_amdgcn_mfma_f32_16x16x32_bf16(pf1, vf, o0, 0, 0, 0);
            vf = *(const short8*)&Vl[cur][vr1 * 64 + ((t4 ^ (vr1 & 7)) * 8)];
            o1 = __builtin_amdgcn_mfma_f32_16x16x32_bf16(pf0, vf, o1, 0, 0, 0);
            vf = *(const short8*)&Vl[cur][vr1 * 64 + (((4 + t4) ^ (vr1 & 7)) * 8)];
            o1 = __builtin_amdgcn_mfma_f32_16x16x32_bf16(pf1, vf, o1, 0, 0, 0);
            vf = *(const short8*)&Vl[cur][vr2 * 64 + ((t4 ^ (vr2 & 7)) * 8)];
            o2 = __builtin_amdgcn_mfma_f32_16x16x32_bf16(pf0, vf, o2, 0, 0, 0);
            vf = *(const short8*)&Vl[cur][vr2 * 64 + (((4 + t4) ^ (vr2 & 7)) * 8)];
            o2 = __builtin_amdgcn_mfma_f32_16x16x32_bf16(pf1, vf, o2, 0, 0, 0);
            vf = *(const short8*)&Vl[cur][vr3 * 64 + ((t4 ^ (vr3 & 7)) * 8)];
            o3 = __builtin_amdgcn_mfma_f32_16x16x32_bf16(pf0, vf, o3, 0, 0, 0);
            vf = *(const short8*)&Vl[cur][vr3 * 64 + (((4 + t4) ^ (vr3 & 7)) * 8)];
            o3 = __builtin_amdgcn_mfma_f32_16x16x32_bf16(pf1, vf, o3, 0, 0, 0);
        }
        __builtin_amdgcn_s_setprio(0);
        __syncthreads();
    }

    // ---- epilogue: one sum-reduce per row, normalize, store
    #pragma unroll
    for (int r = 0; r < 4; r++) {
        float s = lrow[r];
        s += __shfl_xor(s, 1);
        s += __shfl_xor(s, 2);
        s += __shfl_xor(s, 4);
        s += __shfl_xor(s, 8);
        int q = q0 + t4 * 4 + r;
        if (q < SEQ) {
            float inv = 1.f / s;
            short* ao = aob + ((size_t)(b * SEQ + q)) * DIM + h * 64 + c;
            ao[0]  = (short)f2bf(o0[r] * inv);
            ao[16] = (short)f2bf(o1[r] * inv);
            ao[32] = (short)f2bf(o2[r] * inv);
            ao[48] = (short)f2bf(o3[r] * inv);
        }
    }
}

// ---------------------------------------------------------------------------
// LayerNorm (input already contains residual sum): hb = LN(sum)*g + b
// ---------------------------------------------------------------------------
__global__ __launch_bounds__(256) void k_ln(short* __restrict__ hb,
                                            const short* __restrict__ sum,
                                            const float* __restrict__ g,
                                            const float* __restrict__ bta) {
    int row = blockIdx.x * 4 + (threadIdx.x >> 6);
    int l = threadIdx.x & 63;
    size_t base = (size_t)row * DIM + l * 8;
    short8 hv = *(const short8*)&sum[base];
    float a[8];
    float s1 = 0.f, s2 = 0.f;
    #pragma unroll
    for (int e = 0; e < 8; e++) {
        a[e] = bf2f(hv[e]);
        s1 += a[e];
        s2 += a[e] * a[e];
    }
    s1 = wred_sum(s1);
    s2 = wred_sum(s2);
    float mu = s1 * (1.f / 512.f);
    float rr = rsqrtf(s2 * (1.f / 512.f) - mu * mu + 1e-6f);
    float4 g0 = *(const float4*)&g[l * 8];
    float4 g1 = *(const float4*)&g[l * 8 + 4];
    float4 b0 = *(const float4*)&bta[l * 8];
    float4 b1 = *(const float4*)&bta[l * 8 + 4];
    unsigned o[4];
    o[0] = cvt_pk_bf16((a[0] - mu) * rr * g0.x + b0.x,
                       (a[1] - mu) * rr * g0.y + b0.y);
    o[1] = cvt_pk_bf16((a[2] - mu) * rr * g0.z + b0.z,
                       (a[3] - mu) * rr * g0.w + b0.w);
    o[2] = cvt_pk_bf16((a[4] - mu) * rr * g1.x + b1.x,
                       (a[5] - mu) * rr * g1.y + b1.y);
    o[3] = cvt_pk_bf16((a[6] - mu) * rr * g1.z + b1.z,
                       (a[7] - mu) * rr * g1.w + b1.w);
    *(uint4*)&hb[base] = make_uint4(o[0], o[1], o[2], o[3]);
}

// ---------------------------------------------------------------------------
// Head hidden: hid[b,o,j] = relu(x_cls[b,o,:] @ Wh[o] + bh[o,j])
// ---------------------------------------------------------------------------
__global__ __launch_bounds__(256) void k_hid(const short* __restrict__ hb,
                                             const float* __restrict__ Wh,
                                             const float* __restrict__ bh,
                                             float* __restrict__ hid) {
    int j = blockIdx.x * 256 + threadIdx.x;
    int o = blockIdx.y, b = blockIdx.z;
    const short* xr = hb + ((size_t)(b * SEQ + o)) * DIM;
    const float* wcol = Wh + (size_t)o * DIM * DIM + j;
    float acc = bh[o * DIM + j];
    #pragma unroll 8
    for (int d = 0; d < DIM; d++)
        acc = fmaf(bf2f(xr[d]), wcol[(size_t)d * DIM], acc);
    hid[((size_t)b * 8 + o) * DIM + j] = fmaxf(acc, 0.f);
}

// ---------------------------------------------------------------------------
__device__ __forceinline__ float softplus_f(float x) { return log1pf(expf(x)); }

__global__ __launch_bounds__(64) void k_var(const float* __restrict__ hid,
                                            const float* __restrict__ mu_wmu,
                                            const float* __restrict__ mu_wrho,
                                            const float* __restrict__ mu_bmu,
                                            const float* __restrict__ mu_brho,
                                            const float* __restrict__ lv_wmu,
                                            const float* __restrict__ lv_wrho,
                                            const float* __restrict__ lv_bmu,
                                            const float* __restrict__ lv_brho,
                                            const float* __restrict__ eps_mu_w,
                                            const float* __restrict__ eps_mu_b,
                                            const float* __restrict__ eps_lv_w,
                                            const float* __restrict__ eps_lv_b,
                                            float* __restrict__ out) {
    const float EPS = 1e-8f;
    int bo = blockIdx.x;
    int o = bo & 7;
    int l = threadIdx.x;
    float am = 0.f, al = 0.f;
    #pragma unroll
    for (int k = 0; k < 8; k++) {
        int d = k * 64 + l;
        int od = o * DIM + d;
        float hv = hid[(size_t)bo * DIM + d];
        am = fmaf(hv, mu_wmu[od] + (softplus_f(mu_wrho[od]) + EPS) * eps_mu_w[od], am);
        al = fmaf(hv, lv_wmu[od] + (softplus_f(lv_wrho[od]) + EPS) * eps_lv_w[od], al);
    }
    am = wred_sum(am);
    al = wred_sum(al);
    if (l == 0) {
        float mu = am + mu_bmu[o] + (softplus_f(mu_brho[o]) + EPS) * eps_mu_b[o];
        out[bo] = mu;
        float lvv = al + lv_bmu[o] + (softplus_f(lv_brho[o]) + EPS) * eps_lv_b[o];
        out[256 + bo] = logf(EPS + softplus_f(lvv));
    }
}

// ---------------------------------------------------------------------------
extern "C" void kernel_launch(void* const* d_in, const int* in_sizes, int n_in,
                              void* d_out, int out_size, void* d_ws, size_t ws_size,
                              hipStream_t stream) {
    const float* x      = (const float*)d_in[0];
    const float* W_in   = (const float*)d_in[1];
    const float* b_in   = (const float*)d_in[2];
    const float* cls    = (const float*)d_in[3];
    const float* Wqkv   = (const float*)d_in[4];
    const float* bqkv   = (const float*)d_in[5];
    const float* Wo     = (const float*)d_in[6];
    const float* bo     = (const float*)d_in[7];
    const float* ln1_g  = (const float*)d_in[8];
    const float* ln1_b  = (const float*)d_in[9];
    const float* Wm1    = (const float*)d_in[10];
    const float* bm1    = (const float*)d_in[11];
    const float* Wm2    = (const float*)d_in[12];
    const float* bm2    = (const float*)d_in[13];
    const float* ln2_g  = (const float*)d_in[14];
    const float* ln2_b  = (const float*)d_in[15];
    const float* Wh     = (const float*)d_in[16];
    const float* bh     = (const float*)d_in[17];
    const float* mu_wmu = (const float*)d_in[18];
    const float* mu_wrho= (const float*)d_in[19];
    const float* mu_bmu = (const float*)d_in[20];
    const float* mu_brho= (const float*)d_in[21];
    const float* lv_wmu = (const float*)d_in[22];
    const float* lv_wrho= (const float*)d_in[23];
    const float* lv_bmu = (const float*)d_in[24];
    const float* lv_brho= (const float*)d_in[25];
    const float* e_mu_w = (const float*)d_in[26];
    const float* e_mu_b = (const float*)d_in[27];
    const float* e_lv_w = (const float*)d_in[28];
    const float* e_lv_b = (const float*)d_in[29];
    float* out = (float*)d_out;

    char* p = (char*)d_ws;
    auto alloc = [&](size_t bytes) {
        char* r = p;
        p += (bytes + 255) & ~(size_t)255;
        return r;
    };
    const size_t qkv_bytes = (size_t)NROW * 1536 * 2;
    const size_t kbuf_bytes = (size_t)BATCH * NHEAD * SP * 64 * 2;
    const size_t attn_bytes = qkv_bytes + 2 * kbuf_bytes + 512;
    const size_t mid_bytes = (size_t)NROW * MLPD * 2;
    char*   U1    =          alloc(attn_bytes > mid_bytes ? attn_bytes : mid_bytes);
    short*  qkv   = (short*)U1;
    short*  kbuf  = (short*)(U1 + ((qkv_bytes + 255) & ~(size_t)255));
    short*  vtbuf = kbuf + kbuf_bytes / 2;
    short*  mid   = (short*)U1;
    short*  hb    = (short*) alloc((size_t)NROW * DIM * 2);
    short*  deltab= (short*) alloc((size_t)NROW * DIM * 2);
    short*  aob   = (short*) alloc((size_t)NROW * DIM * 2);
    short*  wqkvt = (short*) alloc((size_t)NLAYER * 1536 * 512 * 2);
    short*  wot   = (short*) alloc((size_t)NLAYER * 512 * 512 * 2);
    short*  wm1t  = (short*) alloc((size_t)NLAYER * 2048 * 512 * 2);
    short*  wm2t  = (short*) alloc((size_t)NLAYER * 512 * 2048 * 2);
    float2* ropet = (float2*)alloc((size_t)SEQ * NPAIR * 8);
    float*  hid   = (float*) alloc((size_t)256 * DIM * 4);

    k_wconv<<<dim3(24, 8, 4), 256, 0, stream>>>(Wqkv, wqkvt, 512, 1536);
    k_wconv<<<dim3(8, 8, 4),  256, 0, stream>>>(Wo,   wot,   512, 512);
    k_wconv<<<dim3(32, 8, 4), 256, 0, stream>>>(Wm1,  wm1t,  512, 2048);
    k_wconv<<<dim3(8, 32, 4), 256, 0, stream>>>(Wm2,  wm2t,  2048, 512);
    k_rope_tab<<<SEQ, NPAIR, 0, stream>>>(ropet);
    k_in_proj<<<NROW, 256, 0, stream>>>(x, W_in, b_in, cls, hb);

    const int RT = NROW / 128;   // 130
    for (int l = 0; l < NLAYER; l++) {
        k_gemm<32, false, false><<<RT * 12, 256, 0, stream>>>(
            hb, wqkvt + (size_t)l * 1536 * 512, bqkv + l * 1536, nullptr, qkv, 1536, 512);
        k_kvprep<<<BATCH * NHEAD * 9, 256, 0, stream>>>(qkv, ropet, kbuf, vtbuf);
        k_attn_mfma<<<9 * 256, 256, 0, stream>>>(qkv, kbuf, vtbuf, ropet, aob);
        k_gemm<64, false, true><<<RT * 4, 256, 0, stream>>>(
            aob, wot + (size_t)l * 512 * 512, bo + l * 512, hb, deltab, 512, 512);
        k_ln<<<NROW / 4, 256, 0, stream>>>(hb, deltab, ln1_g + l * 512, ln1_b + l * 512);
        k_gemm<32, true, false><<<RT * 16, 256, 0, stream>>>(
            hb, wm1t + (size_t)l * 2048 * 512, bm1 + l * 2048, nullptr, mid, 2048, 512);
        k_gemm<64, false, true><<<RT * 4, 256, 0, stream>>>(
            mid, wm2t + (size_t)l * 512 * 2048, bm2 + l * 512, hb, deltab, 512, 2048);
        k_ln<<<NROW / 4, 256, 0, stream>>>(hb, deltab, ln2_g + l * 512, ln2_b + l * 512);
    }

    k_hid<<<dim3(2, 8, 32), 256, 0, stream>>>(hb, Wh, bh, hid);
    k_var<<<256, 64, 0, stream>>>(hid, mu_wmu, mu_wrho, mu_bmu, mu_brho,
                                  lv_wmu, lv_wrho, lv_bmu, lv_brho,
                                  e_mu_w, e_mu_b, e_lv_w, e_lv_b, out);
}

// Round 7
// 1098.680 us; speedup vs baseline: 4.8434x; 1.0532x over previous
//
#include <hip/hip_runtime.h>
#include <cstdint>

// ---------------------------------------------------------------------------
// QRoPETRegressor: 4-layer transformer (B=32, S=520 w/ 8 cls, D=512, NH=8,
// HD=64, MLP=2048) + variational heads.
// R7: counted-vmcnt depth-2 pipelines (raw s_barrier, never vmcnt(0) in the
//     main loop) in GEMM and attention.  setprio around GEMM MFMA cluster.
// ---------------------------------------------------------------------------

#define BATCH   32
#define SEQ     520
#define SP      576
#define DIM     512
#define NHEAD   8
#define HDIM    64
#define MLPD    2048
#define NLAYER  4
#define NROW    (BATCH * SEQ)   // 16640
#define NPAIR   256

typedef __attribute__((ext_vector_type(4))) float  f32x4;
typedef __attribute__((ext_vector_type(8))) short  short8;

__device__ __forceinline__ unsigned short f2bf(float f) {
    unsigned u = __float_as_uint(f);
    unsigned r = (u + 0x7fffu + ((u >> 16) & 1u)) >> 16;
    return (unsigned short)r;
}
__device__ __forceinline__ float bf2f(short s) {
    return __uint_as_float(((unsigned)(unsigned short)s) << 16);
}
__device__ __forceinline__ unsigned cvt_pk_bf16(float lo, float hi) {
    unsigned r;
    asm("v_cvt_pk_bf16_f32 %0, %1, %2" : "=v"(r) : "v"(lo), "v"(hi));
    return r;
}
__device__ __forceinline__ float exp2_hw(float x) {
    float r;
    asm("v_exp_f32 %0, %1" : "=v"(r) : "v"(x));
    return r;
}
__device__ __forceinline__ float wred_sum(float v) {
    #pragma unroll
    for (int off = 32; off; off >>= 1) v += __shfl_xor(v, off);
    return v;
}

__device__ __forceinline__ void gload16(const void* g, void* l) {
    __builtin_amdgcn_global_load_lds(
        (const __attribute__((address_space(1))) unsigned int*)g,
        (__attribute__((address_space(3))) unsigned int*)l,
        16, 0, 0);
}

// ---------------------------------------------------------------------------
// Weight transpose-convert: src fp32 (K,N) -> dst bf16 (N,K)
// ---------------------------------------------------------------------------
__global__ __launch_bounds__(256) void k_wconv(const float* __restrict__ src,
                                               short* __restrict__ dst,
                                               int K, int N) {
    src += (size_t)blockIdx.z * K * N;
    dst += (size_t)blockIdx.z * K * N;
    int n0 = blockIdx.x * 64, k0 = blockIdx.y * 64;
    __shared__ float t[64][65];
    int tid = threadIdx.x;
    int r = tid >> 2, cq = (tid & 3) * 16;
    const float* sp = src + (size_t)(k0 + r) * N + n0 + cq;
    #pragma unroll
    for (int e = 0; e < 16; e += 4) {
        float4 v = *(const float4*)(sp + e);
        t[r][cq + e] = v.x; t[r][cq + e + 1] = v.y;
        t[r][cq + e + 2] = v.z; t[r][cq + e + 3] = v.w;
    }
    __syncthreads();
    int n = tid >> 2, kq = (tid & 3) * 16;
    short* dp = dst + (size_t)(n0 + n) * K + k0 + kq;
    unsigned o0[4], o1[4];
    #pragma unroll
    for (int e = 0; e < 4; e++)
        o0[e] = cvt_pk_bf16(t[kq + 2 * e][n], t[kq + 2 * e + 1][n]);
    #pragma unroll
    for (int e = 0; e < 4; e++)
        o1[e] = cvt_pk_bf16(t[kq + 8 + 2 * e][n], t[kq + 9 + 2 * e][n]);
    *(uint4*)dp = make_uint4(o0[0], o0[1], o0[2], o0[3]);
    *(uint4*)(dp + 8) = make_uint4(o1[0], o1[1], o1[2], o1[3]);
}

// ---------------------------------------------------------------------------
__global__ void k_rope_tab(float2* __restrict__ tab) {
    int s = blockIdx.x, i = threadIdx.x;
    float fr = powf(10000.f, -2.f * (float)i / 512.f);
    float th = (float)s * fr;
    float sn, cn;
    sincosf(th, &sn, &cn);
    tab[s * NPAIR + i] = make_float2(cn, sn);
}

// ---------------------------------------------------------------------------
// Input proj + cls concat -> bf16 h
// ---------------------------------------------------------------------------
__global__ __launch_bounds__(256) void k_in_proj(const float* __restrict__ x,
                                                 const float* __restrict__ Wi,
                                                 const float* __restrict__ bi,
                                                 const float* __restrict__ cls,
                                                 short* __restrict__ hb) {
    int row = blockIdx.x;
    int b = row / SEQ, s = row % SEQ;
    bool is_cls = s < 8;
    float xr[16];
    if (!is_cls) {
        const float* xp = x + (size_t)(b * 512 + (s - 8)) * 16;
        #pragma unroll
        for (int f = 0; f < 16; f++) xr[f] = xp[f];
    }
    for (int c = threadIdx.x; c < DIM; c += 256) {
        float v;
        if (is_cls) {
            v = cls[s * DIM + c];
        } else {
            v = bi[c];
            #pragma unroll
            for (int f = 0; f < 16; f++) v = fmaf(xr[f], Wi[f * DIM + c], v);
        }
        hb[(size_t)row * DIM + c] = (short)f2bf(v);
    }
}

// ---------------------------------------------------------------------------
// GEMM: C[M,N](bf16) = act(A @ W + bias [+ Res]), A bf16 [M][K], Bt [N][K].
// 128x128 tile, templated BK, dbuf LDS, counted-vmcnt depth-2 pipeline:
//   vmcnt(NLD) -> barrier -> ds_read -> lgkmcnt(0) -> barrier -> stage(t+2)
//   -> MFMA.  Never vmcnt(0) mid-loop.
// ---------------------------------------------------------------------------
template <int BK, bool RELU, bool ADDRES>
__global__ __launch_bounds__(256) void k_gemm(const short* __restrict__ A,
                                              const short* __restrict__ Bt,
                                              const float* __restrict__ bias,
                                              const short* __restrict__ Res,
                                              short* __restrict__ Cout,
                                              int N, int K) {
    constexpr int NB  = BK / 8;
    constexpr int MSK = NB - 1;
    constexpr int RPG = 1024 / (BK * 2);
    constexpr int GPW = 32 / RPG;
    constexpr int NLD = 2 * GPW;      // gload16 per wave per stage (A+B)
    __shared__ __align__(16) short As[2][128 * BK];
    __shared__ __align__(16) short Bs[2][128 * BK];
    const int tid = threadIdx.x;
    const int w = tid >> 6, l = tid & 63;

    const int chunk = gridDim.x >> 3;
    const int t = (blockIdx.x & 7) * chunk + (blockIdx.x >> 3);
    const int C = N >> 7;
    const int brow = (t / C) * 128, bcol = (t % C) * 128;

    const int srow = l / NB;
    const int sblk = l & MSK;
    const int soff = ((sblk ^ (srow & MSK)) * 8);
    const int fr = l & 15, t4 = l >> 4;
    const int wr = (w >> 1) * 64, wc = (w & 1) * 64;

    const short* Ab = A  + (size_t)(brow + w * 32 + srow) * K + soff;
    const short* Bb = Bt + (size_t)(bcol + w * 32 + srow) * K + soff;

    f32x4 acc[4][4];
    #pragma unroll
    for (int m = 0; m < 4; m++)
        #pragma unroll
        for (int n = 0; n < 4; n++) acc[m][n] = (f32x4){0.f, 0.f, 0.f, 0.f};

    auto stage = [&](int ko, int pb) {
        #pragma unroll
        for (int i = 0; i < GPW; i++)
            gload16(Ab + (size_t)(i * RPG) * K + ko,
                    &As[pb][(w * 32 + i * RPG) * BK]);
        #pragma unroll
        for (int i = 0; i < GPW; i++)
            gload16(Bb + (size_t)(i * RPG) * K + ko,
                    &Bs[pb][(w * 32 + i * RPG) * BK]);
    };

    const int nk = K / BK;
    stage(0, 0);
    stage(BK, 1);

    for (int kt = 0; kt < nk; ++kt) {
        const int cur = kt & 1;
        // ---- wait for MY stage(kt) to land (stage(kt+1) stays in flight)
        if (kt + 1 < nk) {
            if constexpr (NLD == 8) asm volatile("s_waitcnt vmcnt(8)" ::: "memory");
            else                    asm volatile("s_waitcnt vmcnt(4)" ::: "memory");
        } else {
            asm volatile("s_waitcnt vmcnt(0)" ::: "memory");
        }
        __builtin_amdgcn_s_barrier();          // now ALL waves' data is in LDS
        __builtin_amdgcn_sched_barrier(0);

        short8 af[4][BK / 32], bf[4][BK / 32];
        #pragma unroll
        for (int m = 0; m < 4; m++) {
            int r = wr + m * 16 + fr;
            #pragma unroll
            for (int kk = 0; kk < BK / 32; kk++)
                af[m][kk] = *(const short8*)
                    &As[cur][r * BK + (((kk * 4 + t4) ^ (r & MSK)) * 8)];
        }
        #pragma unroll
        for (int n = 0; n < 4; n++) {
            int r = wc + n * 16 + fr;
            #pragma unroll
            for (int kk = 0; kk < BK / 32; kk++)
                bf[n][kk] = *(const short8*)
                    &Bs[cur][r * BK + (((kk * 4 + t4) ^ (r & MSK)) * 8)];
        }
        asm volatile("s_waitcnt lgkmcnt(0)" ::: "memory");
        __builtin_amdgcn_s_barrier();          // all waves done reading [cur]
        __builtin_amdgcn_sched_barrier(0);
        if (kt + 2 < nk) stage((kt + 2) * BK, cur);   // overwrite [cur]

        __builtin_amdgcn_s_setprio(1);
        #pragma unroll
        for (int kk = 0; kk < BK / 32; kk++)
            #pragma unroll
            for (int m = 0; m < 4; m++)
                #pragma unroll
                for (int n = 0; n < 4; n++)
                    acc[m][n] = __builtin_amdgcn_mfma_f32_16x16x32_bf16(
                        af[m][kk], bf[n][kk], acc[m][n], 0, 0, 0);
        __builtin_amdgcn_s_setprio(0);
    }

    const int r0 = (l >> 4) * 4, c0 = l & 15;
    #pragma unroll
    for (int m = 0; m < 4; m++) {
        #pragma unroll
        for (int n = 0; n < 4; n++) {
            int col = bcol + wc + n * 16 + c0;
            float bv = bias[col];
            #pragma unroll
            for (int q = 0; q < 4; q++) {
                int row = brow + wr + m * 16 + r0 + q;
                float v = acc[m][n][q] + bv;
                if (ADDRES) v += bf2f(Res[(size_t)row * N + col]);
                if (RELU) v = fmaxf(v, 0.f);
                Cout[(size_t)row * N + col] = (short)f2bf(v);
            }
        }
    }
}

// ---------------------------------------------------------------------------
// K/V prep: rope K -> kbuf[bh][SP][64]; transpose V -> vtbuf[bh][64][SP].
// ---------------------------------------------------------------------------
__global__ __launch_bounds__(256) void k_kvprep(const short* __restrict__ qkv,
                                                const float2* __restrict__ tab,
                                                short* __restrict__ kbuf,
                                                short* __restrict__ vtbuf) {
    int bx = blockIdx.x;
    int jt = bx % 9, bh = bx / 9, b = bh >> 3, h = bh & 7;
    int tid = threadIdx.x;
    int row = tid >> 2, ch = tid & 3;
    int s = jt * 64 + row;
    bool valid = s < SEQ;
    size_t g = (size_t)(b * SEQ + (valid ? s : 0)) * 1536;

    short8 ok0 = (short8)0, ok1 = (short8)0;
    if (valid) {
        short8 k0 = *(const short8*)(qkv + g + 512 + h * 64 + ch * 16);
        short8 k1 = *(const short8*)(qkv + g + 512 + h * 64 + ch * 16 + 8);
        unsigned* u0 = (unsigned*)&ok0;
        unsigned* u1 = (unsigned*)&ok1;
        #pragma unroll
        for (int pp = 0; pp < 4; pp++) {
            float2 cs = tab[s * NPAIR + h * 32 + ch * 8 + pp];
            float x1 = bf2f(k0[2 * pp]), x2 = bf2f(k0[2 * pp + 1]);
            u0[pp] = cvt_pk_bf16(x1 * cs.x - x2 * cs.y, x1 * cs.y + x2 * cs.x);
            cs = tab[s * NPAIR + h * 32 + ch * 8 + 4 + pp];
            x1 = bf2f(k1[2 * pp]); x2 = bf2f(k1[2 * pp + 1]);
            u1[pp] = cvt_pk_bf16(x1 * cs.x - x2 * cs.y, x1 * cs.y + x2 * cs.x);
        }
    }
    short* kd = kbuf + ((size_t)bh * SP + jt * 64 + row) * 64 + ch * 16;
    *(short8*)kd = ok0;
    *(short8*)(kd + 8) = ok1;

    __shared__ short vt[64][72];
    short8 v0 = (short8)0, v1 = (short8)0;
    if (valid) {
        v0 = *(const short8*)(qkv + g + 1024 + h * 64 + ch * 16);
        v1 = *(const short8*)(qkv + g + 1024 + h * 64 + ch * 16 + 8);
    }
    *(short8*)&vt[row][ch * 16] = v0;
    *(short8*)&vt[row][ch * 16 + 8] = v1;
    __syncthreads();
    int d = row;
    short8 w0, w1;
    #pragma unroll
    for (int e = 0; e < 8; e++) w0[e] = vt[ch * 16 + e][d];
    #pragma unroll
    for (int e = 0; e < 8; e++) w1[e] = vt[ch * 16 + 8 + e][d];
    short* vd = vtbuf + ((size_t)bh * 64 + d) * SP + jt * 64 + ch * 16;
    *(short8*)vd = w0;
    *(short8*)(vd + 8) = w1;
}

// ---------------------------------------------------------------------------
// MFMA flash attention, counted-vmcnt depth-2 K/V pipeline, rope fused on Q.
// Softmax in log2 domain: defer-max (THR=8), per-lane deferred sum.
// grid: bx = qt*256 + bh
// ---------------------------------------------------------------------------
__global__ __launch_bounds__(256) void k_attn_mfma(const short* __restrict__ qkv,
                                                   const short* __restrict__ kbuf,
                                                   const short* __restrict__ vtbuf,
                                                   const float2* __restrict__ tab,
                                                   short* __restrict__ aob) {
    __shared__ __align__(16) short Kl[2][64 * 64];
    __shared__ __align__(16) short Vl[2][64 * 64];
    __shared__ __align__(16) short sP[4][16][72];
    const int tid = threadIdx.x;
    const int w = tid >> 6, l = tid & 63;
    const int c = l & 15, t4 = l >> 4;
    int bx = blockIdx.x;
    int qt = bx >> 8, bh = bx & 255, b = bh >> 3, h = bh & 7;

    // ---- Q fragments, rope fused, scaled by 0.125*log2(e) (exp2 domain) ----
    const float QSC = 0.125f * 1.44269504f;
    int q0 = qt * 64 + w * 16;
    int qrow = q0 + c;
    int qr = qrow < SEQ ? qrow : SEQ - 1;
    size_t gq = (size_t)(b * SEQ + qr) * 1536 + h * 64;
    short8 qf0 = *(const short8*)(qkv + gq + t4 * 8);
    short8 qf1 = *(const short8*)(qkv + gq + 32 + t4 * 8);
    {
        const float2* tq = tab + (size_t)qr * NPAIR + h * 32;
        unsigned* u0 = (unsigned*)&qf0;
        unsigned* u1 = (unsigned*)&qf1;
        #pragma unroll
        for (int pp = 0; pp < 4; pp++) {
            float2 cs = tq[t4 * 4 + pp];
            float x1 = bf2f(qf0[2 * pp]), x2 = bf2f(qf0[2 * pp + 1]);
            u0[pp] = cvt_pk_bf16((x1 * cs.x - x2 * cs.y) * QSC,
                                 (x1 * cs.y + x2 * cs.x) * QSC);
            cs = tq[16 + t4 * 4 + pp];
            x1 = bf2f(qf1[2 * pp]); x2 = bf2f(qf1[2 * pp + 1]);
            u1[pp] = cvt_pk_bf16((x1 * cs.x - x2 * cs.y) * QSC,
                                 (x1 * cs.y + x2 * cs.x) * QSC);
        }
    }

    f32x4 o0 = {0,0,0,0}, o1 = {0,0,0,0}, o2 = {0,0,0,0}, o3 = {0,0,0,0};
    float mrow[4] = {-1e30f, -1e30f, -1e30f, -1e30f};
    float lrow[4] = {0.f, 0.f, 0.f, 0.f};

    const short* kb = kbuf + (size_t)bh * SP * 64;
    const short* vb = vtbuf + (size_t)bh * 64 * SP;
    const int r1 = w * 16 + (l >> 3);
    const int r2 = r1 + 8;
    const int blk = l & 7;

    auto stage = [&](int jt, int pb) {
        gload16(kb + ((size_t)(jt * 64 + r1)) * 64 + ((blk ^ (r1 & 7)) * 8),
                &Kl[pb][(w * 16) * 64]);
        gload16(kb + ((size_t)(jt * 64 + r2)) * 64 + ((blk ^ (r2 & 7)) * 8),
                &Kl[pb][(w * 16 + 8) * 64]);
        gload16(vb + (size_t)r1 * SP + jt * 64 + ((blk ^ (r1 & 7)) * 8),
                &Vl[pb][(w * 16) * 64]);
        gload16(vb + (size_t)r2 * SP + jt * 64 + ((blk ^ (r2 & 7)) * 8),
                &Vl[pb][(w * 16 + 8) * 64]);
    };

    stage(0, 0);
    stage(1, 1);

    for (int jt = 0; jt < 9; jt++) {
        const int cur = jt & 1;
        if (jt + 1 < 9) asm volatile("s_waitcnt vmcnt(4)" ::: "memory");
        else            asm volatile("s_waitcnt vmcnt(0)" ::: "memory");
        __builtin_amdgcn_s_barrier();
        __builtin_amdgcn_sched_barrier(0);

        // ---- QK^T (scores in log2 domain)
        f32x4 s0 = {0,0,0,0}, s1 = {0,0,0,0}, s2 = {0,0,0,0}, s3 = {0,0,0,0};
        __builtin_amdgcn_s_setprio(1);
        {
            int kr0 = c, kr1 = 16 + c, kr2 = 32 + c, kr3 = 48 + c;
            short8 kf;
            kf = *(const short8*)&Kl[cur][kr0 * 64 + ((t4 ^ (kr0 & 7)) * 8)];
            s0 = __builtin_amdgcn_mfma_f32_16x16x32_bf16(qf0, kf, s0, 0, 0, 0);
            kf = *(const short8*)&Kl[cur][kr0 * 64 + (((4 + t4) ^ (kr0 & 7)) * 8)];
            s0 = __builtin_amdgcn_mfma_f32_16x16x32_bf16(qf1, kf, s0, 0, 0, 0);
            kf = *(const short8*)&Kl[cur][kr1 * 64 + ((t4 ^ (kr1 & 7)) * 8)];
            s1 = __builtin_amdgcn_mfma_f32_16x16x32_bf16(qf0, kf, s1, 0, 0, 0);
            kf = *(const short8*)&Kl[cur][kr1 * 64 + (((4 + t4) ^ (kr1 & 7)) * 8)];
            s1 = __builtin_amdgcn_mfma_f32_16x16x32_bf16(qf1, kf, s1, 0, 0, 0);
            kf = *(const short8*)&Kl[cur][kr2 * 64 + ((t4 ^ (kr2 & 7)) * 8)];
            s2 = __builtin_amdgcn_mfma_f32_16x16x32_bf16(qf0, kf, s2, 0, 0, 0);
            kf = *(const short8*)&Kl[cur][kr2 * 64 + (((4 + t4) ^ (kr2 & 7)) * 8)];
            s2 = __builtin_amdgcn_mfma_f32_16x16x32_bf16(qf1, kf, s2, 0, 0, 0);
            kf = *(const short8*)&Kl[cur][kr3 * 64 + ((t4 ^ (kr3 & 7)) * 8)];
            s3 = __builtin_amdgcn_mfma_f32_16x16x32_bf16(qf0, kf, s3, 0, 0, 0);
            kf = *(const short8*)&Kl[cur][kr3 * 64 + (((4 + t4) ^ (kr3 & 7)) * 8)];
            s3 = __builtin_amdgcn_mfma_f32_16x16x32_bf16(qf1, kf, s3, 0, 0, 0);
        }
        __builtin_amdgcn_s_setprio(0);

        if (jt == 8) {
            #pragma unroll
            for (int r = 0; r < 4; r++) {
                if (c >= 8) s0[r] = -1e30f;
                s1[r] = -1e30f; s2[r] = -1e30f; s3[r] = -1e30f;
            }
        }

        // ---- online softmax: defer-max (THR=8 in log2 domain), lazy sum
        #pragma unroll
        for (int r = 0; r < 4; r++) {
            float pmax = fmaxf(fmaxf(s0[r], s1[r]), fmaxf(s2[r], s3[r]));
            if (!__all(pmax <= mrow[r] + 8.f)) {
                float mx = pmax;
                mx = fmaxf(mx, __shfl_xor(mx, 1));
                mx = fmaxf(mx, __shfl_xor(mx, 2));
                mx = fmaxf(mx, __shfl_xor(mx, 4));
                mx = fmaxf(mx, __shfl_xor(mx, 8));
                if (mx > mrow[r]) {
                    float sc = exp2_hw(mrow[r] - mx);
                    mrow[r] = mx;
                    lrow[r] *= sc;
                    o0[r] *= sc; o1[r] *= sc; o2[r] *= sc; o3[r] *= sc;
                }
            }
            float p0 = exp2_hw(s0[r] - mrow[r]);
            float p1 = exp2_hw(s1[r] - mrow[r]);
            float p2 = exp2_hw(s2[r] - mrow[r]);
            float p3 = exp2_hw(s3[r] - mrow[r]);
            lrow[r] += (p0 + p1) + (p2 + p3);
            unsigned pk01 = cvt_pk_bf16(p0, p1);
            unsigned pk23 = cvt_pk_bf16(p2, p3);
            int q = t4 * 4 + r;
            sP[w][q][c]      = (short)(pk01 & 0xffff);
            sP[w][q][16 + c] = (short)(pk01 >> 16);
            sP[w][q][32 + c] = (short)(pk23 & 0xffff);
            sP[w][q][48 + c] = (short)(pk23 >> 16);
        }

        // ---- PV
        __builtin_amdgcn_s_setprio(1);
        {
            short8 pf0 = *(const short8*)&sP[w][c][t4 * 8];
            short8 pf1 = *(const short8*)&sP[w][c][32 + t4 * 8];
            int vr0 = c, vr1 = 16 + c, vr2 = 32 + c, vr3 = 48 + c;
            short8 vf;
            vf = *(const short8*)&Vl[cur][vr0 * 64 + ((t4 ^ (vr0 & 7)) * 8)];
            o0 = __builtin_amdgcn_mfma_f32_16x16x32_bf16(pf0, vf, o0, 0, 0, 0);
            vf = *(const short8*)&Vl[cur][vr0 * 64 + (((4 + t4) ^ (vr0 & 7)) * 8)];
            o0 = __builtin_amdgcn_mfma_f32_16x16x32_bf16(pf1, vf, o0, 0, 0, 0);
            vf = *(const short8*)&Vl[cur][vr1 * 64 + ((t4 ^ (vr1 & 7)) * 8)];
            o1 = __builtin_amdgcn_mfma_f32_16x16x32_bf16(pf0, vf, o1, 0, 0, 0);
            vf = *(const short8*)&Vl[cur][vr1 * 64 + (((4 + t4) ^ (vr1 & 7)) * 8)];
            o1 = __builtin_amdgcn_mfma_f32_16x16x32_bf16(pf1, vf, o1, 0, 0, 0);
            vf = *(const short8*)&Vl[cur][vr2 * 64 + ((t4 ^ (vr2 & 7)) * 8)];
            o2 = __builtin_amdgcn_mfma_f32_16x16x32_bf16(pf0, vf, o2, 0, 0, 0);
            vf = *(const short8*)&Vl[cur][vr2 * 64 + (((4 + t4) ^ (vr2 & 7)) * 8)];
            o2 = __builtin_amdgcn_mfma_f32_16x16x32_bf16(pf1, vf, o2, 0, 0, 0);
            vf = *(const short8*)&Vl[cur][vr3 * 64 + ((t4 ^ (vr3 & 7)) * 8)];
            o3 = __builtin_amdgcn_mfma_f32_16x16x32_bf16(pf0, vf, o3, 0, 0, 0);
            vf = *(const short8*)&Vl[cur][vr3 * 64 + (((4 + t4) ^ (vr3 & 7)) * 8)];
            o3 = __builtin_amdgcn_mfma_f32_16x16x32_bf16(pf1, vf, o3, 0, 0, 0);
        }
        __builtin_amdgcn_s_setprio(0);

        asm volatile("s_waitcnt lgkmcnt(0)" ::: "memory");
        __builtin_amdgcn_s_barrier();          // all waves done with [cur]
        __builtin_amdgcn_sched_barrier(0);
        if (jt + 2 < 9) stage(jt + 2, cur);    // refill [cur] over next compute
    }

    // ---- epilogue: one sum-reduce per row, normalize, store
    #pragma unroll
    for (int r = 0; r < 4; r++) {
        float s = lrow[r];
        s += __shfl_xor(s, 1);
        s += __shfl_xor(s, 2);
        s += __shfl_xor(s, 4);
        s += __shfl_xor(s, 8);
        int q = q0 + t4 * 4 + r;
        if (q < SEQ) {
            float inv = 1.f / s;
            short* ao = aob + ((size_t)(b * SEQ + q)) * DIM + h * 64 + c;
            ao[0]  = (short)f2bf(o0[r] * inv);
            ao[16] = (short)f2bf(o1[r] * inv);
            ao[32] = (short)f2bf(o2[r] * inv);
            ao[48] = (short)f2bf(o3[r] * inv);
        }
    }
}

// ---------------------------------------------------------------------------
// LayerNorm (input already contains residual sum): hb = LN(sum)*g + b
// ---------------------------------------------------------------------------
__global__ __launch_bounds__(256) void k_ln(short* __restrict__ hb,
                                            const short* __restrict__ sum,
                                            const float* __restrict__ g,
                                            const float* __restrict__ bta) {
    int row = blockIdx.x * 4 + (threadIdx.x >> 6);
    int l = threadIdx.x & 63;
    size_t base = (size_t)row * DIM + l * 8;
    short8 hv = *(const short8*)&sum[base];
    float a[8];
    float s1 = 0.f, s2 = 0.f;
    #pragma unroll
    for (int e = 0; e < 8; e++) {
        a[e] = bf2f(hv[e]);
        s1 += a[e];
        s2 += a[e] * a[e];
    }
    s1 = wred_sum(s1);
    s2 = wred_sum(s2);
    float mu = s1 * (1.f / 512.f);
    float rr = rsqrtf(s2 * (1.f / 512.f) - mu * mu + 1e-6f);
    float4 g0 = *(const float4*)&g[l * 8];
    float4 g1 = *(const float4*)&g[l * 8 + 4];
    float4 b0 = *(const float4*)&bta[l * 8];
    float4 b1 = *(const float4*)&bta[l * 8 + 4];
    unsigned o[4];
    o[0] = cvt_pk_bf16((a[0] - mu) * rr * g0.x + b0.x,
                       (a[1] - mu) * rr * g0.y + b0.y);
    o[1] = cvt_pk_bf16((a[2] - mu) * rr * g0.z + b0.z,
                       (a[3] - mu) * rr * g0.w + b0.w);
    o[2] = cvt_pk_bf16((a[4] - mu) * rr * g1.x + b1.x,
                       (a[5] - mu) * rr * g1.y + b1.y);
    o[3] = cvt_pk_bf16((a[6] - mu) * rr * g1.z + b1.z,
                       (a[7] - mu) * rr * g1.w + b1.w);
    *(uint4*)&hb[base] = make_uint4(o[0], o[1], o[2], o[3]);
}

// ---------------------------------------------------------------------------
// Head hidden: hid[b,o,j] = relu(x_cls[b,o,:] @ Wh[o] + bh[o,j])
// ---------------------------------------------------------------------------
__global__ __launch_bounds__(256) void k_hid(const short* __restrict__ hb,
                                             const float* __restrict__ Wh,
                                             const float* __restrict__ bh,
                                             float* __restrict__ hid) {
    int j = blockIdx.x * 256 + threadIdx.x;
    int o = blockIdx.y, b = blockIdx.z;
    const short* xr = hb + ((size_t)(b * SEQ + o)) * DIM;
    const float* wcol = Wh + (size_t)o * DIM * DIM + j;
    float acc = bh[o * DIM + j];
    #pragma unroll 8
    for (int d = 0; d < DIM; d++)
        acc = fmaf(bf2f(xr[d]), wcol[(size_t)d * DIM], acc);
    hid[((size_t)b * 8 + o) * DIM + j] = fmaxf(acc, 0.f);
}

// ---------------------------------------------------------------------------
__device__ __forceinline__ float softplus_f(float x) { return log1pf(expf(x)); }

__global__ __launch_bounds__(64) void k_var(const float* __restrict__ hid,
                                            const float* __restrict__ mu_wmu,
                                            const float* __restrict__ mu_wrho,
                                            const float* __restrict__ mu_bmu,
                                            const float* __restrict__ mu_brho,
                                            const float* __restrict__ lv_wmu,
                                            const float* __restrict__ lv_wrho,
                                            const float* __restrict__ lv_bmu,
                                            const float* __restrict__ lv_brho,
                                            const float* __restrict__ eps_mu_w,
                                            const float* __restrict__ eps_mu_b,
                                            const float* __restrict__ eps_lv_w,
                                            const float* __restrict__ eps_lv_b,
                                            float* __restrict__ out) {
    const float EPS = 1e-8f;
    int bo = blockIdx.x;
    int o = bo & 7;
    int l = threadIdx.x;
    float am = 0.f, al = 0.f;
    #pragma unroll
    for (int k = 0; k < 8; k++) {
        int d = k * 64 + l;
        int od = o * DIM + d;
        float hv = hid[(size_t)bo * DIM + d];
        am = fmaf(hv, mu_wmu[od] + (softplus_f(mu_wrho[od]) + EPS) * eps_mu_w[od], am);
        al = fmaf(hv, lv_wmu[od] + (softplus_f(lv_wrho[od]) + EPS) * eps_lv_w[od], al);
    }
    am = wred_sum(am);
    al = wred_sum(al);
    if (l == 0) {
        float mu = am + mu_bmu[o] + (softplus_f(mu_brho[o]) + EPS) * eps_mu_b[o];
        out[bo] = mu;
        float lvv = al + lv_bmu[o] + (softplus_f(lv_brho[o]) + EPS) * eps_lv_b[o];
        out[256 + bo] = logf(EPS + softplus_f(lvv));
    }
}

// ---------------------------------------------------------------------------
extern "C" void kernel_launch(void* const* d_in, const int* in_sizes, int n_in,
                              void* d_out, int out_size, void* d_ws, size_t ws_size,
                              hipStream_t stream) {
    const float* x      = (const float*)d_in[0];
    const float* W_in   = (const float*)d_in[1];
    const float* b_in   = (const float*)d_in[2];
    const float* cls    = (const float*)d_in[3];
    const float* Wqkv   = (const float*)d_in[4];
    const float* bqkv   = (const float*)d_in[5];
    const float* Wo     = (const float*)d_in[6];
    const float* bo     = (const float*)d_in[7];
    const float* ln1_g  = (const float*)d_in[8];
    const float* ln1_b  = (const float*)d_in[9];
    const float* Wm1    = (const float*)d_in[10];
    const float* bm1    = (const float*)d_in[11];
    const float* Wm2    = (const float*)d_in[12];
    const float* bm2    = (const float*)d_in[13];
    const float* ln2_g  = (const float*)d_in[14];
    const float* ln2_b  = (const float*)d_in[15];
    const float* Wh     = (const float*)d_in[16];
    const float* bh     = (const float*)d_in[17];
    const float* mu_wmu = (const float*)d_in[18];
    const float* mu_wrho= (const float*)d_in[19];
    const float* mu_bmu = (const float*)d_in[20];
    const float* mu_brho= (const float*)d_in[21];
    const float* lv_wmu = (const float*)d_in[22];
    const float* lv_wrho= (const float*)d_in[23];
    const float* lv_bmu = (const float*)d_in[24];
    const float* lv_brho= (const float*)d_in[25];
    const float* e_mu_w = (const float*)d_in[26];
    const float* e_mu_b = (const float*)d_in[27];
    const float* e_lv_w = (const float*)d_in[28];
    const float* e_lv_b = (const float*)d_in[29];
    float* out = (float*)d_out;

    char* p = (char*)d_ws;
    auto alloc = [&](size_t bytes) {
        char* r = p;
        p += (bytes + 255) & ~(size_t)255;
        return r;
    };
    const size_t qkv_bytes = (size_t)NROW * 1536 * 2;
    const size_t kbuf_bytes = (size_t)BATCH * NHEAD * SP * 64 * 2;
    const size_t attn_bytes = qkv_bytes + 2 * kbuf_bytes + 512;
    const size_t mid_bytes = (size_t)NROW * MLPD * 2;
    char*   U1    =          alloc(attn_bytes > mid_bytes ? attn_bytes : mid_bytes);
    short*  qkv   = (short*)U1;
    short*  kbuf  = (short*)(U1 + ((qkv_bytes + 255) & ~(size_t)255));
    short*  vtbuf = kbuf + kbuf_bytes / 2;
    short*  mid   = (short*)U1;
    short*  hb    = (short*) alloc((size_t)NROW * DIM * 2);
    short*  deltab= (short*) alloc((size_t)NROW * DIM * 2);
    short*  aob   = (short*) alloc((size_t)NROW * DIM * 2);
    short*  wqkvt = (short*) alloc((size_t)NLAYER * 1536 * 512 * 2);
    short*  wot   = (short*) alloc((size_t)NLAYER * 512 * 512 * 2);
    short*  wm1t  = (short*) alloc((size_t)NLAYER * 2048 * 512 * 2);
    short*  wm2t  = (short*) alloc((size_t)NLAYER * 512 * 2048 * 2);
    float2* ropet = (float2*)alloc((size_t)SEQ * NPAIR * 8);
    float*  hid   = (float*) alloc((size_t)256 * DIM * 4);

    k_wconv<<<dim3(24, 8, 4), 256, 0, stream>>>(Wqkv, wqkvt, 512, 1536);
    k_wconv<<<dim3(8, 8, 4),  256, 0, stream>>>(Wo,   wot,   512, 512);
    k_wconv<<<dim3(32, 8, 4), 256, 0, stream>>>(Wm1,  wm1t,  512, 2048);
    k_wconv<<<dim3(8, 32, 4), 256, 0, stream>>>(Wm2,  wm2t,  2048, 512);
    k_rope_tab<<<SEQ, NPAIR, 0, stream>>>(ropet);
    k_in_proj<<<NROW, 256, 0, stream>>>(x, W_in, b_in, cls, hb);

    const int RT = NROW / 128;   // 130
    for (int l = 0; l < NLAYER; l++) {
        k_gemm<32, false, false><<<RT * 12, 256, 0, stream>>>(
            hb, wqkvt + (size_t)l * 1536 * 512, bqkv + l * 1536, nullptr, qkv, 1536, 512);
        k_kvprep<<<BATCH * NHEAD * 9, 256, 0, stream>>>(qkv, ropet, kbuf, vtbuf);
        k_attn_mfma<<<9 * 256, 256, 0, stream>>>(qkv, kbuf, vtbuf, ropet, aob);
        k_gemm<64, false, true><<<RT * 4, 256, 0, stream>>>(
            aob, wot + (size_t)l * 512 * 512, bo + l * 512, hb, deltab, 512, 512);
        k_ln<<<NROW / 4, 256, 0, stream>>>(hb, deltab, ln1_g + l * 512, ln1_b + l * 512);
        k_gemm<32, true, false><<<RT * 16, 256, 0, stream>>>(
            hb, wm1t + (size_t)l * 2048 * 512, bm1 + l * 2048, nullptr, mid, 2048, 512);
        k_gemm<64, false, true><<<RT * 4, 256, 0, stream>>>(
            mid, wm2t + (size_t)l * 512 * 2048, bm2 + l * 512, hb, deltab, 512, 2048);
        k_ln<<<NROW / 4, 256, 0, stream>>>(hb, deltab, ln2_g + l * 512, ln2_b + l * 512);
    }

    k_hid<<<dim3(2, 8, 32), 256, 0, stream>>>(hb, Wh, bh, hid);
    k_var<<<256, 64, 0, stream>>>(hid, mu_wmu, mu_wrho, mu_bmu, mu_brho,
                                  lv_wmu, lv_wrho, lv_bmu, lv_brho,
                                  e_mu_w, e_mu_b, e_lv_w, e_lv_b, out);
}